// Round 10
// baseline (403.263 us; speedup 1.0000x reference)
//
#include <hip/hip_runtime.h>
#include <hip/hip_bf16.h>
#include <math.h>

#define HW 4096

typedef __attribute__((ext_vector_type(8))) short bf16x8;
typedef __attribute__((ext_vector_type(4))) float f32x4;

static __device__ __forceinline__ unsigned short f2bf(float x) {
    unsigned u = __float_as_uint(x);
    u += 0x7fffu + ((u >> 16) & 1u);     // RNE
    return (unsigned short)(u >> 16);
}
static __device__ __forceinline__ float bf2f(unsigned short h) {
    return __uint_as_float((unsigned)h << 16);
}

// ---------------- combined transpose+bf16: z=0: group(192ch)->X0T; z=1: BGc(64ch)->BGcT
__global__ __launch_bounds__(256) void k_transpose2(
    const float* __restrict__ group, const float* __restrict__ BGc, int bstride,
    unsigned short* __restrict__ X0T, unsigned short* __restrict__ BGcT)
{
    extern __shared__ float lds[];          // [C][65]
    const int b = blockIdx.y, p0 = blockIdx.x << 6, t = threadIdx.x;
    const int z = blockIdx.z;
    const int C = z ? 64 : 192;
    const float* xb = (z ? BGc : group) + (size_t)b * bstride;
    unsigned short* outT = z ? BGcT : X0T;
    for (int idx = t; idx < (C << 6); idx += 256) {
        int c = idx >> 6, p = idx & 63;
        lds[c * 65 + p] = xb[(size_t)c * HW + p0 + p];
    }
    __syncthreads();
    unsigned short* ob = outT + ((size_t)b * HW + p0) * C;
    for (int idx = t; idx < (C << 6); idx += 256) {
        int p = idx / C, c = idx - p * C;
        ob[idx] = f2bf(lds[c * 65 + p]);
    }
}

// ---------------- static weight prep (wg1, wc1, wh) + zero pool accumulators
__global__ __launch_bounds__(256) void k_wprep(
    const float* __restrict__ w1, const float* __restrict__ wc1,
    const float* __restrict__ wh,
    unsigned short* __restrict__ o, float* __restrict__ poolz)
{
    int bid = blockIdx.x, t = threadIdx.x;
    if (bid < 144) {
        int i = bid * 256 + t;
        o[i] = f2bf(w1[i]);
    } else if (bid < 160) {
        int i = ((bid - 144) << 8) + t;
        o[36864 + i] = f2bf(wc1[i]);
    } else if (bid < 176) {
        int i = ((bid - 160) << 8) + t;
        o[40960 + i] = f2bf(wh[i]);
    } else {
        #pragma unroll
        for (int j = 0; j < 4; ++j) poolz[t + j * 256] = 0.f;   // pool_g(768)+pool_c(256)
    }
}

// ---------------- MFMA GEMM conv1x1 (+ optional channel-pool atomics epilogue)
__global__ __launch_bounds__(256) void k_gconv(
    const unsigned short* __restrict__ XT, int ldx, int kOff, int xbstride,
    const unsigned short* __restrict__ W, int wbstride,
    const float* __restrict__ bias, int bias_bstride,
    unsigned short* __restrict__ yT, int ldyT,
    unsigned short* __restrict__ yN,
    float* __restrict__ pool,
    int Cin, int Cout)
{
    const int t = threadIdx.x;
    const int w = t >> 6, lane = t & 63;
    const int gid = lane >> 4, cid = lane & 15;
    const int b = blockIdx.z;
    const int p0 = blockIdx.x << 6;
    const int co16 = ((blockIdx.y << 2) + w) << 4;
    const unsigned short* xrow = XT + (size_t)b * xbstride + kOff;
    const unsigned short* wr = W + (size_t)b * wbstride + (size_t)co16 * Cin;
    const float* br = bias + b * bias_bstride;
    f32x4 acc[4];
    #pragma unroll
    for (int n = 0; n < 4; ++n)
        #pragma unroll
        for (int r = 0; r < 4; ++r)
            acc[n][r] = br[co16 + 4 * gid + r];
    for (int kc = 0; kc < Cin; kc += 32) {
        bf16x8 a = *(const bf16x8*)(wr + (size_t)cid * Cin + kc + 8 * gid);
        #pragma unroll
        for (int n = 0; n < 4; ++n) {
            const unsigned short* xp = xrow + (size_t)(p0 + 16 * n + cid) * ldx + kc + 8 * gid;
            bf16x8 bfr = *(const bf16x8*)xp;
            acc[n] = __builtin_amdgcn_mfma_f32_16x16x32_bf16(a, bfr, acc[n], 0, 0, 0);
        }
    }
    #pragma unroll
    for (int n = 0; n < 4; ++n)
        #pragma unroll
        for (int r = 0; r < 4; ++r) {
            float v = acc[n][r];
            int co = co16 + 4 * gid + r;
            int p  = p0 + 16 * n + cid;
            if (yT) yT[((size_t)b * HW + p) * ldyT + co] = f2bf(v);
            if (yN) yN[((size_t)b * Cout + co) * HW + p] = f2bf(v);
        }
    if (pool) {
        float ps[4];
        #pragma unroll
        for (int r = 0; r < 4; ++r) {
            ps[r] = acc[0][r] + acc[1][r] + acc[2][r] + acc[3][r];
            #pragma unroll
            for (int o = 8; o > 0; o >>= 1)
                ps[r] += __shfl_xor(ps[r], o, 64);
        }
        if (cid == 0) {
            #pragma unroll
            for (int r = 0; r < 4; ++r)
                atomicAdd(&pool[b * Cout + co16 + 4 * gid + r], ps[r]);
        }
    }
}

// ---------------- both CA MLPs (x: 0=group C=192 R=12, 1=center C=64 R=4)
__global__ __launch_bounds__(256) void k_ca_mlp2(
    const float* __restrict__ pool_g,
    const float* __restrict__ gw1, const float* __restrict__ gb1,
    const float* __restrict__ gw2, const float* __restrict__ gb2,
    float* __restrict__ s_g,
    const float* __restrict__ pool_c,
    const float* __restrict__ cw1, const float* __restrict__ cb1,
    const float* __restrict__ cw2, const float* __restrict__ cb2,
    float* __restrict__ s_c)
{
    int which = blockIdx.x, b = blockIdx.y, t = threadIdx.x;
    const float* pool = which ? pool_c : pool_g;
    const float* w1 = which ? cw1 : gw1;
    const float* b1 = which ? cb1 : gb1;
    const float* w2 = which ? cw2 : gw2;
    const float* b2 = which ? cb2 : gb2;
    float* s = which ? s_c : s_g;
    const int C = which ? 64 : 192;
    const int R = which ? 4 : 12;
    __shared__ float z[16];
    __shared__ float yv[192];
    for (int i = t; i < C; i += 256) yv[i] = pool[b * C + i] * (1.0f / HW);
    __syncthreads();
    if (t < R) {
        float a = b1[t];
        for (int i = 0; i < C; ++i) a = fmaf(w1[t * C + i], yv[i], a);
        z[t] = fmaxf(a, 0.f);
    }
    __syncthreads();
    if (t < C) {
        float a = b2[t];
        for (int j = 0; j < R; ++j) a = fmaf(w2[t * R + j], z[j], a);
        s[b * C + t] = 1.f / (1.f + __expf(-a));
    }
}

// ---------------- compose conv chains into per-batch weights:
// WfB = log2e * wf @ wg3 @ (wg2 . s_g); biasf = log2e*(wf@(wg3@bg2+bg3)+f_b)
// WgB = wg @ (wc2 . s_c);               biasg = wg@bc2 + g_b
__global__ __launch_bounds__(256) void k_wcombine(
    const float* __restrict__ wg2, const float* __restrict__ wg3,
    const float* __restrict__ wf, const float* __restrict__ bg2,
    const float* __restrict__ bg3, const float* __restrict__ fb,
    const float* __restrict__ wc2, const float* __restrict__ wg,
    const float* __restrict__ bc2, const float* __restrict__ gb,
    const float* __restrict__ s_g, const float* __restrict__ s_c,
    unsigned short* __restrict__ WfB, float* __restrict__ biasf,
    unsigned short* __restrict__ WgB, float* __restrict__ biasg)
{
    const float LOG2E = 1.4426950408889634f;
    int b = blockIdx.y, x = blockIdx.x, t = threadIdx.x;
    __shared__ float T1[64 * 96];
    const int i0 = x * 96;
    for (int idx = t; idx < 64 * 96; idx += 256) {
        int m = idx / 96, ii = idx - m * 96, i = i0 + ii;
        float a = 0.f;
        for (int k2 = 0; k2 < 64; ++k2) a = fmaf(wg3[m * 64 + k2], wg2[k2 * 192 + i], a);
        T1[m * 96 + ii] = a * s_g[b * 192 + i];
    }
    __syncthreads();
    for (int idx = t; idx < 64 * 96; idx += 256) {
        int o = idx / 96, ii = idx - o * 96;
        float a = 0.f;
        for (int m = 0; m < 64; ++m) a = fmaf(wf[o * 64 + m], T1[m * 96 + ii], a);
        WfB[(size_t)b * 12288 + o * 192 + i0 + ii] = f2bf(a * LOG2E);
    }
    const int j0 = x * 32;
    for (int idx = t; idx < 64 * 32; idx += 256) {
        int o = idx / 32, i = j0 + (idx & 31);
        float a = 0.f;
        for (int m = 0; m < 64; ++m) a = fmaf(wg[o * 64 + m], wc2[m * 64 + i] * s_c[b * 64 + i], a);
        WgB[(size_t)b * 4096 + o * 64 + i] = f2bf(a);
    }
    if (x == 0) {
        __shared__ float tb[64];
        if (t < 64) {
            float a = 0.f;
            for (int m = 0; m < 64; ++m) a = fmaf(wg3[t * 64 + m], bg2[m], a);
            tb[t] = a + bg3[t];
        }
        __syncthreads();
        if (t < 64) {
            float a = 0.f, g2 = 0.f;
            for (int m = 0; m < 64; ++m) {
                a  = fmaf(wf[t * 64 + m], tb[m], a);
                g2 = fmaf(wg[t * 64 + m], bc2[m], g2);
            }
            biasf[b * 64 + t] = (a + fb[t]) * LOG2E;
            biasg[b * 64 + t] = g2 + gb[t];
        }
    }
}

// ---------------- MFMA attention, no-max softmax (exp2; Q pre-scaled by log2e).
// Grid 512: kb=bid&1 (k-half), b=(bid&7)>>1 (XCD-pinned), qbase=(bid>>3)*64.
// 8 waves x 256 k each. Writes LINEAR partial sums am/a2/l per k-half.
__global__ __launch_bounds__(512, 4) void k_attn(
    const unsigned short* __restrict__ FqT, const unsigned short* __restrict__ GkT,
    const unsigned short* __restrict__ HvN,
    float* __restrict__ amP0, float* __restrict__ amP1,
    float* __restrict__ a2P0, float* __restrict__ a2P1,
    float* __restrict__ lP)
{
    __shared__ __align__(16) char smem[32768];   // P 8w*4KB; merge scratch overlaid
    const int t = threadIdx.x;
    const int bid = blockIdx.x;
    const int kb = bid & 1;
    const int b  = (bid & 7) >> 1;
    const int qbase = (bid >> 3) << 6;
    const int w = t >> 6, lane = t & 63;
    const int gid = lane >> 4, cid = lane & 15;
    const size_t CQ = (size_t)HW * 64;
    const unsigned short* fqt = FqT + (size_t)b * CQ;
    const unsigned short* gkt = GkT + (size_t)b * CQ;
    const unsigned short* hv  = HvN + (size_t)b * CQ;
    float* amp = kb ? amP1 : amP0;
    float* a2p = kb ? a2P1 : a2P0;
    float* lp  = lP + kb * 16384 + b * 4096;
    unsigned short* Pw = (unsigned short*)smem + w * 2048;   // 4KB/wave: [4qt][16q][64k] swz

    bf16x8 fqa[4][2];
    #pragma unroll
    for (int qt = 0; qt < 4; ++qt) {
        const unsigned short* fr = fqt + (size_t)(qbase + 16 * qt + cid) * 64 + 8 * gid;
        fqa[qt][0] = *(const bf16x8*)fr;
        fqa[qt][1] = *(const bf16x8*)(fr + 32);
    }
    bf16x8 ones;
    #pragma unroll
    for (int j = 0; j < 8; ++j) ones[j] = (short)0x3F80;

    const f32x4 fz = {0.f, 0.f, 0.f, 0.f};
    f32x4 am[4][4], a2[4][4], lac[4];
    #pragma unroll
    for (int qt = 0; qt < 4; ++qt) {
        lac[qt] = fz;
        #pragma unroll
        for (int n = 0; n < 4; ++n) { am[qt][n] = fz; a2[qt][n] = fz; }
    }

    const int k00 = (kb << 11) + (w << 8);       // 256 k per wave
    for (int it = 0; it < 4; ++it) {
        const int k0 = k00 + (it << 6);
        #pragma unroll
        for (int n = 0; n < 4; ++n) {
            const unsigned short* gr = gkt + (size_t)(k0 + 16 * n + cid) * 64 + 8 * gid;
            bf16x8 b0 = *(const bf16x8*)gr;
            bf16x8 b1 = *(const bf16x8*)(gr + 32);
            const int k = 16 * n + cid;
            #pragma unroll
            for (int qt = 0; qt < 4; ++qt) {
                f32x4 s = __builtin_amdgcn_mfma_f32_16x16x32_bf16(fqa[qt][0], b0, fz, 0, 0, 0);
                s = __builtin_amdgcn_mfma_f32_16x16x32_bf16(fqa[qt][1], b1, s, 0, 0, 0);
                #pragma unroll
                for (int r = 0; r < 4; ++r) {
                    int q = 4 * gid + r;
                    Pw[qt * 1024 + q * 64 + (((k >> 3) ^ (q & 7)) << 3) + (k & 7)] =
                        f2bf(__builtin_amdgcn_exp2f(s[r]));
                }
            }
        }
        bf16x8 pa[4][2];
        #pragma unroll
        for (int qt = 0; qt < 4; ++qt)
            #pragma unroll
            for (int kh = 0; kh < 2; ++kh)
                pa[qt][kh] = *(const bf16x8*)(Pw + qt * 1024 + cid * 64 +
                                              (((4 * kh + gid) ^ (cid & 7)) << 3));
        #pragma unroll
        for (int qt = 0; qt < 4; ++qt) {
            lac[qt] = __builtin_amdgcn_mfma_f32_16x16x32_bf16(pa[qt][0], ones, lac[qt], 0, 0, 0);
            lac[qt] = __builtin_amdgcn_mfma_f32_16x16x32_bf16(pa[qt][1], ones, lac[qt], 0, 0, 0);
        }
        #pragma unroll
        for (int n = 0; n < 4; ++n) {
            const unsigned short* hr = hv + (size_t)(16 * n + cid) * HW + k0;
            #pragma unroll
            for (int kh = 0; kh < 2; ++kh) {
                bf16x8 hb = *(const bf16x8*)(hr + 32 * kh + 8 * gid);
                bf16x8 h2;
                #pragma unroll
                for (int j = 0; j < 8; ++j) {
                    float v = bf2f((unsigned short)hb[j]);
                    h2[j] = (short)f2bf(v * v);
                }
                #pragma unroll
                for (int qt = 0; qt < 4; ++qt) {
                    am[qt][n] = __builtin_amdgcn_mfma_f32_16x16x32_bf16(pa[qt][kh], hb, am[qt][n], 0, 0, 0);
                    a2[qt][n] = __builtin_amdgcn_mfma_f32_16x16x32_bf16(pa[qt][kh], h2, a2[qt][n], 0, 0, 0);
                }
            }
        }
    }

    // ---- 8-way linear in-block merge -> write raw partial sums
    __syncthreads();
    float* lb = (float*)smem;                    // [8w][4qt][64][4] = 32 KB
    #pragma unroll
    for (int qt = 0; qt < 4; ++qt)
        *(f32x4*)(lb + ((size_t)(w * 4 + qt) * 64 + lane) * 4) = lac[qt];
    __syncthreads();
    if (t < 256) {
        int qt = t >> 6, ls = t & 63;
        f32x4 s = fz;
        #pragma unroll
        for (int ww = 0; ww < 8; ++ww)
            s += *(const f32x4*)(lb + ((size_t)(ww * 4 + qt) * 64 + ls) * 4);
        if ((ls & 15) == 0)
            *(f32x4*)(lp + qbase + qt * 16 + (ls >> 4) * 4) = s;
    }
    __syncthreads();
    float* ab = (float*)smem;
    for (int qt = 0; qt < 4; ++qt) {
        #pragma unroll
        for (int n = 0; n < 4; ++n)
            *(f32x4*)(ab + ((size_t)(w * 4 + n) * 64 + lane) * 4) = am[qt][n];
        __syncthreads();
        if (t < 256) {
            int n = t >> 6, ls = t & 63;
            f32x4 s = fz;
            #pragma unroll
            for (int ww = 0; ww < 8; ++ww)
                s += *(const f32x4*)(ab + ((size_t)(ww * 4 + n) * 64 + ls) * 4);
            int q0s = qbase + 16 * qt + 4 * (ls >> 4);
            int c   = 16 * n + (ls & 15);
            *(f32x4*)(amp + ((size_t)(b * 64 + c)) * HW + q0s) = s;
        }
        __syncthreads();
        #pragma unroll
        for (int n = 0; n < 4; ++n)
            *(f32x4*)(ab + ((size_t)(w * 4 + n) * 64 + lane) * 4) = a2[qt][n];
        __syncthreads();
        if (t < 256) {
            int n = t >> 6, ls = t & 63;
            f32x4 s = fz;
            #pragma unroll
            for (int ww = 0; ww < 8; ++ww)
                s += *(const f32x4*)(ab + ((size_t)(ww * 4 + n) * 64 + ls) * 4);
            int q0s = qbase + 16 * qt + 4 * (ls >> 4);
            int c   = 16 * n + (ls & 15);
            *(f32x4*)(a2p + ((size_t)(b * 64 + c)) * HW + q0s) = s;
        }
        __syncthreads();
    }
}

// ---------------- fused: attn finalize + mvn stats + transfer + cbam channel pools
// one block per (b,c); FG row cached in LDS
__global__ __launch_bounds__(256) void k_transfer_f(
    const float* __restrict__ am0, const float* __restrict__ am1,
    const float* __restrict__ a20, const float* __restrict__ a21,
    const float* __restrict__ lP,
    const float* __restrict__ FG, const float* __restrict__ BG, int bstride,
    float* __restrict__ xb, float* __restrict__ pavg, float* __restrict__ pmaxb)
{
    __shared__ float fgl[4096];
    __shared__ float r1[4], r2[4];
    const int bc = blockIdx.x, t = threadIdx.x;
    const int b = bc >> 6, c = bc & 63;
    const size_t row = (size_t)bc * HW;
    const float* fg = FG + (size_t)b * bstride + (size_t)(64 + c) * HW;
    const float* bg = BG + (size_t)b * bstride + (size_t)(64 + c) * HW;
    float s = 0.f, s2 = 0.f;
    #pragma unroll
    for (int j = 0; j < 16; ++j) {
        int i = t + j * 256;
        float v = fg[i];
        fgl[i] = v;
        s += v; s2 += v * v;
    }
    #pragma unroll
    for (int o = 32; o > 0; o >>= 1) { s += __shfl_down(s, o, 64); s2 += __shfl_down(s2, o, 64); }
    if ((t & 63) == 0) { r1[t >> 6] = s; r2[t >> 6] = s2; }
    __syncthreads();
    float m  = (r1[0] + r1[1] + r1[2] + r1[3]) * (1.0f / HW);
    float e2 = (r2[0] + r2[1] + r2[2] + r2[3]) * (1.0f / HW);
    float rs = rsqrtf(fmaxf(e2 - m * m, 0.f) + 1e-5f);
    const float* l0 = lP + (size_t)b * 4096;
    const float* l1 = lP + 16384 + (size_t)b * 4096;
    float psum = 0.f, pmax = -1e30f;
    #pragma unroll
    for (int j = 0; j < 16; ++j) {
        int q = t + j * 256;
        float linv = 1.f / (l0[q] + l1[q]);
        float mean = (am0[row + q] + am1[row + q]) * linv;
        float sec  = (a20[row + q] + a21[row + q]) * linv;
        float sd = sqrtf(fmaxf(sec - mean * mean, 0.f));
        float xv = sd * (fgl[q] - m) * rs + mean + bg[q];
        xb[row + q] = xv;
        psum += xv; pmax = fmaxf(pmax, xv);
    }
    __syncthreads();
    #pragma unroll
    for (int o = 32; o > 0; o >>= 1) {
        psum += __shfl_down(psum, o, 64);
        pmax = fmaxf(pmax, __shfl_down(pmax, o, 64));
    }
    if ((t & 63) == 0) { r1[t >> 6] = psum; r2[t >> 6] = pmax; }
    __syncthreads();
    if (t == 0) {
        pavg[bc]  = (r1[0] + r1[1] + r1[2] + r1[3]) * (1.0f / HW);
        pmaxb[bc] = fmaxf(fmaxf(r2[0], r2[1]), fmaxf(r2[2], r2[3]));
    }
}

// ---------------- CBAM channel-scale (recomputed per block; trivial cost)
static __device__ __forceinline__ void cbam_scale(
    const float* __restrict__ pav, const float* __restrict__ pmx,
    const float* __restrict__ w1, const float* __restrict__ b1,
    const float* __restrict__ w2, const float* __restrict__ b2,
    int b, int t, float* scb)
{
    __shared__ float za[4], zm[4];
    if (t < 4) {
        float aa = b1[t], am = b1[t];
        for (int i = 0; i < 64; ++i) {
            aa = fmaf(w1[t * 64 + i], pav[b * 64 + i], aa);
            am = fmaf(w1[t * 64 + i], pmx[b * 64 + i], am);
        }
        za[t] = fmaxf(aa, 0.f);
        zm[t] = fmaxf(am, 0.f);
    }
    __syncthreads();
    if (t < 64) {
        float a = 2.f * b2[t];
        for (int j = 0; j < 4; ++j) a = fmaf(w2[t * 4 + j], za[j] + zm[j], a);
        scb[t] = 1.f / (1.f + __expf(-a));
    }
    __syncthreads();
}

// ---------------- spatial pool of (xb*s) with inlined cbam MLP
__global__ __launch_bounds__(256) void k_sp_pool(
    const float* __restrict__ xb,
    const float* __restrict__ pav, const float* __restrict__ pmx,
    const float* __restrict__ w1, const float* __restrict__ b1,
    const float* __restrict__ w2, const float* __restrict__ b2,
    float* __restrict__ spm, float* __restrict__ spx)
{
    __shared__ float scb[64];
    const int b = blockIdx.y, t = threadIdx.x;
    cbam_scale(pav, pmx, w1, b1, w2, b2, b, t, scb);
    const int p = blockIdx.x * 256 + t;
    const float* xp = xb + (size_t)b * 262144 + p;
    float sum = 0.f, mx = -1e30f;
    for (int c = 0; c < 64; ++c) {
        float v = xp[(size_t)c * HW] * scb[c];
        sum += v;
        mx = fmaxf(mx, v);
    }
    spm[b * HW + p] = sum * (1.0f / 64.0f);
    spx[b * HW + p] = mx;
}

// ---------------- fused 7x7 spatial conv + sigmoid + final output
__global__ __launch_bounds__(256) void k_spf(
    const float* __restrict__ spm, const float* __restrict__ spx,
    const float* __restrict__ w, const float* __restrict__ bias,
    const float* __restrict__ xb,
    const float* __restrict__ pav, const float* __restrict__ pmx,
    const float* __restrict__ w1, const float* __restrict__ b1,
    const float* __restrict__ w2, const float* __restrict__ b2,
    float* __restrict__ out)
{
    __shared__ float scb[64];
    const int b = blockIdx.y, t = threadIdx.x;
    cbam_scale(pav, pmx, w1, b1, w2, b2, b, t, scb);
    const int p = blockIdx.x * 256 + t;
    const int y = p >> 6, x = p & 63;
    float acc = bias[0];
    for (int dy = 0; dy < 7; ++dy) {
        int yy = y + dy - 3;
        if (yy < 0 || yy >= 64) continue;
        for (int dx = 0; dx < 7; ++dx) {
            int xx = x + dx - 3;
            if (xx < 0 || xx >= 64) continue;
            int q = b * HW + yy * 64 + xx;
            acc = fmaf(spm[q], w[dy * 7 + dx],      acc);
            acc = fmaf(spx[q], w[49 + dy * 7 + dx], acc);
        }
    }
    float sgm = 1.f / (1.f + __expf(-acc));
    const float* xp = xb + (size_t)b * 262144 + p;
    float* op = out + (size_t)b * 262144 + p;
    for (int c = 0; c < 64; ++c)
        op[(size_t)c * HW] = xp[(size_t)c * HW] * scb[c] * sgm;
}

extern "C" void kernel_launch(void* const* d_in, const int* in_sizes, int n_in,
                              void* d_out, int out_size, void* d_ws, size_t ws_size,
                              hipStream_t stream)
{
    const float* group  = (const float*)d_in[0];
    const float* FG     = (const float*)d_in[1];
    const float* BG     = (const float*)d_in[2];
    const float* wg1    = (const float*)d_in[3];
    const float* bg1    = (const float*)d_in[4];
    const float* cag_w1 = (const float*)d_in[5];
    const float* cag_b1 = (const float*)d_in[6];
    const float* cag_w2 = (const float*)d_in[7];
    const float* cag_b2 = (const float*)d_in[8];
    const float* wg2    = (const float*)d_in[9];
    const float* bg2    = (const float*)d_in[10];
    const float* wg3    = (const float*)d_in[11];
    const float* bg3    = (const float*)d_in[12];
    const float* wc1    = (const float*)d_in[13];
    const float* bc1    = (const float*)d_in[14];
    const float* cac_w1 = (const float*)d_in[15];
    const float* cac_b1 = (const float*)d_in[16];
    const float* cac_w2 = (const float*)d_in[17];
    const float* cac_b2 = (const float*)d_in[18];
    const float* wc2    = (const float*)d_in[19];
    const float* bc2    = (const float*)d_in[20];
    const float* f_w    = (const float*)d_in[21];
    const float* f_b    = (const float*)d_in[22];
    const float* g_w    = (const float*)d_in[23];
    const float* g_b    = (const float*)d_in[24];
    const float* h_w    = (const float*)d_in[25];
    const float* h_b    = (const float*)d_in[26];
    const float* mlp_w1 = (const float*)d_in[27];
    const float* mlp_b1 = (const float*)d_in[28];
    const float* mlp_w2 = (const float*)d_in[29];
    const float* mlp_b2 = (const float*)d_in[30];
    const float* sp_w   = (const float*)d_in[31];
    const float* sp_b   = (const float*)d_in[32];
    float* out = (float*)d_out;

    const int B = 4;
    const size_t CHW = (size_t)64 * HW;
    const int BST = (int)(3 * CHW);

    float* ws = (float*)d_ws;
    const size_t M = 1048576;
    // bf16 tiles:
    unsigned short* X0T  = (unsigned short*)ws;                 // [0,1.5M)f; dead after g1,c1
    unsigned short* g1T  = (unsigned short*)(ws + 3 * M / 2);   // [1.5M,3M); dead after Fq
    unsigned short* c1T  = (unsigned short*)(ws + 3 * M);       // [3M,3.5M); dead after Gk
    unsigned short* BGcT = (unsigned short*)(ws + 7 * M / 2);   // [3.5M,4M); dead after Hv
    unsigned short* FqT  = (unsigned short*)(ws + 4 * M);       // [4M,4.5M); dead after attn
    unsigned short* GkT  = (unsigned short*)(ws + 9 * M / 2);   // [4.5M,5M); dead after attn
    unsigned short* hvN  = (unsigned short*)(ws + 5 * M);       // [5M,5.5M); dead after attn
    // attn partials (live only attn->transfer):
    float* am0 = ws;                 // [0,1M)
    float* am1 = ws + M;             // [1M,2M)
    float* a20 = ws + 2 * M;         // [2M,3M)
    float* a21 = ws + 11 * M / 2;    // [5.5M,6.5M)
    float* lP  = ws + 13 * M / 2;    // [6.5M,+32768) : [2][B][4096]
    float* xb  = ws + 4 * M;         // [4M,5M) over FqT/GkT (dead after attn)
    // smalls
    float* smalls = ws + 13 * M / 2 + 32768;
    float* pool_g = smalls;            // 768
    float* pool_c = smalls + 768;      // 256 (contiguous with pool_g for zeroing)
    float* s_g    = smalls + 1024;     // 768
    float* s_c    = smalls + 1792;     // 256
    float* pav    = smalls + 2048;     // 256
    float* pmx    = smalls + 2304;     // 256
    float* biasf  = smalls + 2560;     // 256
    float* biasg  = smalls + 2816;     // 256
    float* spm    = smalls + 3072;     // 16384
    float* spx    = smalls + 19456;    // 16384
    unsigned short* wreg = (unsigned short*)(smalls + 35840);
    unsigned short* wg1b = wreg;                    // 36864
    unsigned short* wc1b = wreg + 36864;            // 4096
    unsigned short* whb  = wreg + 40960;            // 4096
    unsigned short* WfB  = wreg + 45056;            // 4*64*192 = 49152
    unsigned short* WgB  = wreg + 94208;            // 4*4096 = 16384

    unsigned short* nil = (unsigned short*)nullptr;
    dim3 blk(256);

    // input transposes + static weights + pool zero-init
    k_transpose2<<<dim3(64, B, 2), blk, 192 * 65 * 4, stream>>>(group, BG + CHW, BST, X0T, BGcT);
    k_wprep<<<177, blk, 0, stream>>>(wg1, wc1, h_w, wreg, pool_g);
    // g1 (192->192) + pool ; c1 (64->64) + pool
    k_gconv<<<dim3(64, 3, B), blk, 0, stream>>>(X0T, 192, 0, HW * 192, wg1b, 0, bg1, 0, g1T, 192, nil, pool_g, 192, 192);
    k_gconv<<<dim3(64, 1, B), blk, 0, stream>>>(X0T, 192, 64, HW * 192, wc1b, 0, bc1, 0, c1T, 64, nil, pool_c, 64, 64);
    // CA scales + weight composition
    k_ca_mlp2<<<dim3(2, B), blk, 0, stream>>>(pool_g, cag_w1, cag_b1, cag_w2, cag_b2, s_g,
                                              pool_c, cac_w1, cac_b1, cac_w2, cac_b2, s_c);
    k_wcombine<<<dim3(2, B), blk, 0, stream>>>(wg2, wg3, f_w, bg2, bg3, f_b,
                                               wc2, g_w, bc2, g_b, s_g, s_c,
                                               WfB, biasf, WgB, biasg);
    // projections (composed convs)
    k_gconv<<<dim3(64, 1, B), blk, 0, stream>>>(g1T, 192, 0, HW * 192, WfB, 12288, biasf, 64, FqT, 64, nil, nullptr, 192, 64);
    k_gconv<<<dim3(64, 1, B), blk, 0, stream>>>(c1T, 64, 0, HW * 64, WgB, 4096, biasg, 64, GkT, 64, nil, nullptr, 64, 64);
    k_gconv<<<dim3(64, 1, B), blk, 0, stream>>>(BGcT, 64, 0, HW * 64, whb, 0, h_b, 0, nil, 64, hvN, nullptr, 64, 64);
    // attention (k-split=2, XCD-pinned, 2 blocks/CU)
    k_attn<<<512, 512, 0, stream>>>(FqT, GkT, hvN, am0, am1, a20, a21, lP);
    // fused finalize + mvn + transfer + cbam pools
    k_transfer_f<<<B * 64, blk, 0, stream>>>(am0, am1, a20, a21, lP, FG, BG, BST, xb, pav, pmx);
    // CBAM spatial
    k_sp_pool<<<dim3(HW / 256, B), blk, 0, stream>>>(xb, pav, pmx, mlp_w1, mlp_b1, mlp_w2, mlp_b2, spm, spx);
    k_spf<<<dim3(HW / 256, B), blk, 0, stream>>>(spm, spx, sp_w, sp_b, xb, pav, pmx, mlp_w1, mlp_b1, mlp_w2, mlp_b2, out);
}

// Round 11
// 245.198 us; speedup vs baseline: 1.6446x; 1.6446x over previous
//
#include <hip/hip_runtime.h>
#include <hip/hip_bf16.h>
#include <math.h>

#define HW 4096

typedef __attribute__((ext_vector_type(8))) short bf16x8;
typedef __attribute__((ext_vector_type(4))) float f32x4;

static __device__ __forceinline__ unsigned short f2bf(float x) {
    unsigned u = __float_as_uint(x);
    u += 0x7fffu + ((u >> 16) & 1u);     // RNE
    return (unsigned short)(u >> 16);
}
static __device__ __forceinline__ float bf2f(unsigned short h) {
    return __uint_as_float((unsigned)h << 16);
}

// ---------------- combined transpose+bf16: z=0: group(192ch)->X0T; z=1: BGc(64ch)->BGcT
__global__ __launch_bounds__(256) void k_transpose2(
    const float* __restrict__ group, const float* __restrict__ BGc, int bstride,
    unsigned short* __restrict__ X0T, unsigned short* __restrict__ BGcT)
{
    extern __shared__ float lds[];          // [C][65]
    const int b = blockIdx.y, p0 = blockIdx.x << 6, t = threadIdx.x;
    const int z = blockIdx.z;
    const int C = z ? 64 : 192;
    const float* xb = (z ? BGc : group) + (size_t)b * bstride;
    unsigned short* outT = z ? BGcT : X0T;
    for (int idx = t; idx < (C << 6); idx += 256) {
        int c = idx >> 6, p = idx & 63;
        lds[c * 65 + p] = xb[(size_t)c * HW + p0 + p];
    }
    __syncthreads();
    unsigned short* ob = outT + ((size_t)b * HW + p0) * C;
    for (int idx = t; idx < (C << 6); idx += 256) {
        int p = idx / C, c = idx - p * C;
        ob[idx] = f2bf(lds[c * 65 + p]);
    }
}

// ---------------- static weight prep (wg1, wc1, wh) + zero pool accumulators
__global__ __launch_bounds__(256) void k_wprep(
    const float* __restrict__ w1, const float* __restrict__ wc1,
    const float* __restrict__ wh,
    unsigned short* __restrict__ o, float* __restrict__ poolz)
{
    int bid = blockIdx.x, t = threadIdx.x;
    if (bid < 144) {
        int i = bid * 256 + t;
        o[i] = f2bf(w1[i]);
    } else if (bid < 160) {
        int i = ((bid - 144) << 8) + t;
        o[36864 + i] = f2bf(wc1[i]);
    } else if (bid < 176) {
        int i = ((bid - 160) << 8) + t;
        o[40960 + i] = f2bf(wh[i]);
    } else {
        #pragma unroll
        for (int j = 0; j < 4; ++j) poolz[t + j * 256] = 0.f;   // pool_g(768)+pool_c(256)
    }
}

// ---------------- MFMA GEMM conv1x1 (+ optional channel-pool atomics epilogue)
__global__ __launch_bounds__(256) void k_gconv(
    const unsigned short* __restrict__ XT, int ldx, int kOff, int xbstride,
    const unsigned short* __restrict__ W, int wbstride,
    const float* __restrict__ bias, int bias_bstride,
    unsigned short* __restrict__ yT, int ldyT,
    unsigned short* __restrict__ yN,
    float* __restrict__ pool,
    int Cin, int Cout)
{
    const int t = threadIdx.x;
    const int w = t >> 6, lane = t & 63;
    const int gid = lane >> 4, cid = lane & 15;
    const int b = blockIdx.z;
    const int p0 = blockIdx.x << 6;
    const int co16 = ((blockIdx.y << 2) + w) << 4;
    const unsigned short* xrow = XT + (size_t)b * xbstride + kOff;
    const unsigned short* wr = W + (size_t)b * wbstride + (size_t)co16 * Cin;
    const float* br = bias + b * bias_bstride;
    f32x4 acc[4];
    #pragma unroll
    for (int n = 0; n < 4; ++n)
        #pragma unroll
        for (int r = 0; r < 4; ++r)
            acc[n][r] = br[co16 + 4 * gid + r];
    for (int kc = 0; kc < Cin; kc += 32) {
        bf16x8 a = *(const bf16x8*)(wr + (size_t)cid * Cin + kc + 8 * gid);
        #pragma unroll
        for (int n = 0; n < 4; ++n) {
            const unsigned short* xp = xrow + (size_t)(p0 + 16 * n + cid) * ldx + kc + 8 * gid;
            bf16x8 bfr = *(const bf16x8*)xp;
            acc[n] = __builtin_amdgcn_mfma_f32_16x16x32_bf16(a, bfr, acc[n], 0, 0, 0);
        }
    }
    #pragma unroll
    for (int n = 0; n < 4; ++n)
        #pragma unroll
        for (int r = 0; r < 4; ++r) {
            float v = acc[n][r];
            int co = co16 + 4 * gid + r;
            int p  = p0 + 16 * n + cid;
            if (yT) yT[((size_t)b * HW + p) * ldyT + co] = f2bf(v);
            if (yN) yN[((size_t)b * Cout + co) * HW + p] = f2bf(v);
        }
    if (pool) {
        float ps[4];
        #pragma unroll
        for (int r = 0; r < 4; ++r) {
            ps[r] = acc[0][r] + acc[1][r] + acc[2][r] + acc[3][r];
            #pragma unroll
            for (int o = 8; o > 0; o >>= 1)
                ps[r] += __shfl_xor(ps[r], o, 64);
        }
        if (cid == 0) {
            #pragma unroll
            for (int r = 0; r < 4; ++r)
                atomicAdd(&pool[b * Cout + co16 + 4 * gid + r], ps[r]);
        }
    }
}

// ---------------- both CA MLPs (x: 0=group C=192 R=12, 1=center C=64 R=4)
__global__ __launch_bounds__(256) void k_ca_mlp2(
    const float* __restrict__ pool_g,
    const float* __restrict__ gw1, const float* __restrict__ gb1,
    const float* __restrict__ gw2, const float* __restrict__ gb2,
    float* __restrict__ s_g,
    const float* __restrict__ pool_c,
    const float* __restrict__ cw1, const float* __restrict__ cb1,
    const float* __restrict__ cw2, const float* __restrict__ cb2,
    float* __restrict__ s_c)
{
    int which = blockIdx.x, b = blockIdx.y, t = threadIdx.x;
    const float* pool = which ? pool_c : pool_g;
    const float* w1 = which ? cw1 : gw1;
    const float* b1 = which ? cb1 : gb1;
    const float* w2 = which ? cw2 : gw2;
    const float* b2 = which ? cb2 : gb2;
    float* s = which ? s_c : s_g;
    const int C = which ? 64 : 192;
    const int R = which ? 4 : 12;
    __shared__ float z[16];
    __shared__ float yv[192];
    for (int i = t; i < C; i += 256) yv[i] = pool[b * C + i] * (1.0f / HW);
    __syncthreads();
    if (t < R) {
        float a = b1[t];
        for (int i = 0; i < C; ++i) a = fmaf(w1[t * C + i], yv[i], a);
        z[t] = fmaxf(a, 0.f);
    }
    __syncthreads();
    if (t < C) {
        float a = b2[t];
        for (int j = 0; j < R; ++j) a = fmaf(w2[t * R + j], z[j], a);
        s[b * C + t] = 1.f / (1.f + __expf(-a));
    }
}

// ---------------- compose conv chains into per-batch weights:
// WfB = log2e * wf @ wg3 @ (wg2 . s_g); biasf = log2e*(wf@(wg3@bg2+bg3)+f_b)
// WgB = wg @ (wc2 . s_c);               biasg = wg@bc2 + g_b
__global__ __launch_bounds__(256) void k_wcombine(
    const float* __restrict__ wg2, const float* __restrict__ wg3,
    const float* __restrict__ wf, const float* __restrict__ bg2,
    const float* __restrict__ bg3, const float* __restrict__ fb,
    const float* __restrict__ wc2, const float* __restrict__ wg,
    const float* __restrict__ bc2, const float* __restrict__ gb,
    const float* __restrict__ s_g, const float* __restrict__ s_c,
    unsigned short* __restrict__ WfB, float* __restrict__ biasf,
    unsigned short* __restrict__ WgB, float* __restrict__ biasg)
{
    const float LOG2E = 1.4426950408889634f;
    int b = blockIdx.y, x = blockIdx.x, t = threadIdx.x;
    __shared__ float T1[64 * 96];
    const int i0 = x * 96;
    for (int idx = t; idx < 64 * 96; idx += 256) {
        int m = idx / 96, ii = idx - m * 96, i = i0 + ii;
        float a = 0.f;
        for (int k2 = 0; k2 < 64; ++k2) a = fmaf(wg3[m * 64 + k2], wg2[k2 * 192 + i], a);
        T1[m * 96 + ii] = a * s_g[b * 192 + i];
    }
    __syncthreads();
    for (int idx = t; idx < 64 * 96; idx += 256) {
        int o = idx / 96, ii = idx - o * 96;
        float a = 0.f;
        for (int m = 0; m < 64; ++m) a = fmaf(wf[o * 64 + m], T1[m * 96 + ii], a);
        WfB[(size_t)b * 12288 + o * 192 + i0 + ii] = f2bf(a * LOG2E);
    }
    const int j0 = x * 32;
    for (int idx = t; idx < 64 * 32; idx += 256) {
        int o = idx / 32, i = j0 + (idx & 31);
        float a = 0.f;
        for (int m = 0; m < 64; ++m) a = fmaf(wg[o * 64 + m], wc2[m * 64 + i] * s_c[b * 64 + i], a);
        WgB[(size_t)b * 4096 + o * 64 + i] = f2bf(a);
    }
    if (x == 0) {
        __shared__ float tb[64];
        if (t < 64) {
            float a = 0.f;
            for (int m = 0; m < 64; ++m) a = fmaf(wg3[t * 64 + m], bg2[m], a);
            tb[t] = a + bg3[t];
        }
        __syncthreads();
        if (t < 64) {
            float a = 0.f, g2 = 0.f;
            for (int m = 0; m < 64; ++m) {
                a  = fmaf(wf[t * 64 + m], tb[m], a);
                g2 = fmaf(wg[t * 64 + m], bc2[m], g2);
            }
            biasf[b * 64 + t] = (a + fb[t]) * LOG2E;
            biasg[b * 64 + t] = g2 + gb[t];
        }
    }
}

// ---------------- MFMA attention (round-8 proven config + exp2).
// Grid 256, 512 thr (8 waves), launch_bounds(512,2) -> VGPR 128 + AGPR accs, NO spill.
// b = (bid&7)>>1 XCD-pinned; each wave 512 k; in-block 8-way linear merge -> mean/sd.
__global__ __launch_bounds__(512, 2) void k_attn(
    const unsigned short* __restrict__ FqT, const unsigned short* __restrict__ GkT,
    const unsigned short* __restrict__ HvN,
    float* __restrict__ mb, float* __restrict__ sbuf)
{
    __shared__ __align__(16) char smem[65536];   // loop: P 8w*4KB | merge: 32KB + Lm 4KB
    const int t = threadIdx.x;
    const int bid = blockIdx.x;
    const int b = (bid & 7) >> 1;                         // XCD-pinned batch
    const int qbase = (((bid >> 3) << 1) | (bid & 1)) << 6;
    const int w = t >> 6, lane = t & 63;
    const int gid = lane >> 4, cid = lane & 15;
    const size_t CQ = (size_t)HW * 64;
    const unsigned short* fqt = FqT + (size_t)b * CQ;
    const unsigned short* gkt = GkT + (size_t)b * CQ;
    const unsigned short* hv  = HvN + (size_t)b * CQ;
    unsigned short* Pw = (unsigned short*)smem + w * 4096;   // [4qt][16q][64k] swizzled

    bf16x8 fqa[4][2];
    #pragma unroll
    for (int qt = 0; qt < 4; ++qt) {
        const unsigned short* fr = fqt + (size_t)(qbase + 16 * qt + cid) * 64 + 8 * gid;
        fqa[qt][0] = *(const bf16x8*)fr;
        fqa[qt][1] = *(const bf16x8*)(fr + 32);
    }
    bf16x8 ones;
    #pragma unroll
    for (int j = 0; j < 8; ++j) ones[j] = (short)0x3F80;

    const f32x4 fz = {0.f, 0.f, 0.f, 0.f};
    f32x4 am[4][4], a2[4][4], lac[4];
    #pragma unroll
    for (int qt = 0; qt < 4; ++qt) {
        lac[qt] = fz;
        #pragma unroll
        for (int n = 0; n < 4; ++n) { am[qt][n] = fz; a2[qt][n] = fz; }
    }

    const int k00 = w << 9;                      // 512 k per wave
    for (int it = 0; it < 8; ++it) {
        const int k0 = k00 + (it << 6);
        // ---- QK^T -> exp2 -> P (B-frags shared by 4 q-tiles; log2e pre-folded)
        #pragma unroll
        for (int n = 0; n < 4; ++n) {
            const unsigned short* gr = gkt + (size_t)(k0 + 16 * n + cid) * 64 + 8 * gid;
            bf16x8 b0 = *(const bf16x8*)gr;
            bf16x8 b1 = *(const bf16x8*)(gr + 32);
            const int k = 16 * n + cid;
            #pragma unroll
            for (int qt = 0; qt < 4; ++qt) {
                f32x4 s = __builtin_amdgcn_mfma_f32_16x16x32_bf16(fqa[qt][0], b0, fz, 0, 0, 0);
                s = __builtin_amdgcn_mfma_f32_16x16x32_bf16(fqa[qt][1], b1, s, 0, 0, 0);
                #pragma unroll
                for (int r = 0; r < 4; ++r) {
                    int q = 4 * gid + r;
                    Pw[qt * 1024 + q * 64 + (((k >> 3) ^ (q & 7)) << 3) + (k & 7)] =
                        f2bf(__builtin_amdgcn_exp2f(s[r]));
                }
            }
        }
        bf16x8 pa[4][2];
        #pragma unroll
        for (int qt = 0; qt < 4; ++qt)
            #pragma unroll
            for (int kh = 0; kh < 2; ++kh)
                pa[qt][kh] = *(const bf16x8*)(Pw + qt * 1024 + cid * 64 +
                                              (((4 * kh + gid) ^ (cid & 7)) << 3));
        // ---- l += P @ ones
        #pragma unroll
        for (int qt = 0; qt < 4; ++qt) {
            lac[qt] = __builtin_amdgcn_mfma_f32_16x16x32_bf16(pa[qt][0], ones, lac[qt], 0, 0, 0);
            lac[qt] = __builtin_amdgcn_mfma_f32_16x16x32_bf16(pa[qt][1], ones, lac[qt], 0, 0, 0);
        }
        // ---- PV: Hv frag loaded once, squared in-register, shared by 4 q-tiles
        #pragma unroll
        for (int n = 0; n < 4; ++n) {
            const unsigned short* hr = hv + (size_t)(16 * n + cid) * HW + k0;
            #pragma unroll
            for (int kh = 0; kh < 2; ++kh) {
                bf16x8 hb = *(const bf16x8*)(hr + 32 * kh + 8 * gid);
                bf16x8 h2;
                #pragma unroll
                for (int j = 0; j < 8; ++j) {
                    float v = bf2f((unsigned short)hb[j]);
                    h2[j] = (short)f2bf(v * v);
                }
                #pragma unroll
                for (int qt = 0; qt < 4; ++qt) {
                    am[qt][n] = __builtin_amdgcn_mfma_f32_16x16x32_bf16(pa[qt][kh], hb, am[qt][n], 0, 0, 0);
                    a2[qt][n] = __builtin_amdgcn_mfma_f32_16x16x32_bf16(pa[qt][kh], h2, a2[qt][n], 0, 0, 0);
                }
            }
        }
    }

    // ---- 8-way linear merge via LDS -> mean & sd
    __syncthreads();
    float* lb = (float*)smem;                    // [8w][4qt][64][4] = 32 KB
    #pragma unroll
    for (int qt = 0; qt < 4; ++qt)
        *(f32x4*)(lb + ((size_t)(w * 4 + qt) * 64 + lane) * 4) = lac[qt];
    __syncthreads();
    float* Lm = (float*)(smem + 32768);          // [4qt][64][4] = 4 KB
    if (t < 256) {
        int qt = t >> 6, ls = t & 63;
        f32x4 s = fz;
        #pragma unroll
        for (int ww = 0; ww < 8; ++ww)
            s += *(const f32x4*)(lb + ((size_t)(ww * 4 + qt) * 64 + ls) * 4);
        *(f32x4*)(Lm + ((size_t)qt * 64 + ls) * 4) = s;
    }
    __syncthreads();
    float* ab = (float*)smem;                    // [8w][4n][64][4] = 32 KB (Lm preserved)
    f32x4 meanv = fz;
    for (int qt = 0; qt < 4; ++qt) {
        #pragma unroll
        for (int n = 0; n < 4; ++n)
            *(f32x4*)(ab + ((size_t)(w * 4 + n) * 64 + lane) * 4) = am[qt][n];
        __syncthreads();
        if (t < 256) {
            int n = t >> 6, ls = t & 63;
            f32x4 s = fz;
            #pragma unroll
            for (int ww = 0; ww < 8; ++ww)
                s += *(const f32x4*)(ab + ((size_t)(ww * 4 + n) * 64 + ls) * 4);
            f32x4 lv = *(const f32x4*)(Lm + ((size_t)qt * 64 + ls) * 4);
            #pragma unroll
            for (int r = 0; r < 4; ++r) meanv[r] = s[r] / lv[r];
            int q0s = qbase + 16 * qt + 4 * (ls >> 4);
            int c   = 16 * n + (ls & 15);
            *(f32x4*)(mb + (size_t)b * CQ + (size_t)c * HW + q0s) = meanv;
        }
        __syncthreads();
        #pragma unroll
        for (int n = 0; n < 4; ++n)
            *(f32x4*)(ab + ((size_t)(w * 4 + n) * 64 + lane) * 4) = a2[qt][n];
        __syncthreads();
        if (t < 256) {
            int n = t >> 6, ls = t & 63;
            f32x4 s = fz;
            #pragma unroll
            for (int ww = 0; ww < 8; ++ww)
                s += *(const f32x4*)(ab + ((size_t)(ww * 4 + n) * 64 + ls) * 4);
            f32x4 lv = *(const f32x4*)(Lm + ((size_t)qt * 64 + ls) * 4);
            f32x4 sv;
            #pragma unroll
            for (int r = 0; r < 4; ++r) {
                float sec = s[r] / lv[r];
                sv[r] = sqrtf(fmaxf(sec - meanv[r] * meanv[r], 0.f));
            }
            int q0s = qbase + 16 * qt + 4 * (ls >> 4);
            int c   = 16 * n + (ls & 15);
            *(f32x4*)(sbuf + (size_t)b * CQ + (size_t)c * HW + q0s) = sv;
        }
        __syncthreads();
    }
}

// ---------------- fused: mvn stats + transfer + cbam channel pools
// one block per (b,c); FG row cached in LDS
__global__ __launch_bounds__(256) void k_transfer_f(
    const float* __restrict__ mb, const float* __restrict__ sb,
    const float* __restrict__ FG, const float* __restrict__ BG, int bstride,
    float* __restrict__ xb, float* __restrict__ pavg, float* __restrict__ pmaxb)
{
    __shared__ float fgl[4096];
    __shared__ float r1[4], r2[4];
    const int bc = blockIdx.x, t = threadIdx.x;
    const int b = bc >> 6, c = bc & 63;
    const size_t row = (size_t)bc * HW;
    const float* fg = FG + (size_t)b * bstride + (size_t)(64 + c) * HW;
    const float* bg = BG + (size_t)b * bstride + (size_t)(64 + c) * HW;
    float s = 0.f, s2 = 0.f;
    #pragma unroll
    for (int j = 0; j < 16; ++j) {
        int i = t + j * 256;
        float v = fg[i];
        fgl[i] = v;
        s += v; s2 += v * v;
    }
    #pragma unroll
    for (int o = 32; o > 0; o >>= 1) { s += __shfl_down(s, o, 64); s2 += __shfl_down(s2, o, 64); }
    if ((t & 63) == 0) { r1[t >> 6] = s; r2[t >> 6] = s2; }
    __syncthreads();
    float m  = (r1[0] + r1[1] + r1[2] + r1[3]) * (1.0f / HW);
    float e2 = (r2[0] + r2[1] + r2[2] + r2[3]) * (1.0f / HW);
    float rs = rsqrtf(fmaxf(e2 - m * m, 0.f) + 1e-5f);
    float psum = 0.f, pmax = -1e30f;
    #pragma unroll
    for (int j = 0; j < 16; ++j) {
        int q = t + j * 256;
        float xv = sb[row + q] * (fgl[q] - m) * rs + mb[row + q] + bg[q];
        xb[row + q] = xv;
        psum += xv; pmax = fmaxf(pmax, xv);
    }
    __syncthreads();
    #pragma unroll
    for (int o = 32; o > 0; o >>= 1) {
        psum += __shfl_down(psum, o, 64);
        pmax = fmaxf(pmax, __shfl_down(pmax, o, 64));
    }
    if ((t & 63) == 0) { r1[t >> 6] = psum; r2[t >> 6] = pmax; }
    __syncthreads();
    if (t == 0) {
        pavg[bc]  = (r1[0] + r1[1] + r1[2] + r1[3]) * (1.0f / HW);
        pmaxb[bc] = fmaxf(fmaxf(r2[0], r2[1]), fmaxf(r2[2], r2[3]));
    }
}

// ---------------- CBAM channel-scale (recomputed per block; trivial cost)
static __device__ __forceinline__ void cbam_scale(
    const float* __restrict__ pav, const float* __restrict__ pmx,
    const float* __restrict__ w1, const float* __restrict__ b1,
    const float* __restrict__ w2, const float* __restrict__ b2,
    int b, int t, float* scb)
{
    __shared__ float za[4], zm[4];
    if (t < 4) {
        float aa = b1[t], am = b1[t];
        for (int i = 0; i < 64; ++i) {
            aa = fmaf(w1[t * 64 + i], pav[b * 64 + i], aa);
            am = fmaf(w1[t * 64 + i], pmx[b * 64 + i], am);
        }
        za[t] = fmaxf(aa, 0.f);
        zm[t] = fmaxf(am, 0.f);
    }
    __syncthreads();
    if (t < 64) {
        float a = 2.f * b2[t];
        for (int j = 0; j < 4; ++j) a = fmaf(w2[t * 4 + j], za[j] + zm[j], a);
        scb[t] = 1.f / (1.f + __expf(-a));
    }
    __syncthreads();
}

// ---------------- spatial pool of (xb*s) with inlined cbam MLP
__global__ __launch_bounds__(256) void k_sp_pool(
    const float* __restrict__ xb,
    const float* __restrict__ pav, const float* __restrict__ pmx,
    const float* __restrict__ w1, const float* __restrict__ b1,
    const float* __restrict__ w2, const float* __restrict__ b2,
    float* __restrict__ spm, float* __restrict__ spx)
{
    __shared__ float scb[64];
    const int b = blockIdx.y, t = threadIdx.x;
    cbam_scale(pav, pmx, w1, b1, w2, b2, b, t, scb);
    const int p = blockIdx.x * 256 + t;
    const float* xp = xb + (size_t)b * 262144 + p;
    float sum = 0.f, mx = -1e30f;
    for (int c = 0; c < 64; ++c) {
        float v = xp[(size_t)c * HW] * scb[c];
        sum += v;
        mx = fmaxf(mx, v);
    }
    spm[b * HW + p] = sum * (1.0f / 64.0f);
    spx[b * HW + p] = mx;
}

// ---------------- fused 7x7 spatial conv + sigmoid + final output
__global__ __launch_bounds__(256) void k_spf(
    const float* __restrict__ spm, const float* __restrict__ spx,
    const float* __restrict__ w, const float* __restrict__ bias,
    const float* __restrict__ xb,
    const float* __restrict__ pav, const float* __restrict__ pmx,
    const float* __restrict__ w1, const float* __restrict__ b1,
    const float* __restrict__ w2, const float* __restrict__ b2,
    float* __restrict__ out)
{
    __shared__ float scb[64];
    const int b = blockIdx.y, t = threadIdx.x;
    cbam_scale(pav, pmx, w1, b1, w2, b2, b, t, scb);
    const int p = blockIdx.x * 256 + t;
    const int y = p >> 6, x = p & 63;
    float acc = bias[0];
    for (int dy = 0; dy < 7; ++dy) {
        int yy = y + dy - 3;
        if (yy < 0 || yy >= 64) continue;
        for (int dx = 0; dx < 7; ++dx) {
            int xx = x + dx - 3;
            if (xx < 0 || xx >= 64) continue;
            int q = b * HW + yy * 64 + xx;
            acc = fmaf(spm[q], w[dy * 7 + dx],      acc);
            acc = fmaf(spx[q], w[49 + dy * 7 + dx], acc);
        }
    }
    float sgm = 1.f / (1.f + __expf(-acc));
    const float* xp = xb + (size_t)b * 262144 + p;
    float* op = out + (size_t)b * 262144 + p;
    for (int c = 0; c < 64; ++c)
        op[(size_t)c * HW] = xp[(size_t)c * HW] * scb[c] * sgm;
}

extern "C" void kernel_launch(void* const* d_in, const int* in_sizes, int n_in,
                              void* d_out, int out_size, void* d_ws, size_t ws_size,
                              hipStream_t stream)
{
    const float* group  = (const float*)d_in[0];
    const float* FG     = (const float*)d_in[1];
    const float* BG     = (const float*)d_in[2];
    const float* wg1    = (const float*)d_in[3];
    const float* bg1    = (const float*)d_in[4];
    const float* cag_w1 = (const float*)d_in[5];
    const float* cag_b1 = (const float*)d_in[6];
    const float* cag_w2 = (const float*)d_in[7];
    const float* cag_b2 = (const float*)d_in[8];
    const float* wg2    = (const float*)d_in[9];
    const float* bg2    = (const float*)d_in[10];
    const float* wg3    = (const float*)d_in[11];
    const float* bg3    = (const float*)d_in[12];
    const float* wc1    = (const float*)d_in[13];
    const float* bc1    = (const float*)d_in[14];
    const float* cac_w1 = (const float*)d_in[15];
    const float* cac_b1 = (const float*)d_in[16];
    const float* cac_w2 = (const float*)d_in[17];
    const float* cac_b2 = (const float*)d_in[18];
    const float* wc2    = (const float*)d_in[19];
    const float* bc2    = (const float*)d_in[20];
    const float* f_w    = (const float*)d_in[21];
    const float* f_b    = (const float*)d_in[22];
    const float* g_w    = (const float*)d_in[23];
    const float* g_b    = (const float*)d_in[24];
    const float* h_w    = (const float*)d_in[25];
    const float* h_b    = (const float*)d_in[26];
    const float* mlp_w1 = (const float*)d_in[27];
    const float* mlp_b1 = (const float*)d_in[28];
    const float* mlp_w2 = (const float*)d_in[29];
    const float* mlp_b2 = (const float*)d_in[30];
    const float* sp_w   = (const float*)d_in[31];
    const float* sp_b   = (const float*)d_in[32];
    float* out = (float*)d_out;

    const int B = 4;
    const size_t CHW = (size_t)64 * HW;
    const int BST = (int)(3 * CHW);

    float* ws = (float*)d_ws;
    const size_t M = 1048576;
    // bf16 tiles:
    unsigned short* X0T  = (unsigned short*)ws;                 // [0,1.5M)f; dead before attn
    unsigned short* g1T  = (unsigned short*)(ws + 3 * M / 2);   // [1.5M,3M); dead before attn
    unsigned short* c1T  = (unsigned short*)(ws + 3 * M);       // [3M,3.5M); dead before attn
    unsigned short* BGcT = (unsigned short*)(ws + 7 * M / 2);   // [3.5M,4M); dead before attn
    unsigned short* FqT  = (unsigned short*)(ws + 4 * M);       // [4M,4.5M)
    unsigned short* GkT  = (unsigned short*)(ws + 9 * M / 2);   // [4.5M,5M)
    unsigned short* hvN  = (unsigned short*)(ws + 5 * M);       // [5M,5.5M)
    // attn outputs + xb (over regions dead by then):
    float* mbuf = ws;                // [0,1M)   over X0T
    float* sbuf = ws + M;            // [1M,2M)  over X0T/g1T
    float* xb   = ws + 2 * M;        // [2M,3M)  over g1T
    // smalls
    float* smalls = ws + 11 * M / 2;     // after hvN
    float* pool_g = smalls;            // 768
    float* pool_c = smalls + 768;      // 256 (contiguous with pool_g for zeroing)
    float* s_g    = smalls + 1024;     // 768
    float* s_c    = smalls + 1792;     // 256
    float* pav    = smalls + 2048;     // 256
    float* pmx    = smalls + 2304;     // 256
    float* biasf  = smalls + 2560;     // 256
    float* biasg  = smalls + 2816;     // 256
    float* spm    = smalls + 3072;     // 16384
    float* spx    = smalls + 19456;    // 16384
    unsigned short* wreg = (unsigned short*)(smalls + 35840);
    unsigned short* wg1b = wreg;                    // 36864
    unsigned short* wc1b = wreg + 36864;            // 4096
    unsigned short* whb  = wreg + 40960;            // 4096
    unsigned short* WfB  = wreg + 45056;            // 4*64*192 = 49152
    unsigned short* WgB  = wreg + 94208;            // 4*4096 = 16384

    unsigned short* nil = (unsigned short*)nullptr;
    dim3 blk(256);

    // input transposes + static weights + pool zero-init
    k_transpose2<<<dim3(64, B, 2), blk, 192 * 65 * 4, stream>>>(group, BG + CHW, BST, X0T, BGcT);
    k_wprep<<<177, blk, 0, stream>>>(wg1, wc1, h_w, wreg, pool_g);
    // g1 (192->192) + pool ; c1 (64->64) + pool
    k_gconv<<<dim3(64, 3, B), blk, 0, stream>>>(X0T, 192, 0, HW * 192, wg1b, 0, bg1, 0, g1T, 192, nil, pool_g, 192, 192);
    k_gconv<<<dim3(64, 1, B), blk, 0, stream>>>(X0T, 192, 64, HW * 192, wc1b, 0, bc1, 0, c1T, 64, nil, pool_c, 64, 64);
    // CA scales + weight composition
    k_ca_mlp2<<<dim3(2, B), blk, 0, stream>>>(pool_g, cag_w1, cag_b1, cag_w2, cag_b2, s_g,
                                              pool_c, cac_w1, cac_b1, cac_w2, cac_b2, s_c);
    k_wcombine<<<dim3(2, B), blk, 0, stream>>>(wg2, wg3, f_w, bg2, bg3, f_b,
                                               wc2, g_w, bc2, g_b, s_g, s_c,
                                               WfB, biasf, WgB, biasg);
    // projections (composed convs)
    k_gconv<<<dim3(64, 1, B), blk, 0, stream>>>(g1T, 192, 0, HW * 192, WfB, 12288, biasf, 64, FqT, 64, nil, nullptr, 192, 64);
    k_gconv<<<dim3(64, 1, B), blk, 0, stream>>>(c1T, 64, 0, HW * 64, WgB, 4096, biasg, 64, GkT, 64, nil, nullptr, 64, 64);
    k_gconv<<<dim3(64, 1, B), blk, 0, stream>>>(BGcT, 64, 0, HW * 64, whb, 0, h_b, 0, nil, 64, hvN, nullptr, 64, 64);
    // attention (round-8 config: grid 256, 8 waves, no spill)
    k_attn<<<256, 512, 0, stream>>>(FqT, GkT, hvN, mbuf, sbuf);
    // fused mvn + transfer + cbam pools
    k_transfer_f<<<B * 64, blk, 0, stream>>>(mbuf, sbuf, FG, BG, BST, xb, pav, pmx);
    // CBAM spatial
    k_sp_pool<<<dim3(HW / 256, B), blk, 0, stream>>>(xb, pav, pmx, mlp_w1, mlp_b1, mlp_w2, mlp_b2, spm, spx);
    k_spf<<<dim3(HW / 256, B), blk, 0, stream>>>(spm, spx, sp_w, sp_b, xb, pav, pmx, mlp_w1, mlp_b1, mlp_w2, mlp_b2, out);
}

// Round 12
// 205.505 us; speedup vs baseline: 1.9623x; 1.1932x over previous
//
#include <hip/hip_runtime.h>
#include <hip/hip_bf16.h>
#include <math.h>

#define HW 4096

typedef __attribute__((ext_vector_type(8))) short bf16x8;
typedef __attribute__((ext_vector_type(4))) float f32x4;

static __device__ __forceinline__ unsigned short f2bf(float x) {
    unsigned u = __float_as_uint(x);
    u += 0x7fffu + ((u >> 16) & 1u);     // RNE
    return (unsigned short)(u >> 16);
}
static __device__ __forceinline__ float bf2f(unsigned short h) {
    return __uint_as_float((unsigned)h << 16);
}

// ---------------- combined transpose+bf16: z=0: group(192ch)->X0T; z=1: BGc(64ch)->BGcT
__global__ __launch_bounds__(256) void k_transpose2(
    const float* __restrict__ group, const float* __restrict__ BGc, int bstride,
    unsigned short* __restrict__ X0T, unsigned short* __restrict__ BGcT)
{
    extern __shared__ float lds[];          // [C][65]
    const int b = blockIdx.y, p0 = blockIdx.x << 6, t = threadIdx.x;
    const int z = blockIdx.z;
    const int C = z ? 64 : 192;
    const float* xb = (z ? BGc : group) + (size_t)b * bstride;
    unsigned short* outT = z ? BGcT : X0T;
    for (int idx = t; idx < (C << 6); idx += 256) {
        int c = idx >> 6, p = idx & 63;
        lds[c * 65 + p] = xb[(size_t)c * HW + p0 + p];
    }
    __syncthreads();
    unsigned short* ob = outT + ((size_t)b * HW + p0) * C;
    for (int idx = t; idx < (C << 6); idx += 256) {
        int p = idx / C, c = idx - p * C;
        ob[idx] = f2bf(lds[c * 65 + p]);
    }
}

// ---------------- static weight prep (wg1, wc1, wh) + zero pool accumulators
__global__ __launch_bounds__(256) void k_wprep(
    const float* __restrict__ w1, const float* __restrict__ wc1,
    const float* __restrict__ wh,
    unsigned short* __restrict__ o, float* __restrict__ poolz)
{
    int bid = blockIdx.x, t = threadIdx.x;
    if (bid < 144) {
        int i = bid * 256 + t;
        o[i] = f2bf(w1[i]);
    } else if (bid < 160) {
        int i = ((bid - 144) << 8) + t;
        o[36864 + i] = f2bf(wc1[i]);
    } else if (bid < 176) {
        int i = ((bid - 160) << 8) + t;
        o[40960 + i] = f2bf(wh[i]);
    } else {
        #pragma unroll
        for (int j = 0; j < 4; ++j) poolz[t + j * 256] = 0.f;   // pool_g(768)+pool_c(256)
    }
}

// ---------------- batch-INDEPENDENT weight chain (LDS-staged):
// W3L = log2e*(wf@wg3@wg2) [64x192]; biasfL = log2e*(wf@(wg3@bg2+bg3)+f_b)
// Wgc = wg@wc2 [64x64];              biasg = wg@bc2 + g_b
// grid 4: block x computes W3L cols [48x,48x+48); block 0 also Wgc/biases.
__global__ __launch_bounds__(256) void k_wchain(
    const float* __restrict__ wf, const float* __restrict__ wg3,
    const float* __restrict__ wg2,
    const float* __restrict__ bg2, const float* __restrict__ bg3,
    const float* __restrict__ fb,
    const float* __restrict__ wgw, const float* __restrict__ wc2,
    const float* __restrict__ bc2, const float* __restrict__ gbv,
    float* __restrict__ W3L, float* __restrict__ biasfL,
    float* __restrict__ Wgc, float* __restrict__ biasgv)
{
    const float LOG2E = 1.4426950408889634f;
    __shared__ float sA[4096], sB[4096], T2[4096], tb[64];
    const int x = blockIdx.x, t = threadIdx.x;
    #pragma unroll
    for (int j = 0; j < 16; ++j) {
        sA[t + j * 256] = wf[t + j * 256];
        sB[t + j * 256] = wg3[t + j * 256];
    }
    __syncthreads();
    // T2 = wf @ wg3
    #pragma unroll
    for (int j = 0; j < 16; ++j) {
        int idx = t + j * 256, o = idx >> 6, k = idx & 63;
        float a = 0.f;
        for (int m = 0; m < 64; ++m) a = fmaf(sA[(o << 6) + m], sB[(m << 6) + k], a);
        T2[idx] = a;
    }
    if (x == 0 && t < 64) {
        float a = 0.f;
        for (int k = 0; k < 64; ++k) a = fmaf(sB[(t << 6) + k], bg2[k], a);
        tb[t] = a + bg3[t];
    }
    __syncthreads();
    if (x == 0 && t < 64) {
        float a = 0.f;
        for (int m = 0; m < 64; ++m) a = fmaf(sA[(t << 6) + m], tb[m], a);
        biasfL[t] = (a + fb[t]) * LOG2E;
    }
    __syncthreads();                         // sA/sB free
    // stage wg2 slice (cols [48x, 48x+48))
    const int i0 = x * 48;
    for (int idx = t; idx < 64 * 48; idx += 256) {
        int k = idx / 48, ii = idx - k * 48;
        sA[idx] = wg2[k * 192 + i0 + ii];
    }
    __syncthreads();
    for (int idx = t; idx < 64 * 48; idx += 256) {
        int o = idx / 48, ii = idx - o * 48;
        float a = 0.f;
        for (int k = 0; k < 64; ++k) a = fmaf(T2[(o << 6) + k], sA[k * 48 + ii], a);
        W3L[o * 192 + i0 + ii] = a * LOG2E;
    }
    if (x == 0) {
        __syncthreads();
        #pragma unroll
        for (int j = 0; j < 16; ++j) {
            sB[t + j * 256] = wgw[t + j * 256];
            T2[t + j * 256] = wc2[t + j * 256];
        }
        __syncthreads();
        #pragma unroll
        for (int j = 0; j < 16; ++j) {
            int idx = t + j * 256, o = idx >> 6, i = idx & 63;
            float a = 0.f;
            for (int m = 0; m < 64; ++m) a = fmaf(sB[(o << 6) + m], T2[(m << 6) + i], a);
            Wgc[idx] = a;
        }
        if (t < 64) {
            float a = 0.f;
            for (int m = 0; m < 64; ++m) a = fmaf(sB[(t << 6) + m], bc2[m], a);
            biasgv[t] = a + gbv[t];
        }
    }
}

// ---------------- per-batch column scale + bf16: WfB=W3L.*s_g, WgB=Wgc.*s_c
__global__ __launch_bounds__(256) void k_wscale(
    const float* __restrict__ W3L, const float* __restrict__ Wgc,
    const float* __restrict__ s_g, const float* __restrict__ s_c,
    unsigned short* __restrict__ WfB, unsigned short* __restrict__ WgB)
{
    int i = blockIdx.x * 256 + threadIdx.x;      // grid 256 -> [0,65536)
    int b = i >> 14;
    int r = i & 16383;
    if (r < 12288) {
        int col = r % 192;
        WfB[(size_t)b * 12288 + r] = f2bf(W3L[r] * s_g[b * 192 + col]);
    } else {
        int r2 = r - 12288;
        int col = r2 & 63;
        WgB[(size_t)b * 4096 + r2] = f2bf(Wgc[r2] * s_c[b * 64 + col]);
    }
}

// ---------------- MFMA GEMM conv1x1 (+ optional channel-pool atomics epilogue)
__global__ __launch_bounds__(256) void k_gconv(
    const unsigned short* __restrict__ XT, int ldx, int kOff, int xbstride,
    const unsigned short* __restrict__ W, int wbstride,
    const float* __restrict__ bias, int bias_bstride,
    unsigned short* __restrict__ yT, int ldyT,
    unsigned short* __restrict__ yN,
    float* __restrict__ pool,
    int Cin, int Cout)
{
    const int t = threadIdx.x;
    const int w = t >> 6, lane = t & 63;
    const int gid = lane >> 4, cid = lane & 15;
    const int b = blockIdx.z;
    const int p0 = blockIdx.x << 6;
    const int co16 = ((blockIdx.y << 2) + w) << 4;
    const unsigned short* xrow = XT + (size_t)b * xbstride + kOff;
    const unsigned short* wr = W + (size_t)b * wbstride + (size_t)co16 * Cin;
    const float* br = bias + b * bias_bstride;
    f32x4 acc[4];
    #pragma unroll
    for (int n = 0; n < 4; ++n)
        #pragma unroll
        for (int r = 0; r < 4; ++r)
            acc[n][r] = br[co16 + 4 * gid + r];
    for (int kc = 0; kc < Cin; kc += 32) {
        bf16x8 a = *(const bf16x8*)(wr + (size_t)cid * Cin + kc + 8 * gid);
        #pragma unroll
        for (int n = 0; n < 4; ++n) {
            const unsigned short* xp = xrow + (size_t)(p0 + 16 * n + cid) * ldx + kc + 8 * gid;
            bf16x8 bfr = *(const bf16x8*)xp;
            acc[n] = __builtin_amdgcn_mfma_f32_16x16x32_bf16(a, bfr, acc[n], 0, 0, 0);
        }
    }
    #pragma unroll
    for (int n = 0; n < 4; ++n)
        #pragma unroll
        for (int r = 0; r < 4; ++r) {
            float v = acc[n][r];
            int co = co16 + 4 * gid + r;
            int p  = p0 + 16 * n + cid;
            if (yT) yT[((size_t)b * HW + p) * ldyT + co] = f2bf(v);
            if (yN) yN[((size_t)b * Cout + co) * HW + p] = f2bf(v);
        }
    if (pool) {
        float ps[4];
        #pragma unroll
        for (int r = 0; r < 4; ++r) {
            ps[r] = acc[0][r] + acc[1][r] + acc[2][r] + acc[3][r];
            #pragma unroll
            for (int o = 8; o > 0; o >>= 1)
                ps[r] += __shfl_xor(ps[r], o, 64);
        }
        if (cid == 0) {
            #pragma unroll
            for (int r = 0; r < 4; ++r)
                atomicAdd(&pool[b * Cout + co16 + 4 * gid + r], ps[r]);
        }
    }
}

// ---------------- both CA MLPs (x: 0=group C=192 R=12, 1=center C=64 R=4)
__global__ __launch_bounds__(256) void k_ca_mlp2(
    const float* __restrict__ pool_g,
    const float* __restrict__ gw1, const float* __restrict__ gb1,
    const float* __restrict__ gw2, const float* __restrict__ gb2,
    float* __restrict__ s_g,
    const float* __restrict__ pool_c,
    const float* __restrict__ cw1, const float* __restrict__ cb1,
    const float* __restrict__ cw2, const float* __restrict__ cb2,
    float* __restrict__ s_c)
{
    int which = blockIdx.x, b = blockIdx.y, t = threadIdx.x;
    const float* pool = which ? pool_c : pool_g;
    const float* w1 = which ? cw1 : gw1;
    const float* b1 = which ? cb1 : gb1;
    const float* w2 = which ? cw2 : gw2;
    const float* b2 = which ? cb2 : gb2;
    float* s = which ? s_c : s_g;
    const int C = which ? 64 : 192;
    const int R = which ? 4 : 12;
    __shared__ float z[16];
    __shared__ float yv[192];
    for (int i = t; i < C; i += 256) yv[i] = pool[b * C + i] * (1.0f / HW);
    __syncthreads();
    if (t < R) {
        float a = b1[t];
        for (int i = 0; i < C; ++i) a = fmaf(w1[t * C + i], yv[i], a);
        z[t] = fmaxf(a, 0.f);
    }
    __syncthreads();
    if (t < C) {
        float a = b2[t];
        for (int j = 0; j < R; ++j) a = fmaf(w2[t * R + j], z[j], a);
        s[b * C + t] = 1.f / (1.f + __expf(-a));
    }
}

// ---------------- MFMA attention, no-max softmax (exp2; log2e pre-folded into WfB).
// Grid 512: kb=bid&1 (k-half), b=(bid&7)>>1 (XCD-pinned), qbase=(bid>>3)*64.
// launch_bounds(512,2) -> VGPR 128 (proven no-spill), 2 blocks/CU = 16 waves/CU.
// 8 waves x 256 k each. Writes LINEAR partial sums am/a2/l per k-half.
__global__ __launch_bounds__(512, 2) void k_attn(
    const unsigned short* __restrict__ FqT, const unsigned short* __restrict__ GkT,
    const unsigned short* __restrict__ HvN,
    float* __restrict__ amP0, float* __restrict__ amP1,
    float* __restrict__ a2P0, float* __restrict__ a2P1,
    float* __restrict__ lP)
{
    __shared__ __align__(16) char smem[32768];   // P 8w*4KB; merge scratch overlaid
    const int t = threadIdx.x;
    const int bid = blockIdx.x;
    const int kb = bid & 1;
    const int b  = (bid & 7) >> 1;
    const int qbase = (bid >> 3) << 6;
    const int w = t >> 6, lane = t & 63;
    const int gid = lane >> 4, cid = lane & 15;
    const size_t CQ = (size_t)HW * 64;
    const unsigned short* fqt = FqT + (size_t)b * CQ;
    const unsigned short* gkt = GkT + (size_t)b * CQ;
    const unsigned short* hv  = HvN + (size_t)b * CQ;
    float* amp = kb ? amP1 : amP0;
    float* a2p = kb ? a2P1 : a2P0;
    float* lp  = lP + kb * 16384 + b * 4096;
    unsigned short* Pw = (unsigned short*)smem + w * 2048;   // 4KB/wave

    bf16x8 fqa[4][2];
    #pragma unroll
    for (int qt = 0; qt < 4; ++qt) {
        const unsigned short* fr = fqt + (size_t)(qbase + 16 * qt + cid) * 64 + 8 * gid;
        fqa[qt][0] = *(const bf16x8*)fr;
        fqa[qt][1] = *(const bf16x8*)(fr + 32);
    }
    bf16x8 ones;
    #pragma unroll
    for (int j = 0; j < 8; ++j) ones[j] = (short)0x3F80;

    const f32x4 fz = {0.f, 0.f, 0.f, 0.f};
    f32x4 am[4][4], a2[4][4], lac[4];
    #pragma unroll
    for (int qt = 0; qt < 4; ++qt) {
        lac[qt] = fz;
        #pragma unroll
        for (int n = 0; n < 4; ++n) { am[qt][n] = fz; a2[qt][n] = fz; }
    }

    const int k00 = (kb << 11) + (w << 8);       // 256 k per wave
    for (int it = 0; it < 4; ++it) {
        const int k0 = k00 + (it << 6);
        #pragma unroll
        for (int n = 0; n < 4; ++n) {
            const unsigned short* gr = gkt + (size_t)(k0 + 16 * n + cid) * 64 + 8 * gid;
            bf16x8 b0 = *(const bf16x8*)gr;
            bf16x8 b1 = *(const bf16x8*)(gr + 32);
            const int k = 16 * n + cid;
            #pragma unroll
            for (int qt = 0; qt < 4; ++qt) {
                f32x4 s = __builtin_amdgcn_mfma_f32_16x16x32_bf16(fqa[qt][0], b0, fz, 0, 0, 0);
                s = __builtin_amdgcn_mfma_f32_16x16x32_bf16(fqa[qt][1], b1, s, 0, 0, 0);
                #pragma unroll
                for (int r = 0; r < 4; ++r) {
                    int q = 4 * gid + r;
                    Pw[qt * 1024 + q * 64 + (((k >> 3) ^ (q & 7)) << 3) + (k & 7)] =
                        f2bf(__builtin_amdgcn_exp2f(s[r]));
                }
            }
        }
        bf16x8 pa[4][2];
        #pragma unroll
        for (int qt = 0; qt < 4; ++qt)
            #pragma unroll
            for (int kh = 0; kh < 2; ++kh)
                pa[qt][kh] = *(const bf16x8*)(Pw + qt * 1024 + cid * 64 +
                                              (((4 * kh + gid) ^ (cid & 7)) << 3));
        #pragma unroll
        for (int qt = 0; qt < 4; ++qt) {
            lac[qt] = __builtin_amdgcn_mfma_f32_16x16x32_bf16(pa[qt][0], ones, lac[qt], 0, 0, 0);
            lac[qt] = __builtin_amdgcn_mfma_f32_16x16x32_bf16(pa[qt][1], ones, lac[qt], 0, 0, 0);
        }
        #pragma unroll
        for (int n = 0; n < 4; ++n) {
            const unsigned short* hr = hv + (size_t)(16 * n + cid) * HW + k0;
            #pragma unroll
            for (int kh = 0; kh < 2; ++kh) {
                bf16x8 hb = *(const bf16x8*)(hr + 32 * kh + 8 * gid);
                bf16x8 h2;
                #pragma unroll
                for (int j = 0; j < 8; ++j) {
                    float v = bf2f((unsigned short)hb[j]);
                    h2[j] = (short)f2bf(v * v);
                }
                #pragma unroll
                for (int qt = 0; qt < 4; ++qt) {
                    am[qt][n] = __builtin_amdgcn_mfma_f32_16x16x32_bf16(pa[qt][kh], hb, am[qt][n], 0, 0, 0);
                    a2[qt][n] = __builtin_amdgcn_mfma_f32_16x16x32_bf16(pa[qt][kh], h2, a2[qt][n], 0, 0, 0);
                }
            }
        }
    }

    // ---- 8-way linear in-block merge -> write raw partial sums
    __syncthreads();
    float* lb = (float*)smem;                    // [8w][4qt][64][4] = 32 KB
    #pragma unroll
    for (int qt = 0; qt < 4; ++qt)
        *(f32x4*)(lb + ((size_t)(w * 4 + qt) * 64 + lane) * 4) = lac[qt];
    __syncthreads();
    if (t < 256) {
        int qt = t >> 6, ls = t & 63;
        f32x4 s = fz;
        #pragma unroll
        for (int ww = 0; ww < 8; ++ww)
            s += *(const f32x4*)(lb + ((size_t)(ww * 4 + qt) * 64 + ls) * 4);
        if ((ls & 15) == 0)
            *(f32x4*)(lp + qbase + qt * 16 + (ls >> 4) * 4) = s;
    }
    __syncthreads();
    float* ab = (float*)smem;
    for (int qt = 0; qt < 4; ++qt) {
        #pragma unroll
        for (int n = 0; n < 4; ++n)
            *(f32x4*)(ab + ((size_t)(w * 4 + n) * 64 + lane) * 4) = am[qt][n];
        __syncthreads();
        if (t < 256) {
            int n = t >> 6, ls = t & 63;
            f32x4 s = fz;
            #pragma unroll
            for (int ww = 0; ww < 8; ++ww)
                s += *(const f32x4*)(ab + ((size_t)(ww * 4 + n) * 64 + ls) * 4);
            int q0s = qbase + 16 * qt + 4 * (ls >> 4);
            int c   = 16 * n + (ls & 15);
            *(f32x4*)(amp + ((size_t)(b * 64 + c)) * HW + q0s) = s;
        }
        __syncthreads();
        #pragma unroll
        for (int n = 0; n < 4; ++n)
            *(f32x4*)(ab + ((size_t)(w * 4 + n) * 64 + lane) * 4) = a2[qt][n];
        __syncthreads();
        if (t < 256) {
            int n = t >> 6, ls = t & 63;
            f32x4 s = fz;
            #pragma unroll
            for (int ww = 0; ww < 8; ++ww)
                s += *(const f32x4*)(ab + ((size_t)(ww * 4 + n) * 64 + ls) * 4);
            int q0s = qbase + 16 * qt + 4 * (ls >> 4);
            int c   = 16 * n + (ls & 15);
            *(f32x4*)(a2p + ((size_t)(b * 64 + c)) * HW + q0s) = s;
        }
        __syncthreads();
    }
}

// ---------------- fused: attn finalize + mvn stats + transfer + cbam channel pools
__global__ __launch_bounds__(256) void k_transfer_f(
    const float* __restrict__ am0, const float* __restrict__ am1,
    const float* __restrict__ a20, const float* __restrict__ a21,
    const float* __restrict__ lP,
    const float* __restrict__ FG, const float* __restrict__ BG, int bstride,
    float* __restrict__ xb, float* __restrict__ pavg, float* __restrict__ pmaxb)
{
    __shared__ float fgl[4096];
    __shared__ float r1[4], r2[4];
    const int bc = blockIdx.x, t = threadIdx.x;
    const int b = bc >> 6, c = bc & 63;
    const size_t row = (size_t)bc * HW;
    const float* fg = FG + (size_t)b * bstride + (size_t)(64 + c) * HW;
    const float* bg = BG + (size_t)b * bstride + (size_t)(64 + c) * HW;
    float s = 0.f, s2 = 0.f;
    #pragma unroll
    for (int j = 0; j < 16; ++j) {
        int i = t + j * 256;
        float v = fg[i];
        fgl[i] = v;
        s += v; s2 += v * v;
    }
    #pragma unroll
    for (int o = 32; o > 0; o >>= 1) { s += __shfl_down(s, o, 64); s2 += __shfl_down(s2, o, 64); }
    if ((t & 63) == 0) { r1[t >> 6] = s; r2[t >> 6] = s2; }
    __syncthreads();
    float m  = (r1[0] + r1[1] + r1[2] + r1[3]) * (1.0f / HW);
    float e2 = (r2[0] + r2[1] + r2[2] + r2[3]) * (1.0f / HW);
    float rs = rsqrtf(fmaxf(e2 - m * m, 0.f) + 1e-5f);
    const float* l0 = lP + (size_t)b * 4096;
    const float* l1 = lP + 16384 + (size_t)b * 4096;
    float psum = 0.f, pmax = -1e30f;
    #pragma unroll
    for (int j = 0; j < 16; ++j) {
        int q = t + j * 256;
        float linv = 1.f / (l0[q] + l1[q]);
        float mean = (am0[row + q] + am1[row + q]) * linv;
        float sec  = (a20[row + q] + a21[row + q]) * linv;
        float sd = sqrtf(fmaxf(sec - mean * mean, 0.f));
        float xv = sd * (fgl[q] - m) * rs + mean + bg[q];
        xb[row + q] = xv;
        psum += xv; pmax = fmaxf(pmax, xv);
    }
    __syncthreads();
    #pragma unroll
    for (int o = 32; o > 0; o >>= 1) {
        psum += __shfl_down(psum, o, 64);
        pmax = fmaxf(pmax, __shfl_down(pmax, o, 64));
    }
    if ((t & 63) == 0) { r1[t >> 6] = psum; r2[t >> 6] = pmax; }
    __syncthreads();
    if (t == 0) {
        pavg[bc]  = (r1[0] + r1[1] + r1[2] + r1[3]) * (1.0f / HW);
        pmaxb[bc] = fmaxf(fmaxf(r2[0], r2[1]), fmaxf(r2[2], r2[3]));
    }
}

// ---------------- CBAM channel-scale (recomputed per block; trivial cost)
static __device__ __forceinline__ void cbam_scale(
    const float* __restrict__ pav, const float* __restrict__ pmx,
    const float* __restrict__ w1, const float* __restrict__ b1,
    const float* __restrict__ w2, const float* __restrict__ b2,
    int b, int t, float* scb)
{
    __shared__ float za[4], zm[4];
    if (t < 4) {
        float aa = b1[t], am = b1[t];
        for (int i = 0; i < 64; ++i) {
            aa = fmaf(w1[t * 64 + i], pav[b * 64 + i], aa);
            am = fmaf(w1[t * 64 + i], pmx[b * 64 + i], am);
        }
        za[t] = fmaxf(aa, 0.f);
        zm[t] = fmaxf(am, 0.f);
    }
    __syncthreads();
    if (t < 64) {
        float a = 2.f * b2[t];
        for (int j = 0; j < 4; ++j) a = fmaf(w2[t * 4 + j], za[j] + zm[j], a);
        scb[t] = 1.f / (1.f + __expf(-a));
    }
    __syncthreads();
}

// ---------------- spatial pool of (xb*s) with inlined cbam MLP
__global__ __launch_bounds__(256) void k_sp_pool(
    const float* __restrict__ xb,
    const float* __restrict__ pav, const float* __restrict__ pmx,
    const float* __restrict__ w1, const float* __restrict__ b1,
    const float* __restrict__ w2, const float* __restrict__ b2,
    float* __restrict__ spm, float* __restrict__ spx)
{
    __shared__ float scb[64];
    const int b = blockIdx.y, t = threadIdx.x;
    cbam_scale(pav, pmx, w1, b1, w2, b2, b, t, scb);
    const int p = blockIdx.x * 256 + t;
    const float* xp = xb + (size_t)b * 262144 + p;
    float sum = 0.f, mx = -1e30f;
    for (int c = 0; c < 64; ++c) {
        float v = xp[(size_t)c * HW] * scb[c];
        sum += v;
        mx = fmaxf(mx, v);
    }
    spm[b * HW + p] = sum * (1.0f / 64.0f);
    spx[b * HW + p] = mx;
}

// ---------------- fused 7x7 spatial conv + sigmoid + final output
__global__ __launch_bounds__(256) void k_spf(
    const float* __restrict__ spm, const float* __restrict__ spx,
    const float* __restrict__ w, const float* __restrict__ bias,
    const float* __restrict__ xb,
    const float* __restrict__ pav, const float* __restrict__ pmx,
    const float* __restrict__ w1, const float* __restrict__ b1,
    const float* __restrict__ w2, const float* __restrict__ b2,
    float* __restrict__ out)
{
    __shared__ float scb[64];
    const int b = blockIdx.y, t = threadIdx.x;
    cbam_scale(pav, pmx, w1, b1, w2, b2, b, t, scb);
    const int p = blockIdx.x * 256 + t;
    const int y = p >> 6, x = p & 63;
    float acc = bias[0];
    for (int dy = 0; dy < 7; ++dy) {
        int yy = y + dy - 3;
        if (yy < 0 || yy >= 64) continue;
        for (int dx = 0; dx < 7; ++dx) {
            int xx = x + dx - 3;
            if (xx < 0 || xx >= 64) continue;
            int q = b * HW + yy * 64 + xx;
            acc = fmaf(spm[q], w[dy * 7 + dx],      acc);
            acc = fmaf(spx[q], w[49 + dy * 7 + dx], acc);
        }
    }
    float sgm = 1.f / (1.f + __expf(-acc));
    const float* xp = xb + (size_t)b * 262144 + p;
    float* op = out + (size_t)b * 262144 + p;
    for (int c = 0; c < 64; ++c)
        op[(size_t)c * HW] = xp[(size_t)c * HW] * scb[c] * sgm;
}

extern "C" void kernel_launch(void* const* d_in, const int* in_sizes, int n_in,
                              void* d_out, int out_size, void* d_ws, size_t ws_size,
                              hipStream_t stream)
{
    const float* group  = (const float*)d_in[0];
    const float* FG     = (const float*)d_in[1];
    const float* BG     = (const float*)d_in[2];
    const float* wg1    = (const float*)d_in[3];
    const float* bg1    = (const float*)d_in[4];
    const float* cag_w1 = (const float*)d_in[5];
    const float* cag_b1 = (const float*)d_in[6];
    const float* cag_w2 = (const float*)d_in[7];
    const float* cag_b2 = (const float*)d_in[8];
    const float* wg2    = (const float*)d_in[9];
    const float* bg2    = (const float*)d_in[10];
    const float* wg3    = (const float*)d_in[11];
    const float* bg3    = (const float*)d_in[12];
    const float* wc1    = (const float*)d_in[13];
    const float* bc1    = (const float*)d_in[14];
    const float* cac_w1 = (const float*)d_in[15];
    const float* cac_b1 = (const float*)d_in[16];
    const float* cac_w2 = (const float*)d_in[17];
    const float* cac_b2 = (const float*)d_in[18];
    const float* wc2    = (const float*)d_in[19];
    const float* bc2    = (const float*)d_in[20];
    const float* f_w    = (const float*)d_in[21];
    const float* f_b    = (const float*)d_in[22];
    const float* g_w    = (const float*)d_in[23];
    const float* g_b    = (const float*)d_in[24];
    const float* h_w    = (const float*)d_in[25];
    const float* h_b    = (const float*)d_in[26];
    const float* mlp_w1 = (const float*)d_in[27];
    const float* mlp_b1 = (const float*)d_in[28];
    const float* mlp_w2 = (const float*)d_in[29];
    const float* mlp_b2 = (const float*)d_in[30];
    const float* sp_w   = (const float*)d_in[31];
    const float* sp_b   = (const float*)d_in[32];
    float* out = (float*)d_out;

    const int B = 4;
    const size_t CHW = (size_t)64 * HW;
    const int BST = (int)(3 * CHW);

    float* ws = (float*)d_ws;
    const size_t M = 1048576;
    // bf16 tiles:
    unsigned short* X0T  = (unsigned short*)ws;                 // [0,1.5M)f
    unsigned short* g1T  = (unsigned short*)(ws + 3 * M / 2);   // [1.5M,3M)
    unsigned short* c1T  = (unsigned short*)(ws + 3 * M);       // [3M,3.5M)
    unsigned short* BGcT = (unsigned short*)(ws + 7 * M / 2);   // [3.5M,4M)
    unsigned short* FqT  = (unsigned short*)(ws + 4 * M);       // [4M,4.5M)
    unsigned short* GkT  = (unsigned short*)(ws + 9 * M / 2);   // [4.5M,5M)
    unsigned short* hvN  = (unsigned short*)(ws + 5 * M);       // [5M,5.5M)
    // attn partials (attn writes after the bf16 tiles they overlay are dead):
    float* am0 = ws;                 // [0,1M)  over X0T
    float* am1 = ws + M;             // [1M,2M) over X0T/g1T
    float* a20 = ws + 2 * M;         // [2M,3M) over g1T
    float* a21 = ws + 3 * M;         // [3M,4M) over c1T/BGcT
    float* xb  = ws + 4 * M;         // [4M,5M) over FqT/GkT (dead after attn)
    float* lP  = ws + 11 * M / 2;    // [5.5M,+32768) : [2][B][4096]
    // smalls
    float* smalls = ws + 11 * M / 2 + 32768;
    float* pool_g = smalls;            // 768
    float* pool_c = smalls + 768;      // 256 (contiguous with pool_g for zeroing)
    float* s_g    = smalls + 1024;     // 768
    float* s_c    = smalls + 1792;     // 256
    float* pav    = smalls + 2048;     // 256
    float* pmx    = smalls + 2304;     // 256
    float* biasf  = smalls + 2560;     // 64
    float* biasg  = smalls + 2624;     // 64
    float* W3L    = smalls + 2688;     // 12288
    float* Wgc    = smalls + 14976;    // 4096
    float* spm    = smalls + 19072;    // 16384
    float* spx    = smalls + 35456;    // 16384
    unsigned short* wreg = (unsigned short*)(smalls + 51840);
    unsigned short* wg1b = wreg;                    // 36864
    unsigned short* wc1b = wreg + 36864;            // 4096
    unsigned short* whb  = wreg + 40960;            // 4096
    unsigned short* WfB  = wreg + 45056;            // 4*12288 = 49152
    unsigned short* WgB  = wreg + 94208;            // 4*4096 = 16384

    unsigned short* nil = (unsigned short*)nullptr;
    dim3 blk(256);

    // input transposes + static weights + batch-independent weight chain
    k_transpose2<<<dim3(64, B, 2), blk, 192 * 65 * 4, stream>>>(group, BG + CHW, BST, X0T, BGcT);
    k_wprep<<<177, blk, 0, stream>>>(wg1, wc1, h_w, wreg, pool_g);
    k_wchain<<<4, blk, 0, stream>>>(f_w, wg3, wg2, bg2, bg3, f_b,
                                    g_w, wc2, bc2, g_b, W3L, biasf, Wgc, biasg);
    // g1 (192->192) + pool ; c1 (64->64) + pool
    k_gconv<<<dim3(64, 3, B), blk, 0, stream>>>(X0T, 192, 0, HW * 192, wg1b, 0, bg1, 0, g1T, 192, nil, pool_g, 192, 192);
    k_gconv<<<dim3(64, 1, B), blk, 0, stream>>>(X0T, 192, 64, HW * 192, wc1b, 0, bc1, 0, c1T, 64, nil, pool_c, 64, 64);
    // CA scales + per-batch weight scale
    k_ca_mlp2<<<dim3(2, B), blk, 0, stream>>>(pool_g, cag_w1, cag_b1, cag_w2, cag_b2, s_g,
                                              pool_c, cac_w1, cac_b1, cac_w2, cac_b2, s_c);
    k_wscale<<<256, blk, 0, stream>>>(W3L, Wgc, s_g, s_c, WfB, WgB);
    // projections (composed convs; biases batch-independent -> bstride 0)
    k_gconv<<<dim3(64, 1, B), blk, 0, stream>>>(g1T, 192, 0, HW * 192, WfB, 12288, biasf, 0, FqT, 64, nil, nullptr, 192, 64);
    k_gconv<<<dim3(64, 1, B), blk, 0, stream>>>(c1T, 64, 0, HW * 64, WgB, 4096, biasg, 0, GkT, 64, nil, nullptr, 64, 64);
    k_gconv<<<dim3(64, 1, B), blk, 0, stream>>>(BGcT, 64, 0, HW * 64, whb, 0, h_b, 0, nil, 64, hvN, nullptr, 64, 64);
    // attention (k-split=2, XCD-pinned, launch_bounds(512,2) -> no spill)
    k_attn<<<512, 512, 0, stream>>>(FqT, GkT, hvN, am0, am1, a20, a21, lP);
    // fused finalize + mvn + transfer + cbam pools
    k_transfer_f<<<B * 64, blk, 0, stream>>>(am0, am1, a20, a21, lP, FG, BG, BST, xb, pav, pmx);
    // CBAM spatial
    k_sp_pool<<<dim3(HW / 256, B), blk, 0, stream>>>(xb, pav, pmx, mlp_w1, mlp_b1, mlp_w2, mlp_b2, spm, spx);
    k_spf<<<dim3(HW / 256, B), blk, 0, stream>>>(spm, spx, sp_w, sp_b, xb, pav, pmx, mlp_w1, mlp_b1, mlp_w2, mlp_b2, out);
}

// Round 13
// 187.357 us; speedup vs baseline: 2.1524x; 1.0969x over previous
//
#include <hip/hip_runtime.h>
#include <hip/hip_bf16.h>
#include <math.h>

#define HW 4096

typedef __attribute__((ext_vector_type(8))) short bf16x8;
typedef __attribute__((ext_vector_type(4))) float f32x4;

static __device__ __forceinline__ unsigned short f2bf(float x) {
    unsigned u = __float_as_uint(x);
    u += 0x7fffu + ((u >> 16) & 1u);     // RNE
    return (unsigned short)(u >> 16);
}
static __device__ __forceinline__ float bf2f(unsigned short h) {
    return __uint_as_float((unsigned)h << 16);
}

// ---------------- combined transpose+bf16: z=0: group(192ch)->X0T; z=1: BGc(64ch)->BGcT
__global__ __launch_bounds__(256) void k_transpose2(
    const float* __restrict__ group, const float* __restrict__ BGc, int bstride,
    unsigned short* __restrict__ X0T, unsigned short* __restrict__ BGcT)
{
    extern __shared__ float lds[];          // [C][65]
    const int b = blockIdx.y, p0 = blockIdx.x << 6, t = threadIdx.x;
    const int z = blockIdx.z;
    const int C = z ? 64 : 192;
    const float* xb = (z ? BGc : group) + (size_t)b * bstride;
    unsigned short* outT = z ? BGcT : X0T;
    for (int idx = t; idx < (C << 6); idx += 256) {
        int c = idx >> 6, p = idx & 63;
        lds[c * 65 + p] = xb[(size_t)c * HW + p0 + p];
    }
    __syncthreads();
    unsigned short* ob = outT + ((size_t)b * HW + p0) * C;
    for (int idx = t; idx < (C << 6); idx += 256) {
        int p = idx / C, c = idx - p * C;
        ob[idx] = f2bf(lds[c * 65 + p]);
    }
}

// ---------------- per-(b,ci) mean over pixels of `group` (192 channels)
__global__ __launch_bounds__(256) void k_xmean(
    const float* __restrict__ g, int bstride, float* __restrict__ xmean)
{
    int bc = blockIdx.x;                 // B*192
    int b = bc / 192, ci = bc - b * 192;
    const float* p = g + (size_t)b * bstride + (size_t)ci * HW;
    int t = threadIdx.x;
    float s = 0.f;
    for (int i = t; i < HW; i += 256) s += p[i];
    for (int o = 32; o > 0; o >>= 1) s += __shfl_down(s, o, 64);
    __shared__ float red[4];
    if ((t & 63) == 0) red[t >> 6] = s;
    __syncthreads();
    if (t == 0) xmean[bc] = (red[0] + red[1] + red[2] + red[3]) * (1.0f / HW);
}

// ---------------- pools (analytic, via xmean) + CA MLPs + full weight composition:
// WQ[b] = log2e * wf@wg3@(wg2.diag(s_g))@wg1   [64x192], biasQ
// WK[b] = wg@(wc2.diag(s_c))@wc1               [64x64],  biasK
// grid (4 col-slices, B); block x==0 also does biases, WK, whb.
__global__ __launch_bounds__(256) void k_mlp_compose(
    const float* __restrict__ xmean,
    const float* __restrict__ wg1, const float* __restrict__ bg1,
    const float* __restrict__ cag_w1, const float* __restrict__ cag_b1,
    const float* __restrict__ cag_w2, const float* __restrict__ cag_b2,
    const float* __restrict__ wc1, const float* __restrict__ bc1,
    const float* __restrict__ cac_w1, const float* __restrict__ cac_b1,
    const float* __restrict__ cac_w2, const float* __restrict__ cac_b2,
    const float* __restrict__ wg2, const float* __restrict__ bg2,
    const float* __restrict__ wg3, const float* __restrict__ bg3,
    const float* __restrict__ wc2, const float* __restrict__ bc2,
    const float* __restrict__ wf, const float* __restrict__ fb,
    const float* __restrict__ wgw, const float* __restrict__ gbv,
    const float* __restrict__ wh,
    unsigned short* __restrict__ WQb, float* __restrict__ biasQ,
    unsigned short* __restrict__ WKb, float* __restrict__ biasK,
    unsigned short* __restrict__ whb)
{
    const float LOG2E = 1.4426950408889634f;
    __shared__ float SM[29184];          // 114 KB
    float* xm = SM;          // 192
    float* sg = SM + 192;    // 192 (pool_g then s_g)
    float* sc = SM + 384;    // 64  (pool_c then s_c)
    float* zz = SM + 448;    // 16
    float* T1 = SM + 512;    // 4096
    float* Aa = SM + 4608;   // 12288
    float* W1S = SM + 16896; // 9216
    float* Mm = SM + 26112;  // 3072
    const int x = blockIdx.x, b = blockIdx.y, t = threadIdx.x;

    if (t < 192) xm[t] = xmean[b * 192 + t];
    __syncthreads();
    // pools (linear: pool = W @ xmean + bias)
    if (t < 192) {
        float a = bg1[t];
        for (int i = 0; i < 192; ++i) a = fmaf(wg1[t * 192 + i], xm[i], a);
        sg[t] = a;
    } else {
        int c = t - 192;
        float a = bc1[c];
        for (int i = 0; i < 64; ++i) a = fmaf(wc1[c * 64 + i], xm[64 + i], a);
        sc[c] = a;
    }
    __syncthreads();
    // MLP hidden layers
    if (t < 12) {
        float a = cag_b1[t];
        for (int i = 0; i < 192; ++i) a = fmaf(cag_w1[t * 192 + i], sg[i], a);
        zz[t] = fmaxf(a, 0.f);
    }
    if (t >= 64 && t < 68) {
        int r = t - 64;
        float a = cac_b1[r];
        for (int i = 0; i < 64; ++i) a = fmaf(cac_w1[r * 64 + i], sc[i], a);
        zz[12 + r] = fmaxf(a, 0.f);
    }
    __syncthreads();
    // sigmoid scales overwrite sg/sc
    if (t < 192) {
        float a = cag_b2[t];
        for (int j = 0; j < 12; ++j) a = fmaf(cag_w2[t * 12 + j], zz[j], a);
        sg[t] = 1.f / (1.f + __expf(-a));
    } else {
        int c = t - 192;
        float a = cac_b2[c];
        for (int j = 0; j < 4; ++j) a = fmaf(cac_w2[c * 4 + j], zz[12 + j], a);
        sc[c] = 1.f / (1.f + __expf(-a));
    }
    __syncthreads();
    // T1 = wf @ wg3 (stage into Aa temporarily)
    float* wfS = Aa;
    float* wg3S = Aa + 4096;
    #pragma unroll
    for (int j = 0; j < 16; ++j) {
        wfS[t + j * 256] = wf[t + j * 256];
        wg3S[t + j * 256] = wg3[t + j * 256];
    }
    __syncthreads();
    #pragma unroll
    for (int j = 0; j < 16; ++j) {
        int idx = t + j * 256, o = idx >> 6, k = idx & 63;
        float a = 0.f;
        for (int m = 0; m < 64; ++m) a = fmaf(wfS[(o << 6) + m], wg3S[(m << 6) + k], a);
        T1[idx] = a;
    }
    __syncthreads();
    // Aa = wg2 . diag(s_g); W1S = wg1[:, i0:i0+48]
    for (int idx = t; idx < 12288; idx += 256)
        Aa[idx] = wg2[idx] * sg[idx % 192];
    const int i0 = x * 48;
    for (int idx = t; idx < 9216; idx += 256) {
        int r = idx / 48, ii = idx - r * 48;
        W1S[idx] = wg1[r * 192 + i0 + ii];
    }
    __syncthreads();
    // Mm = Aa @ W1S (64x48, K=192)
    for (int idx = t; idx < 3072; idx += 256) {
        int o = idx / 48, ii = idx - o * 48;
        float a = 0.f;
        for (int k = 0; k < 192; ++k) a = fmaf(Aa[o * 192 + k], W1S[k * 48 + ii], a);
        Mm[idx] = a;
    }
    __syncthreads();
    // WQ slice = LOG2E * T1 @ Mm
    for (int idx = t; idx < 3072; idx += 256) {
        int o = idx / 48, ii = idx - o * 48;
        float a = 0.f;
        for (int m = 0; m < 64; ++m) a = fmaf(T1[(o << 6) + m], Mm[m * 48 + ii], a);
        WQb[(size_t)b * 12288 + o * 192 + i0 + ii] = f2bf(a * LOG2E);
    }

    if (x == 0) {
        float* bq1 = Mm;        // scratch vectors (Mm reads done after sync)
        float* bq2 = Mm + 64;
        float* bk1 = Mm + 128;
        __syncthreads();
        if (t < 64) {
            float a = bg2[t];
            for (int i = 0; i < 192; ++i) a = fmaf(Aa[t * 192 + i], bg1[i], a);
            bq1[t] = a;
            float c = bc2[t];
            for (int j = 0; j < 64; ++j) c = fmaf(wc2[t * 64 + j] * sc[j], bc1[j], c);
            bk1[t] = c;
        }
        __syncthreads();
        if (t < 64) {
            float a = bg3[t];
            for (int m = 0; m < 64; ++m) a = fmaf(wg3[t * 64 + m], bq1[m], a);
            bq2[t] = a;
        }
        __syncthreads();
        if (t < 64) {
            float a = fb[t];
            for (int m = 0; m < 64; ++m) a = fmaf(wf[t * 64 + m], bq2[m], a);
            biasQ[b * 64 + t] = a * LOG2E;
            float c = gbv[t];
            for (int m = 0; m < 64; ++m) c = fmaf(wgw[t * 64 + m], bk1[m], c);
            biasK[b * 64 + t] = c;
        }
        // WK = wg @ ((wc2.diag(s_c)) @ wc1)
        float* wc1S = Aa;
        float* wc2S = Aa + 4096;
        float* T3   = Aa + 8192;
        __syncthreads();
        #pragma unroll
        for (int j = 0; j < 16; ++j) {
            int idx = t + j * 256;
            wc1S[idx] = wc1[idx];
            wc2S[idx] = wc2[idx] * sc[idx & 63];
        }
        __syncthreads();
        #pragma unroll
        for (int j = 0; j < 16; ++j) {
            int idx = t + j * 256, m = idx >> 6, i = idx & 63;
            float a = 0.f;
            for (int k = 0; k < 64; ++k) a = fmaf(wc2S[(m << 6) + k], wc1S[(k << 6) + i], a);
            T3[idx] = a;
        }
        __syncthreads();
        #pragma unroll
        for (int j = 0; j < 16; ++j) {
            int idx = t + j * 256, o = idx >> 6, i = idx & 63;
            float a = 0.f;
            for (int m = 0; m < 64; ++m) a = fmaf(wgw[(o << 6) + m], T3[(m << 6) + i], a);
            WKb[(size_t)b * 4096 + idx] = f2bf(a);
        }
        if (b == 0) {
            #pragma unroll
            for (int j = 0; j < 16; ++j) whb[t + j * 256] = f2bf(wh[t + j * 256]);
        }
    }
}

// ---------------- merged MFMA projections: y=0 Fq (Cin192), y=1 Gk (Cin64@off64), y=2 Hv
__global__ __launch_bounds__(256) void k_proj(
    const unsigned short* __restrict__ X0T, const unsigned short* __restrict__ BGcT,
    const unsigned short* __restrict__ WQb, const float* __restrict__ biasQ,
    const unsigned short* __restrict__ WKb, const float* __restrict__ biasK,
    const unsigned short* __restrict__ whb, const float* __restrict__ h_b,
    unsigned short* __restrict__ FqT, unsigned short* __restrict__ GkT,
    unsigned short* __restrict__ hvN)
{
    const int t = threadIdx.x;
    const int w = t >> 6, lane = t & 63;
    const int gid = lane >> 4, cid = lane & 15;
    const int which = blockIdx.y;
    const int b = blockIdx.z;
    const int p0 = blockIdx.x << 6;
    const int co16 = w << 4;
    int Cin, kOff, ldx;
    const unsigned short *XT, *W;
    const float* bp;
    if (which == 0) { XT = X0T; ldx = 192; kOff = 0;  Cin = 192; W = WQb + (size_t)b * 12288; bp = biasQ + b * 64; }
    else if (which == 1) { XT = X0T; ldx = 192; kOff = 64; Cin = 64; W = WKb + (size_t)b * 4096; bp = biasK + b * 64; }
    else { XT = BGcT; ldx = 64; kOff = 0; Cin = 64; W = whb; bp = h_b; }
    const unsigned short* xrow = XT + (size_t)b * HW * ldx + kOff;
    const unsigned short* wr = W + (size_t)co16 * Cin;
    f32x4 acc[4];
    #pragma unroll
    for (int n = 0; n < 4; ++n)
        #pragma unroll
        for (int r = 0; r < 4; ++r)
            acc[n][r] = bp[co16 + 4 * gid + r];
    for (int kc = 0; kc < Cin; kc += 32) {
        bf16x8 a = *(const bf16x8*)(wr + (size_t)cid * Cin + kc + 8 * gid);
        #pragma unroll
        for (int n = 0; n < 4; ++n) {
            const unsigned short* xp = xrow + (size_t)(p0 + 16 * n + cid) * ldx + kc + 8 * gid;
            bf16x8 bfr = *(const bf16x8*)xp;
            acc[n] = __builtin_amdgcn_mfma_f32_16x16x32_bf16(a, bfr, acc[n], 0, 0, 0);
        }
    }
    #pragma unroll
    for (int n = 0; n < 4; ++n)
        #pragma unroll
        for (int r = 0; r < 4; ++r) {
            float v = acc[n][r];
            int co = co16 + 4 * gid + r;
            int p  = p0 + 16 * n + cid;
            if (which == 0)      FqT[((size_t)b * HW + p) * 64 + co] = f2bf(v);
            else if (which == 1) GkT[((size_t)b * HW + p) * 64 + co] = f2bf(v);
            else                 hvN[((size_t)b * 64 + co) * HW + p] = f2bf(v);
        }
}

// ---------------- MFMA attention (proven round-8/11 config, exp2, in-reg Hv^2).
__global__ __launch_bounds__(512, 2) void k_attn(
    const unsigned short* __restrict__ FqT, const unsigned short* __restrict__ GkT,
    const unsigned short* __restrict__ HvN,
    float* __restrict__ mb, float* __restrict__ sbuf)
{
    __shared__ __align__(16) char smem[65536];
    const int t = threadIdx.x;
    const int bid = blockIdx.x;
    const int b = (bid & 7) >> 1;                         // XCD-pinned batch
    const int qbase = (((bid >> 3) << 1) | (bid & 1)) << 6;
    const int w = t >> 6, lane = t & 63;
    const int gid = lane >> 4, cid = lane & 15;
    const size_t CQ = (size_t)HW * 64;
    const unsigned short* fqt = FqT + (size_t)b * CQ;
    const unsigned short* gkt = GkT + (size_t)b * CQ;
    const unsigned short* hv  = HvN + (size_t)b * CQ;
    unsigned short* Pw = (unsigned short*)smem + w * 4096;

    bf16x8 fqa[4][2];
    #pragma unroll
    for (int qt = 0; qt < 4; ++qt) {
        const unsigned short* fr = fqt + (size_t)(qbase + 16 * qt + cid) * 64 + 8 * gid;
        fqa[qt][0] = *(const bf16x8*)fr;
        fqa[qt][1] = *(const bf16x8*)(fr + 32);
    }
    bf16x8 ones;
    #pragma unroll
    for (int j = 0; j < 8; ++j) ones[j] = (short)0x3F80;

    const f32x4 fz = {0.f, 0.f, 0.f, 0.f};
    f32x4 am[4][4], a2[4][4], lac[4];
    #pragma unroll
    for (int qt = 0; qt < 4; ++qt) {
        lac[qt] = fz;
        #pragma unroll
        for (int n = 0; n < 4; ++n) { am[qt][n] = fz; a2[qt][n] = fz; }
    }

    const int k00 = w << 9;
    for (int it = 0; it < 8; ++it) {
        const int k0 = k00 + (it << 6);
        #pragma unroll
        for (int n = 0; n < 4; ++n) {
            const unsigned short* gr = gkt + (size_t)(k0 + 16 * n + cid) * 64 + 8 * gid;
            bf16x8 b0 = *(const bf16x8*)gr;
            bf16x8 b1 = *(const bf16x8*)(gr + 32);
            const int k = 16 * n + cid;
            #pragma unroll
            for (int qt = 0; qt < 4; ++qt) {
                f32x4 s = __builtin_amdgcn_mfma_f32_16x16x32_bf16(fqa[qt][0], b0, fz, 0, 0, 0);
                s = __builtin_amdgcn_mfma_f32_16x16x32_bf16(fqa[qt][1], b1, s, 0, 0, 0);
                #pragma unroll
                for (int r = 0; r < 4; ++r) {
                    int q = 4 * gid + r;
                    Pw[qt * 1024 + q * 64 + (((k >> 3) ^ (q & 7)) << 3) + (k & 7)] =
                        f2bf(__builtin_amdgcn_exp2f(s[r]));
                }
            }
        }
        bf16x8 pa[4][2];
        #pragma unroll
        for (int qt = 0; qt < 4; ++qt)
            #pragma unroll
            for (int kh = 0; kh < 2; ++kh)
                pa[qt][kh] = *(const bf16x8*)(Pw + qt * 1024 + cid * 64 +
                                              (((4 * kh + gid) ^ (cid & 7)) << 3));
        #pragma unroll
        for (int qt = 0; qt < 4; ++qt) {
            lac[qt] = __builtin_amdgcn_mfma_f32_16x16x32_bf16(pa[qt][0], ones, lac[qt], 0, 0, 0);
            lac[qt] = __builtin_amdgcn_mfma_f32_16x16x32_bf16(pa[qt][1], ones, lac[qt], 0, 0, 0);
        }
        #pragma unroll
        for (int n = 0; n < 4; ++n) {
            const unsigned short* hr = hv + (size_t)(16 * n + cid) * HW + k0;
            #pragma unroll
            for (int kh = 0; kh < 2; ++kh) {
                bf16x8 hb = *(const bf16x8*)(hr + 32 * kh + 8 * gid);
                bf16x8 h2;
                #pragma unroll
                for (int j = 0; j < 8; ++j) {
                    float v = bf2f((unsigned short)hb[j]);
                    h2[j] = (short)f2bf(v * v);
                }
                #pragma unroll
                for (int qt = 0; qt < 4; ++qt) {
                    am[qt][n] = __builtin_amdgcn_mfma_f32_16x16x32_bf16(pa[qt][kh], hb, am[qt][n], 0, 0, 0);
                    a2[qt][n] = __builtin_amdgcn_mfma_f32_16x16x32_bf16(pa[qt][kh], h2, a2[qt][n], 0, 0, 0);
                }
            }
        }
    }

    __syncthreads();
    float* lb = (float*)smem;
    #pragma unroll
    for (int qt = 0; qt < 4; ++qt)
        *(f32x4*)(lb + ((size_t)(w * 4 + qt) * 64 + lane) * 4) = lac[qt];
    __syncthreads();
    float* Lm = (float*)(smem + 32768);
    if (t < 256) {
        int qt = t >> 6, ls = t & 63;
        f32x4 s = fz;
        #pragma unroll
        for (int ww = 0; ww < 8; ++ww)
            s += *(const f32x4*)(lb + ((size_t)(ww * 4 + qt) * 64 + ls) * 4);
        *(f32x4*)(Lm + ((size_t)qt * 64 + ls) * 4) = s;
    }
    __syncthreads();
    float* ab = (float*)smem;
    f32x4 meanv = fz;
    for (int qt = 0; qt < 4; ++qt) {
        #pragma unroll
        for (int n = 0; n < 4; ++n)
            *(f32x4*)(ab + ((size_t)(w * 4 + n) * 64 + lane) * 4) = am[qt][n];
        __syncthreads();
        if (t < 256) {
            int n = t >> 6, ls = t & 63;
            f32x4 s = fz;
            #pragma unroll
            for (int ww = 0; ww < 8; ++ww)
                s += *(const f32x4*)(ab + ((size_t)(ww * 4 + n) * 64 + ls) * 4);
            f32x4 lv = *(const f32x4*)(Lm + ((size_t)qt * 64 + ls) * 4);
            #pragma unroll
            for (int r = 0; r < 4; ++r) meanv[r] = s[r] / lv[r];
            int q0s = qbase + 16 * qt + 4 * (ls >> 4);
            int c   = 16 * n + (ls & 15);
            *(f32x4*)(mb + (size_t)b * CQ + (size_t)c * HW + q0s) = meanv;
        }
        __syncthreads();
        #pragma unroll
        for (int n = 0; n < 4; ++n)
            *(f32x4*)(ab + ((size_t)(w * 4 + n) * 64 + lane) * 4) = a2[qt][n];
        __syncthreads();
        if (t < 256) {
            int n = t >> 6, ls = t & 63;
            f32x4 s = fz;
            #pragma unroll
            for (int ww = 0; ww < 8; ++ww)
                s += *(const f32x4*)(ab + ((size_t)(ww * 4 + n) * 64 + ls) * 4);
            f32x4 lv = *(const f32x4*)(Lm + ((size_t)qt * 64 + ls) * 4);
            f32x4 sv;
            #pragma unroll
            for (int r = 0; r < 4; ++r) {
                float sec = s[r] / lv[r];
                sv[r] = sqrtf(fmaxf(sec - meanv[r] * meanv[r], 0.f));
            }
            int q0s = qbase + 16 * qt + 4 * (ls >> 4);
            int c   = 16 * n + (ls & 15);
            *(f32x4*)(sbuf + (size_t)b * CQ + (size_t)c * HW + q0s) = sv;
        }
        __syncthreads();
    }
}

// ---------------- fused: mvn stats + transfer + cbam channel pools
__global__ __launch_bounds__(256) void k_transfer_f(
    const float* __restrict__ mb, const float* __restrict__ sb,
    const float* __restrict__ FG, const float* __restrict__ BG, int bstride,
    float* __restrict__ xb, float* __restrict__ pavg, float* __restrict__ pmaxb)
{
    __shared__ float fgl[4096];
    __shared__ float r1[4], r2[4];
    const int bc = blockIdx.x, t = threadIdx.x;
    const int b = bc >> 6, c = bc & 63;
    const size_t row = (size_t)bc * HW;
    const float* fg = FG + (size_t)b * bstride + (size_t)(64 + c) * HW;
    const float* bg = BG + (size_t)b * bstride + (size_t)(64 + c) * HW;
    float s = 0.f, s2 = 0.f;
    #pragma unroll
    for (int j = 0; j < 16; ++j) {
        int i = t + j * 256;
        float v = fg[i];
        fgl[i] = v;
        s += v; s2 += v * v;
    }
    #pragma unroll
    for (int o = 32; o > 0; o >>= 1) { s += __shfl_down(s, o, 64); s2 += __shfl_down(s2, o, 64); }
    if ((t & 63) == 0) { r1[t >> 6] = s; r2[t >> 6] = s2; }
    __syncthreads();
    float m  = (r1[0] + r1[1] + r1[2] + r1[3]) * (1.0f / HW);
    float e2 = (r2[0] + r2[1] + r2[2] + r2[3]) * (1.0f / HW);
    float rs = rsqrtf(fmaxf(e2 - m * m, 0.f) + 1e-5f);
    float psum = 0.f, pmax = -1e30f;
    #pragma unroll
    for (int j = 0; j < 16; ++j) {
        int q = t + j * 256;
        float xv = sb[row + q] * (fgl[q] - m) * rs + mb[row + q] + bg[q];
        xb[row + q] = xv;
        psum += xv; pmax = fmaxf(pmax, xv);
    }
    __syncthreads();
    #pragma unroll
    for (int o = 32; o > 0; o >>= 1) {
        psum += __shfl_down(psum, o, 64);
        pmax = fmaxf(pmax, __shfl_down(pmax, o, 64));
    }
    if ((t & 63) == 0) { r1[t >> 6] = psum; r2[t >> 6] = pmax; }
    __syncthreads();
    if (t == 0) {
        pavg[bc]  = (r1[0] + r1[1] + r1[2] + r1[3]) * (1.0f / HW);
        pmaxb[bc] = fmaxf(fmaxf(r2[0], r2[1]), fmaxf(r2[2], r2[3]));
    }
}

// ---------------- CBAM channel-scale (recomputed per block)
static __device__ __forceinline__ void cbam_scale(
    const float* __restrict__ pav, const float* __restrict__ pmx,
    const float* __restrict__ w1, const float* __restrict__ b1,
    const float* __restrict__ w2, const float* __restrict__ b2,
    int b, int t, float* scb)
{
    __shared__ float za[4], zm[4];
    if (t < 4) {
        float aa = b1[t], am = b1[t];
        for (int i = 0; i < 64; ++i) {
            aa = fmaf(w1[t * 64 + i], pav[b * 64 + i], aa);
            am = fmaf(w1[t * 64 + i], pmx[b * 64 + i], am);
        }
        za[t] = fmaxf(aa, 0.f);
        zm[t] = fmaxf(am, 0.f);
    }
    __syncthreads();
    if (t < 64) {
        float a = 2.f * b2[t];
        for (int j = 0; j < 4; ++j) a = fmaf(w2[t * 4 + j], za[j] + zm[j], a);
        scb[t] = 1.f / (1.f + __expf(-a));
    }
    __syncthreads();
}

// ---------------- spatial pool of (xb*s) with inlined cbam MLP
__global__ __launch_bounds__(256) void k_sp_pool(
    const float* __restrict__ xb,
    const float* __restrict__ pav, const float* __restrict__ pmx,
    const float* __restrict__ w1, const float* __restrict__ b1,
    const float* __restrict__ w2, const float* __restrict__ b2,
    float* __restrict__ spm, float* __restrict__ spx)
{
    __shared__ float scb[64];
    const int b = blockIdx.y, t = threadIdx.x;
    cbam_scale(pav, pmx, w1, b1, w2, b2, b, t, scb);
    const int p = blockIdx.x * 256 + t;
    const float* xp = xb + (size_t)b * 262144 + p;
    float sum = 0.f, mx = -1e30f;
    for (int c = 0; c < 64; ++c) {
        float v = xp[(size_t)c * HW] * scb[c];
        sum += v;
        mx = fmaxf(mx, v);
    }
    spm[b * HW + p] = sum * (1.0f / 64.0f);
    spx[b * HW + p] = mx;
}

// ---------------- fused 7x7 spatial conv + sigmoid + final output
__global__ __launch_bounds__(256) void k_spf(
    const float* __restrict__ spm, const float* __restrict__ spx,
    const float* __restrict__ w, const float* __restrict__ bias,
    const float* __restrict__ xb,
    const float* __restrict__ pav, const float* __restrict__ pmx,
    const float* __restrict__ w1, const float* __restrict__ b1,
    const float* __restrict__ w2, const float* __restrict__ b2,
    float* __restrict__ out)
{
    __shared__ float scb[64];
    const int b = blockIdx.y, t = threadIdx.x;
    cbam_scale(pav, pmx, w1, b1, w2, b2, b, t, scb);
    const int p = blockIdx.x * 256 + t;
    const int y = p >> 6, x = p & 63;
    float acc = bias[0];
    for (int dy = 0; dy < 7; ++dy) {
        int yy = y + dy - 3;
        if (yy < 0 || yy >= 64) continue;
        for (int dx = 0; dx < 7; ++dx) {
            int xx = x + dx - 3;
            if (xx < 0 || xx >= 64) continue;
            int q = b * HW + yy * 64 + xx;
            acc = fmaf(spm[q], w[dy * 7 + dx],      acc);
            acc = fmaf(spx[q], w[49 + dy * 7 + dx], acc);
        }
    }
    float sgm = 1.f / (1.f + __expf(-acc));
    const float* xp = xb + (size_t)b * 262144 + p;
    float* op = out + (size_t)b * 262144 + p;
    for (int c = 0; c < 64; ++c)
        op[(size_t)c * HW] = xp[(size_t)c * HW] * scb[c] * sgm;
}

extern "C" void kernel_launch(void* const* d_in, const int* in_sizes, int n_in,
                              void* d_out, int out_size, void* d_ws, size_t ws_size,
                              hipStream_t stream)
{
    const float* group  = (const float*)d_in[0];
    const float* FG     = (const float*)d_in[1];
    const float* BG     = (const float*)d_in[2];
    const float* wg1    = (const float*)d_in[3];
    const float* bg1    = (const float*)d_in[4];
    const float* cag_w1 = (const float*)d_in[5];
    const float* cag_b1 = (const float*)d_in[6];
    const float* cag_w2 = (const float*)d_in[7];
    const float* cag_b2 = (const float*)d_in[8];
    const float* wg2    = (const float*)d_in[9];
    const float* bg2    = (const float*)d_in[10];
    const float* wg3    = (const float*)d_in[11];
    const float* bg3    = (const float*)d_in[12];
    const float* wc1    = (const float*)d_in[13];
    const float* bc1    = (const float*)d_in[14];
    const float* cac_w1 = (const float*)d_in[15];
    const float* cac_b1 = (const float*)d_in[16];
    const float* cac_w2 = (const float*)d_in[17];
    const float* cac_b2 = (const float*)d_in[18];
    const float* wc2    = (const float*)d_in[19];
    const float* bc2    = (const float*)d_in[20];
    const float* f_w    = (const float*)d_in[21];
    const float* f_b    = (const float*)d_in[22];
    const float* g_w    = (const float*)d_in[23];
    const float* g_b    = (const float*)d_in[24];
    const float* h_w    = (const float*)d_in[25];
    const float* h_b    = (const float*)d_in[26];
    const float* mlp_w1 = (const float*)d_in[27];
    const float* mlp_b1 = (const float*)d_in[28];
    const float* mlp_w2 = (const float*)d_in[29];
    const float* mlp_b2 = (const float*)d_in[30];
    const float* sp_w   = (const float*)d_in[31];
    const float* sp_b   = (const float*)d_in[32];
    float* out = (float*)d_out;

    const int B = 4;
    const size_t CHW = (size_t)64 * HW;
    const int BST = (int)(3 * CHW);

    float* ws = (float*)d_ws;
    const size_t M = 1048576;
    unsigned short* X0T  = (unsigned short*)ws;                 // [0,1.5M)f
    unsigned short* BGcT = (unsigned short*)(ws + 3 * M / 2);   // [1.5M,2M)
    unsigned short* FqT  = (unsigned short*)(ws + 2 * M);       // [2M,2.5M)
    unsigned short* GkT  = (unsigned short*)(ws + 5 * M / 2);   // [2.5M,3M)
    unsigned short* hvN  = (unsigned short*)(ws + 3 * M);       // [3M,3.5M)
    float* mbuf = ws + 7 * M / 2;   // [3.5M,4.5M)
    float* sbuf = ws + 9 * M / 2;   // [4.5M,5.5M)
    float* xb   = ws + 2 * M;       // overlays FqT/GkT (dead after attn)
    float* smalls = ws + 11 * M / 2;
    float* xmean = smalls;             // 768
    float* pav   = smalls + 1024;      // 256
    float* pmx   = smalls + 1280;      // 256
    float* biasQ = smalls + 1536;      // 256
    float* biasK = smalls + 1792;      // 256
    float* spm   = smalls + 2048;      // 16384
    float* spx   = smalls + 18432;     // 16384
    unsigned short* wsh = (unsigned short*)(smalls + 34816);
    unsigned short* WQb = wsh;              // 49152
    unsigned short* WKb = wsh + 49152;      // 16384
    unsigned short* whb = wsh + 65536;      // 4096

    dim3 blk(256);

    // 1. input transposes (X0T 192ch, BGcT 64ch)
    k_transpose2<<<dim3(64, B, 2), blk, 192 * 65 * 4, stream>>>(group, BG + CHW, BST, X0T, BGcT);
    // 2. channel means of group
    k_xmean<<<B * 192, blk, 0, stream>>>(group, BST, xmean);
    // 3. pools + MLPs + full weight composition (WQ, WK, biases, whb)
    k_mlp_compose<<<dim3(4, B), blk, 0, stream>>>(
        xmean, wg1, bg1, cag_w1, cag_b1, cag_w2, cag_b2,
        wc1, bc1, cac_w1, cac_b1, cac_w2, cac_b2,
        wg2, bg2, wg3, bg3, wc2, bc2,
        f_w, f_b, g_w, g_b, h_w,
        WQb, biasQ, WKb, biasK, whb);
    // 4. merged projections Fq/Gk/Hv
    k_proj<<<dim3(64, 3, B), blk, 0, stream>>>(
        X0T, BGcT, WQb, biasQ, WKb, biasK, whb, h_b, FqT, GkT, hvN);
    // 5. attention
    k_attn<<<256, 512, 0, stream>>>(FqT, GkT, hvN, mbuf, sbuf);
    // 6. fused mvn + transfer + cbam channel pools
    k_transfer_f<<<B * 64, blk, 0, stream>>>(mbuf, sbuf, FG, BG, BST, xb, pav, pmx);
    // 7/8. CBAM spatial
    k_sp_pool<<<dim3(HW / 256, B), blk, 0, stream>>>(xb, pav, pmx, mlp_w1, mlp_b1, mlp_w2, mlp_b2, spm, spx);
    k_spf<<<dim3(HW / 256, B), blk, 0, stream>>>(spm, spx, sp_w, sp_b, xb, pav, pmx, mlp_w1, mlp_b1, mlp_w2, mlp_b2, out);
}

// Round 14
// 175.463 us; speedup vs baseline: 2.2983x; 1.0678x over previous
//
#include <hip/hip_runtime.h>
#include <hip/hip_bf16.h>
#include <math.h>

#define HW 4096

typedef __attribute__((ext_vector_type(8))) short bf16x8;
typedef __attribute__((ext_vector_type(4))) float f32x4;

static __device__ __forceinline__ unsigned short f2bf(float x) {
    unsigned u = __float_as_uint(x);
    u += 0x7fffu + ((u >> 16) & 1u);     // RNE
    return (unsigned short)(u >> 16);
}
static __device__ __forceinline__ float bf2f(unsigned short h) {
    return __uint_as_float((unsigned)h << 16);
}

// ---------------- combined transpose+bf16: z=0: group(192ch)->X0T; z=1: BGc(64ch)->BGcT
__global__ __launch_bounds__(256) void k_transpose2(
    const float* __restrict__ group, const float* __restrict__ BGc, int bstride,
    unsigned short* __restrict__ X0T, unsigned short* __restrict__ BGcT)
{
    extern __shared__ float lds[];          // [C][65]
    const int b = blockIdx.y, p0 = blockIdx.x << 6, t = threadIdx.x;
    const int z = blockIdx.z;
    const int C = z ? 64 : 192;
    const float* xb = (z ? BGc : group) + (size_t)b * bstride;
    unsigned short* outT = z ? BGcT : X0T;
    for (int idx = t; idx < (C << 6); idx += 256) {
        int c = idx >> 6, p = idx & 63;
        lds[c * 65 + p] = xb[(size_t)c * HW + p0 + p];
    }
    __syncthreads();
    unsigned short* ob = outT + ((size_t)b * HW + p0) * C;
    for (int idx = t; idx < (C << 6); idx += 256) {
        int p = idx / C, c = idx - p * C;
        ob[idx] = f2bf(lds[c * 65 + p]);
    }
}

// ---------------- per-(b,ci) mean over pixels of `group` (192 channels)
__global__ __launch_bounds__(256) void k_xmean(
    const float* __restrict__ g, int bstride, float* __restrict__ xmean)
{
    int bc = blockIdx.x;                 // B*192
    int b = bc / 192, ci = bc - b * 192;
    const float* p = g + (size_t)b * bstride + (size_t)ci * HW;
    int t = threadIdx.x;
    float s = 0.f;
    #pragma unroll 4
    for (int i = t; i < HW; i += 256) s += p[i];
    for (int o = 32; o > 0; o >>= 1) s += __shfl_down(s, o, 64);
    __shared__ float red[4];
    if ((t & 63) == 0) red[t >> 6] = s;
    __syncthreads();
    if (t == 0) xmean[bc] = (red[0] + red[1] + red[2] + red[3]) * (1.0f / HW);
}

// ---------------- pools (analytic) + CA MLPs + full weight composition.
// WQ[b]=log2e*wf@wg3@(wg2.diag(s_g))@wg1 [64x192]; WK[b]=wg@(wc2.diag(s_c))@wc1 [64x64].
// grid (4 col-slices, B): all blocks do WQ slice; x==1 adds WK, x==2 biases, x==3 whb.
__global__ __launch_bounds__(256) void k_mlp_compose(
    const float* __restrict__ xmean,
    const float* __restrict__ wg1, const float* __restrict__ bg1,
    const float* __restrict__ cag_w1, const float* __restrict__ cag_b1,
    const float* __restrict__ cag_w2, const float* __restrict__ cag_b2,
    const float* __restrict__ wc1, const float* __restrict__ bc1,
    const float* __restrict__ cac_w1, const float* __restrict__ cac_b1,
    const float* __restrict__ cac_w2, const float* __restrict__ cac_b2,
    const float* __restrict__ wg2, const float* __restrict__ bg2,
    const float* __restrict__ wg3, const float* __restrict__ bg3,
    const float* __restrict__ wc2, const float* __restrict__ bc2,
    const float* __restrict__ wf, const float* __restrict__ fb,
    const float* __restrict__ wgw, const float* __restrict__ gbv,
    const float* __restrict__ wh,
    unsigned short* __restrict__ WQb, float* __restrict__ biasQ,
    unsigned short* __restrict__ WKb, float* __restrict__ biasK,
    unsigned short* __restrict__ whb)
{
    const float LOG2E = 1.4426950408889634f;
    __shared__ float SM[29392];          // ~115 KB
    float* xm = SM;           // 192
    float* sg = SM + 192;     // 192 (pool_g then s_g)
    float* sc = SM + 384;     // 64  (pool_c then s_c)
    float* zz = SM + 448;     // 16
    float* T1 = SM + 512;     // 64x65 = 4160 (padded)
    float* Aa = SM + 4672;    // 64x193 = 12352 (padded)
    float* W1S = SM + 17024;  // 9216
    float* Mm = SM + 26240;   // 3072
    const int x = blockIdx.x, b = blockIdx.y, t = threadIdx.x;

    if (t < 192) xm[t] = xmean[b * 192 + t];
    __syncthreads();
    // pools (linear: pool = W @ xmean + bias)
    if (t < 192) {
        float a = bg1[t];
        #pragma unroll 16
        for (int i = 0; i < 192; ++i) a = fmaf(wg1[t * 192 + i], xm[i], a);
        sg[t] = a;
    } else {
        int c = t - 192;
        float a = bc1[c];
        #pragma unroll 16
        for (int i = 0; i < 64; ++i) a = fmaf(wc1[c * 64 + i], xm[64 + i], a);
        sc[c] = a;
    }
    __syncthreads();
    // MLP hidden layers
    if (t < 12) {
        float a = cag_b1[t];
        #pragma unroll 16
        for (int i = 0; i < 192; ++i) a = fmaf(cag_w1[t * 192 + i], sg[i], a);
        zz[t] = fmaxf(a, 0.f);
    }
    if (t >= 64 && t < 68) {
        int r = t - 64;
        float a = cac_b1[r];
        #pragma unroll 16
        for (int i = 0; i < 64; ++i) a = fmaf(cac_w1[r * 64 + i], sc[i], a);
        zz[12 + r] = fmaxf(a, 0.f);
    }
    __syncthreads();
    // sigmoid scales overwrite sg/sc
    if (t < 192) {
        float a = cag_b2[t];
        #pragma unroll
        for (int j = 0; j < 12; ++j) a = fmaf(cag_w2[t * 12 + j], zz[j], a);
        sg[t] = 1.f / (1.f + __expf(-a));
    } else {
        int c = t - 192;
        float a = cac_b2[c];
        #pragma unroll
        for (int j = 0; j < 4; ++j) a = fmaf(cac_w2[c * 4 + j], zz[12 + j], a);
        sc[c] = 1.f / (1.f + __expf(-a));
    }
    __syncthreads();
    // T1 = wf @ wg3 (stage operands into Aa/W1S temporarily)
    float* wfS = Aa;
    float* wg3S = W1S;
    #pragma unroll
    for (int j = 0; j < 16; ++j) {
        wfS[t + j * 256] = wf[t + j * 256];
        wg3S[t + j * 256] = wg3[t + j * 256];
    }
    __syncthreads();
    #pragma unroll
    for (int j = 0; j < 16; ++j) {
        int idx = t + j * 256, o = idx >> 6, k = idx & 63;
        float a = 0.f;
        #pragma unroll 16
        for (int m = 0; m < 64; ++m) a = fmaf(wfS[(o << 6) + m], wg3S[(m << 6) + k], a);
        T1[o * 65 + k] = a;
    }
    __syncthreads();
    // Aa = wg2 . diag(s_g) (padded stride 193); W1S = wg1[:, i0:i0+48]
    #pragma unroll 8
    for (int idx = t; idx < 12288; idx += 256) {
        int r = idx / 192, i = idx - r * 192;
        Aa[r * 193 + i] = wg2[idx] * sg[i];
    }
    const int i0 = x * 48;
    #pragma unroll 8
    for (int idx = t; idx < 9216; idx += 256) {
        int r = idx / 48, ii = idx - r * 48;
        W1S[idx] = wg1[r * 192 + i0 + ii];
    }
    __syncthreads();
    // Mm = Aa @ W1S (64x48, K=192)
    #pragma unroll 3
    for (int idx = t; idx < 3072; idx += 256) {
        int o = idx / 48, ii = idx - o * 48;
        float a = 0.f;
        #pragma unroll 16
        for (int k = 0; k < 192; ++k) a = fmaf(Aa[o * 193 + k], W1S[k * 48 + ii], a);
        Mm[idx] = a;
    }
    __syncthreads();
    // WQ slice = LOG2E * T1 @ Mm
    #pragma unroll 3
    for (int idx = t; idx < 3072; idx += 256) {
        int o = idx / 48, ii = idx - o * 48;
        float a = 0.f;
        #pragma unroll 16
        for (int m = 0; m < 64; ++m) a = fmaf(T1[o * 65 + m], Mm[m * 48 + ii], a);
        WQb[(size_t)b * 12288 + o * 192 + i0 + ii] = f2bf(a * LOG2E);
    }

    if (x == 2) {
        // biases (needs Aa, T1 — both intact in this block)
        float* bq1 = Mm;
        float* bk1 = Mm + 64;
        __syncthreads();
        if (t < 64) {
            float a = bg2[t];
            #pragma unroll 16
            for (int i = 0; i < 192; ++i) a = fmaf(Aa[t * 193 + i], bg1[i], a);
            bq1[t] = a;
            float c = bc2[t];
            #pragma unroll 16
            for (int j = 0; j < 64; ++j) c = fmaf(wc2[t * 64 + j] * sc[j], bc1[j], c);
            bk1[t] = c;
        }
        __syncthreads();
        if (t < 64) {
            float a = bg3[t];
            #pragma unroll 16
            for (int m = 0; m < 64; ++m) a = fmaf(wg3[t * 64 + m], bq1[m], a);
            // a = wg3@(wg2s@bg1)+bg3 ; now through wf:
            Mm[128 + t] = a;
        }
        __syncthreads();
        if (t < 64) {
            float a = fb[t];
            #pragma unroll 16
            for (int m = 0; m < 64; ++m) a = fmaf(wf[t * 64 + m], Mm[128 + m], a);
            biasQ[b * 64 + t] = a * LOG2E;
            float c = gbv[t];
            #pragma unroll 16
            for (int m = 0; m < 64; ++m) c = fmaf(wgw[t * 64 + m], bk1[m], c);
            biasK[b * 64 + t] = c;
        }
    } else if (x == 1) {
        // WK = wg @ ((wc2.diag(s_c)) @ wc1)   (reuse Aa region as scratch)
        float* wc1S = Aa;
        float* wc2S = Aa + 4096;
        float* T3   = Aa + 8192;
        __syncthreads();
        #pragma unroll
        for (int j = 0; j < 16; ++j) {
            int idx = t + j * 256;
            wc1S[idx] = wc1[idx];
            wc2S[idx] = wc2[idx] * sc[idx & 63];
        }
        __syncthreads();
        #pragma unroll
        for (int j = 0; j < 16; ++j) {
            int idx = t + j * 256, m = idx >> 6, i = idx & 63;
            float a = 0.f;
            #pragma unroll 16
            for (int k = 0; k < 64; ++k) a = fmaf(wc2S[(m << 6) + k], wc1S[(k << 6) + i], a);
            T3[idx] = a;
        }
        __syncthreads();
        #pragma unroll
        for (int j = 0; j < 16; ++j) {
            int idx = t + j * 256, o = idx >> 6, i = idx & 63;
            float a = 0.f;
            #pragma unroll 16
            for (int m = 0; m < 64; ++m) a = fmaf(wgw[(o << 6) + m], T3[(m << 6) + i], a);
            WKb[(size_t)b * 4096 + idx] = f2bf(a);
        }
    } else if (x == 3 && b == 0) {
        #pragma unroll
        for (int j = 0; j < 16; ++j) whb[t + j * 256] = f2bf(wh[t + j * 256]);
    }
}

// ---------------- merged MFMA projections: y=0 Fq (Cin192), y=1 Gk (Cin64@off64), y=2 Hv
__global__ __launch_bounds__(256) void k_proj(
    const unsigned short* __restrict__ X0T, const unsigned short* __restrict__ BGcT,
    const unsigned short* __restrict__ WQb, const float* __restrict__ biasQ,
    const unsigned short* __restrict__ WKb, const float* __restrict__ biasK,
    const unsigned short* __restrict__ whb, const float* __restrict__ h_b,
    unsigned short* __restrict__ FqT, unsigned short* __restrict__ GkT,
    unsigned short* __restrict__ hvN)
{
    const int t = threadIdx.x;
    const int w = t >> 6, lane = t & 63;
    const int gid = lane >> 4, cid = lane & 15;
    const int which = blockIdx.y;
    const int b = blockIdx.z;
    const int p0 = blockIdx.x << 6;
    const int co16 = w << 4;
    int Cin, kOff, ldx;
    const unsigned short *XT, *W;
    const float* bp;
    if (which == 0) { XT = X0T; ldx = 192; kOff = 0;  Cin = 192; W = WQb + (size_t)b * 12288; bp = biasQ + b * 64; }
    else if (which == 1) { XT = X0T; ldx = 192; kOff = 64; Cin = 64; W = WKb + (size_t)b * 4096; bp = biasK + b * 64; }
    else { XT = BGcT; ldx = 64; kOff = 0; Cin = 64; W = whb; bp = h_b; }
    const unsigned short* xrow = XT + (size_t)b * HW * ldx + kOff;
    const unsigned short* wr = W + (size_t)co16 * Cin;
    f32x4 acc[4];
    #pragma unroll
    for (int n = 0; n < 4; ++n)
        #pragma unroll
        for (int r = 0; r < 4; ++r)
            acc[n][r] = bp[co16 + 4 * gid + r];
    for (int kc = 0; kc < Cin; kc += 32) {
        bf16x8 a = *(const bf16x8*)(wr + (size_t)cid * Cin + kc + 8 * gid);
        #pragma unroll
        for (int n = 0; n < 4; ++n) {
            const unsigned short* xp = xrow + (size_t)(p0 + 16 * n + cid) * ldx + kc + 8 * gid;
            bf16x8 bfr = *(const bf16x8*)xp;
            acc[n] = __builtin_amdgcn_mfma_f32_16x16x32_bf16(a, bfr, acc[n], 0, 0, 0);
        }
    }
    #pragma unroll
    for (int n = 0; n < 4; ++n)
        #pragma unroll
        for (int r = 0; r < 4; ++r) {
            float v = acc[n][r];
            int co = co16 + 4 * gid + r;
            int p  = p0 + 16 * n + cid;
            if (which == 0)      FqT[((size_t)b * HW + p) * 64 + co] = f2bf(v);
            else if (which == 1) GkT[((size_t)b * HW + p) * 64 + co] = f2bf(v);
            else                 hvN[((size_t)b * 64 + co) * HW + p] = f2bf(v);
        }
}

// ---------------- MFMA attention (proven round-8/11 config, exp2, in-reg Hv^2).
__global__ __launch_bounds__(512, 2) void k_attn(
    const unsigned short* __restrict__ FqT, const unsigned short* __restrict__ GkT,
    const unsigned short* __restrict__ HvN,
    float* __restrict__ mb, float* __restrict__ sbuf)
{
    __shared__ __align__(16) char smem[65536];
    const int t = threadIdx.x;
    const int bid = blockIdx.x;
    const int b = (bid & 7) >> 1;                         // XCD-pinned batch
    const int qbase = (((bid >> 3) << 1) | (bid & 1)) << 6;
    const int w = t >> 6, lane = t & 63;
    const int gid = lane >> 4, cid = lane & 15;
    const size_t CQ = (size_t)HW * 64;
    const unsigned short* fqt = FqT + (size_t)b * CQ;
    const unsigned short* gkt = GkT + (size_t)b * CQ;
    const unsigned short* hv  = HvN + (size_t)b * CQ;
    unsigned short* Pw = (unsigned short*)smem + w * 4096;

    bf16x8 fqa[4][2];
    #pragma unroll
    for (int qt = 0; qt < 4; ++qt) {
        const unsigned short* fr = fqt + (size_t)(qbase + 16 * qt + cid) * 64 + 8 * gid;
        fqa[qt][0] = *(const bf16x8*)fr;
        fqa[qt][1] = *(const bf16x8*)(fr + 32);
    }
    bf16x8 ones;
    #pragma unroll
    for (int j = 0; j < 8; ++j) ones[j] = (short)0x3F80;

    const f32x4 fz = {0.f, 0.f, 0.f, 0.f};
    f32x4 am[4][4], a2[4][4], lac[4];
    #pragma unroll
    for (int qt = 0; qt < 4; ++qt) {
        lac[qt] = fz;
        #pragma unroll
        for (int n = 0; n < 4; ++n) { am[qt][n] = fz; a2[qt][n] = fz; }
    }

    const int k00 = w << 9;
    for (int it = 0; it < 8; ++it) {
        const int k0 = k00 + (it << 6);
        #pragma unroll
        for (int n = 0; n < 4; ++n) {
            const unsigned short* gr = gkt + (size_t)(k0 + 16 * n + cid) * 64 + 8 * gid;
            bf16x8 b0 = *(const bf16x8*)gr;
            bf16x8 b1 = *(const bf16x8*)(gr + 32);
            const int k = 16 * n + cid;
            #pragma unroll
            for (int qt = 0; qt < 4; ++qt) {
                f32x4 s = __builtin_amdgcn_mfma_f32_16x16x32_bf16(fqa[qt][0], b0, fz, 0, 0, 0);
                s = __builtin_amdgcn_mfma_f32_16x16x32_bf16(fqa[qt][1], b1, s, 0, 0, 0);
                #pragma unroll
                for (int r = 0; r < 4; ++r) {
                    int q = 4 * gid + r;
                    Pw[qt * 1024 + q * 64 + (((k >> 3) ^ (q & 7)) << 3) + (k & 7)] =
                        f2bf(__builtin_amdgcn_exp2f(s[r]));
                }
            }
        }
        bf16x8 pa[4][2];
        #pragma unroll
        for (int qt = 0; qt < 4; ++qt)
            #pragma unroll
            for (int kh = 0; kh < 2; ++kh)
                pa[qt][kh] = *(const bf16x8*)(Pw + qt * 1024 + cid * 64 +
                                              (((4 * kh + gid) ^ (cid & 7)) << 3));
        #pragma unroll
        for (int qt = 0; qt < 4; ++qt) {
            lac[qt] = __builtin_amdgcn_mfma_f32_16x16x32_bf16(pa[qt][0], ones, lac[qt], 0, 0, 0);
            lac[qt] = __builtin_amdgcn_mfma_f32_16x16x32_bf16(pa[qt][1], ones, lac[qt], 0, 0, 0);
        }
        #pragma unroll
        for (int n = 0; n < 4; ++n) {
            const unsigned short* hr = hv + (size_t)(16 * n + cid) * HW + k0;
            #pragma unroll
            for (int kh = 0; kh < 2; ++kh) {
                bf16x8 hb = *(const bf16x8*)(hr + 32 * kh + 8 * gid);
                bf16x8 h2;
                #pragma unroll
                for (int j = 0; j < 8; ++j) {
                    float v = bf2f((unsigned short)hb[j]);
                    h2[j] = (short)f2bf(v * v);
                }
                #pragma unroll
                for (int qt = 0; qt < 4; ++qt) {
                    am[qt][n] = __builtin_amdgcn_mfma_f32_16x16x32_bf16(pa[qt][kh], hb, am[qt][n], 0, 0, 0);
                    a2[qt][n] = __builtin_amdgcn_mfma_f32_16x16x32_bf16(pa[qt][kh], h2, a2[qt][n], 0, 0, 0);
                }
            }
        }
    }

    __syncthreads();
    float* lb = (float*)smem;
    #pragma unroll
    for (int qt = 0; qt < 4; ++qt)
        *(f32x4*)(lb + ((size_t)(w * 4 + qt) * 64 + lane) * 4) = lac[qt];
    __syncthreads();
    float* Lm = (float*)(smem + 32768);
    if (t < 256) {
        int qt = t >> 6, ls = t & 63;
        f32x4 s = fz;
        #pragma unroll
        for (int ww = 0; ww < 8; ++ww)
            s += *(const f32x4*)(lb + ((size_t)(ww * 4 + qt) * 64 + ls) * 4);
        *(f32x4*)(Lm + ((size_t)qt * 64 + ls) * 4) = s;
    }
    __syncthreads();
    float* ab = (float*)smem;
    f32x4 meanv = fz;
    for (int qt = 0; qt < 4; ++qt) {
        #pragma unroll
        for (int n = 0; n < 4; ++n)
            *(f32x4*)(ab + ((size_t)(w * 4 + n) * 64 + lane) * 4) = am[qt][n];
        __syncthreads();
        if (t < 256) {
            int n = t >> 6, ls = t & 63;
            f32x4 s = fz;
            #pragma unroll
            for (int ww = 0; ww < 8; ++ww)
                s += *(const f32x4*)(ab + ((size_t)(ww * 4 + n) * 64 + ls) * 4);
            f32x4 lv = *(const f32x4*)(Lm + ((size_t)qt * 64 + ls) * 4);
            #pragma unroll
            for (int r = 0; r < 4; ++r) meanv[r] = s[r] / lv[r];
            int q0s = qbase + 16 * qt + 4 * (ls >> 4);
            int c   = 16 * n + (ls & 15);
            *(f32x4*)(mb + (size_t)b * CQ + (size_t)c * HW + q0s) = meanv;
        }
        __syncthreads();
        #pragma unroll
        for (int n = 0; n < 4; ++n)
            *(f32x4*)(ab + ((size_t)(w * 4 + n) * 64 + lane) * 4) = a2[qt][n];
        __syncthreads();
        if (t < 256) {
            int n = t >> 6, ls = t & 63;
            f32x4 s = fz;
            #pragma unroll
            for (int ww = 0; ww < 8; ++ww)
                s += *(const f32x4*)(ab + ((size_t)(ww * 4 + n) * 64 + ls) * 4);
            f32x4 lv = *(const f32x4*)(Lm + ((size_t)qt * 64 + ls) * 4);
            f32x4 sv;
            #pragma unroll
            for (int r = 0; r < 4; ++r) {
                float sec = s[r] / lv[r];
                sv[r] = sqrtf(fmaxf(sec - meanv[r] * meanv[r], 0.f));
            }
            int q0s = qbase + 16 * qt + 4 * (ls >> 4);
            int c   = 16 * n + (ls & 15);
            *(f32x4*)(sbuf + (size_t)b * CQ + (size_t)c * HW + q0s) = sv;
        }
        __syncthreads();
    }
}

// ---------------- fused: mvn stats + transfer + cbam channel pools
__global__ __launch_bounds__(256) void k_transfer_f(
    const float* __restrict__ mb, const float* __restrict__ sb,
    const float* __restrict__ FG, const float* __restrict__ BG, int bstride,
    float* __restrict__ xb, float* __restrict__ pavg, float* __restrict__ pmaxb)
{
    __shared__ float fgl[4096];
    __shared__ float r1[4], r2[4];
    const int bc = blockIdx.x, t = threadIdx.x;
    const int b = bc >> 6, c = bc & 63;
    const size_t row = (size_t)bc * HW;
    const float* fg = FG + (size_t)b * bstride + (size_t)(64 + c) * HW;
    const float* bg = BG + (size_t)b * bstride + (size_t)(64 + c) * HW;
    float s = 0.f, s2 = 0.f;
    #pragma unroll
    for (int j = 0; j < 16; ++j) {
        int i = t + j * 256;
        float v = fg[i];
        fgl[i] = v;
        s += v; s2 += v * v;
    }
    #pragma unroll
    for (int o = 32; o > 0; o >>= 1) { s += __shfl_down(s, o, 64); s2 += __shfl_down(s2, o, 64); }
    if ((t & 63) == 0) { r1[t >> 6] = s; r2[t >> 6] = s2; }
    __syncthreads();
    float m  = (r1[0] + r1[1] + r1[2] + r1[3]) * (1.0f / HW);
    float e2 = (r2[0] + r2[1] + r2[2] + r2[3]) * (1.0f / HW);
    float rs = rsqrtf(fmaxf(e2 - m * m, 0.f) + 1e-5f);
    float psum = 0.f, pmax = -1e30f;
    #pragma unroll
    for (int j = 0; j < 16; ++j) {
        int q = t + j * 256;
        float xv = sb[row + q] * (fgl[q] - m) * rs + mb[row + q] + bg[q];
        xb[row + q] = xv;
        psum += xv; pmax = fmaxf(pmax, xv);
    }
    __syncthreads();
    #pragma unroll
    for (int o = 32; o > 0; o >>= 1) {
        psum += __shfl_down(psum, o, 64);
        pmax = fmaxf(pmax, __shfl_down(pmax, o, 64));
    }
    if ((t & 63) == 0) { r1[t >> 6] = psum; r2[t >> 6] = pmax; }
    __syncthreads();
    if (t == 0) {
        pavg[bc]  = (r1[0] + r1[1] + r1[2] + r1[3]) * (1.0f / HW);
        pmaxb[bc] = fmaxf(fmaxf(r2[0], r2[1]), fmaxf(r2[2], r2[3]));
    }
}

// ---------------- CBAM channel-scale (recomputed per block)
static __device__ __forceinline__ void cbam_scale(
    const float* __restrict__ pav, const float* __restrict__ pmx,
    const float* __restrict__ w1, const float* __restrict__ b1,
    const float* __restrict__ w2, const float* __restrict__ b2,
    int b, int t, float* scb)
{
    __shared__ float za[4], zm[4];
    if (t < 4) {
        float aa = b1[t], am = b1[t];
        #pragma unroll 16
        for (int i = 0; i < 64; ++i) {
            aa = fmaf(w1[t * 64 + i], pav[b * 64 + i], aa);
            am = fmaf(w1[t * 64 + i], pmx[b * 64 + i], am);
        }
        za[t] = fmaxf(aa, 0.f);
        zm[t] = fmaxf(am, 0.f);
    }
    __syncthreads();
    if (t < 64) {
        float a = 2.f * b2[t];
        #pragma unroll
        for (int j = 0; j < 4; ++j) a = fmaf(w2[t * 4 + j], za[j] + zm[j], a);
        scb[t] = 1.f / (1.f + __expf(-a));
    }
    __syncthreads();
}

// ---------------- spatial pool of (xb*s) with inlined cbam MLP
__global__ __launch_bounds__(256) void k_sp_pool(
    const float* __restrict__ xb,
    const float* __restrict__ pav, const float* __restrict__ pmx,
    const float* __restrict__ w1, const float* __restrict__ b1,
    const float* __restrict__ w2, const float* __restrict__ b2,
    float* __restrict__ spm, float* __restrict__ spx)
{
    __shared__ float scb[64];
    const int b = blockIdx.y, t = threadIdx.x;
    cbam_scale(pav, pmx, w1, b1, w2, b2, b, t, scb);
    const int p = blockIdx.x * 256 + t;
    const float* xp = xb + (size_t)b * 262144 + p;
    float sum = 0.f, mx = -1e30f;
    #pragma unroll 8
    for (int c = 0; c < 64; ++c) {
        float v = xp[(size_t)c * HW] * scb[c];
        sum += v;
        mx = fmaxf(mx, v);
    }
    spm[b * HW + p] = sum * (1.0f / 64.0f);
    spx[b * HW + p] = mx;
}

// ---------------- fused 7x7 spatial conv + sigmoid + final output
__global__ __launch_bounds__(256) void k_spf(
    const float* __restrict__ spm, const float* __restrict__ spx,
    const float* __restrict__ w, const float* __restrict__ bias,
    const float* __restrict__ xb,
    const float* __restrict__ pav, const float* __restrict__ pmx,
    const float* __restrict__ w1, const float* __restrict__ b1,
    const float* __restrict__ w2, const float* __restrict__ b2,
    float* __restrict__ out)
{
    __shared__ float scb[64];
    const int b = blockIdx.y, t = threadIdx.x;
    cbam_scale(pav, pmx, w1, b1, w2, b2, b, t, scb);
    const int p = blockIdx.x * 256 + t;
    const int y = p >> 6, x = p & 63;
    float acc = bias[0];
    for (int dy = 0; dy < 7; ++dy) {
        int yy = y + dy - 3;
        if (yy < 0 || yy >= 64) continue;
        for (int dx = 0; dx < 7; ++dx) {
            int xx = x + dx - 3;
            if (xx < 0 || xx >= 64) continue;
            int q = b * HW + yy * 64 + xx;
            acc = fmaf(spm[q], w[dy * 7 + dx],      acc);
            acc = fmaf(spx[q], w[49 + dy * 7 + dx], acc);
        }
    }
    float sgm = 1.f / (1.f + __expf(-acc));
    const float* xp = xb + (size_t)b * 262144 + p;
    float* op = out + (size_t)b * 262144 + p;
    #pragma unroll 8
    for (int c = 0; c < 64; ++c)
        op[(size_t)c * HW] = xp[(size_t)c * HW] * scb[c] * sgm;
}

extern "C" void kernel_launch(void* const* d_in, const int* in_sizes, int n_in,
                              void* d_out, int out_size, void* d_ws, size_t ws_size,
                              hipStream_t stream)
{
    const float* group  = (const float*)d_in[0];
    const float* FG     = (const float*)d_in[1];
    const float* BG     = (const float*)d_in[2];
    const float* wg1    = (const float*)d_in[3];
    const float* bg1    = (const float*)d_in[4];
    const float* cag_w1 = (const float*)d_in[5];
    const float* cag_b1 = (const float*)d_in[6];
    const float* cag_w2 = (const float*)d_in[7];
    const float* cag_b2 = (const float*)d_in[8];
    const float* wg2    = (const float*)d_in[9];
    const float* bg2    = (const float*)d_in[10];
    const float* wg3    = (const float*)d_in[11];
    const float* bg3    = (const float*)d_in[12];
    const float* wc1    = (const float*)d_in[13];
    const float* bc1    = (const float*)d_in[14];
    const float* cac_w1 = (const float*)d_in[15];
    const float* cac_b1 = (const float*)d_in[16];
    const float* cac_w2 = (const float*)d_in[17];
    const float* cac_b2 = (const float*)d_in[18];
    const float* wc2    = (const float*)d_in[19];
    const float* bc2    = (const float*)d_in[20];
    const float* f_w    = (const float*)d_in[21];
    const float* f_b    = (const float*)d_in[22];
    const float* g_w    = (const float*)d_in[23];
    const float* g_b    = (const float*)d_in[24];
    const float* h_w    = (const float*)d_in[25];
    const float* h_b    = (const float*)d_in[26];
    const float* mlp_w1 = (const float*)d_in[27];
    const float* mlp_b1 = (const float*)d_in[28];
    const float* mlp_w2 = (const float*)d_in[29];
    const float* mlp_b2 = (const float*)d_in[30];
    const float* sp_w   = (const float*)d_in[31];
    const float* sp_b   = (const float*)d_in[32];
    float* out = (float*)d_out;

    const int B = 4;
    const size_t CHW = (size_t)64 * HW;
    const int BST = (int)(3 * CHW);

    float* ws = (float*)d_ws;
    const size_t M = 1048576;
    unsigned short* X0T  = (unsigned short*)ws;                 // [0,1.5M)f
    unsigned short* BGcT = (unsigned short*)(ws + 3 * M / 2);   // [1.5M,2M)
    unsigned short* FqT  = (unsigned short*)(ws + 2 * M);       // [2M,2.5M)
    unsigned short* GkT  = (unsigned short*)(ws + 5 * M / 2);   // [2.5M,3M)
    unsigned short* hvN  = (unsigned short*)(ws + 3 * M);       // [3M,3.5M)
    float* mbuf = ws + 7 * M / 2;   // [3.5M,4.5M)
    float* sbuf = ws + 9 * M / 2;   // [4.5M,5.5M)
    float* xb   = ws + 2 * M;       // overlays FqT/GkT (dead after attn)
    float* smalls = ws + 11 * M / 2;
    float* xmean = smalls;             // 768
    float* pav   = smalls + 1024;      // 256
    float* pmx   = smalls + 1280;      // 256
    float* biasQ = smalls + 1536;      // 256
    float* biasK = smalls + 1792;      // 256
    float* spm   = smalls + 2048;      // 16384
    float* spx   = smalls + 18432;     // 16384
    unsigned short* wsh = (unsigned short*)(smalls + 34816);
    unsigned short* WQb = wsh;              // 49152
    unsigned short* WKb = wsh + 49152;      // 16384
    unsigned short* whb = wsh + 65536;      // 4096

    dim3 blk(256);

    // 1. input transposes (X0T 192ch, BGcT 64ch)
    k_transpose2<<<dim3(64, B, 2), blk, 192 * 65 * 4, stream>>>(group, BG + CHW, BST, X0T, BGcT);
    // 2. channel means of group
    k_xmean<<<B * 192, blk, 0, stream>>>(group, BST, xmean);
    // 3. pools + MLPs + full weight composition (WQ, WK, biases, whb)
    k_mlp_compose<<<dim3(4, B), blk, 0, stream>>>(
        xmean, wg1, bg1, cag_w1, cag_b1, cag_w2, cag_b2,
        wc1, bc1, cac_w1, cac_b1, cac_w2, cac_b2,
        wg2, bg2, wg3, bg3, wc2, bc2,
        f_w, f_b, g_w, g_b, h_w,
        WQb, biasQ, WKb, biasK, whb);
    // 4. merged projections Fq/Gk/Hv
    k_proj<<<dim3(64, 3, B), blk, 0, stream>>>(
        X0T, BGcT, WQb, biasQ, WKb, biasK, whb, h_b, FqT, GkT, hvN);
    // 5. attention
    k_attn<<<256, 512, 0, stream>>>(FqT, GkT, hvN, mbuf, sbuf);
    // 6. fused mvn + transfer + cbam channel pools
    k_transfer_f<<<B * 64, blk, 0, stream>>>(mbuf, sbuf, FG, BG, BST, xb, pav, pmx);
    // 7/8. CBAM spatial
    k_sp_pool<<<dim3(HW / 256, B), blk, 0, stream>>>(xb, pav, pmx, mlp_w1, mlp_b1, mlp_w2, mlp_b2, spm, spx);
    k_spf<<<dim3(HW / 256, B), blk, 0, stream>>>(spm, spx, sp_w, sp_b, xb, pav, pmx, mlp_w1, mlp_b1, mlp_w2, mlp_b2, out);
}

// Round 15
// 164.484 us; speedup vs baseline: 2.4517x; 1.0667x over previous
//
#include <hip/hip_runtime.h>
#include <hip/hip_bf16.h>
#include <math.h>

#define HW 4096

typedef __attribute__((ext_vector_type(8))) short bf16x8;
typedef __attribute__((ext_vector_type(4))) float f32x4;

static __device__ __forceinline__ unsigned short f2bf(float x) {
    unsigned u = __float_as_uint(x);
    u += 0x7fffu + ((u >> 16) & 1u);     // RNE
    return (unsigned short)(u >> 16);
}
static __device__ __forceinline__ float bf2f(unsigned short h) {
    return __uint_as_float((unsigned)h << 16);
}
static __device__ __forceinline__ float g4(const float4& v, int k) {
    return k == 0 ? v.x : k == 1 ? v.y : k == 2 ? v.z : v.w;
}

// ---------------- combined transpose+bf16: z=0: group(192ch)->X0T; z=1: BGc(64ch)->BGcT
__global__ __launch_bounds__(256) void k_transpose2(
    const float* __restrict__ group, const float* __restrict__ BGc, int bstride,
    unsigned short* __restrict__ X0T, unsigned short* __restrict__ BGcT)
{
    extern __shared__ float lds[];          // [C][65]
    const int b = blockIdx.y, p0 = blockIdx.x << 6, t = threadIdx.x;
    const int z = blockIdx.z;
    const int C = z ? 64 : 192;
    const float* xb = (z ? BGc : group) + (size_t)b * bstride;
    unsigned short* outT = z ? BGcT : X0T;
    for (int idx = t; idx < (C << 6); idx += 256) {
        int c = idx >> 6, p = idx & 63;
        lds[c * 65 + p] = xb[(size_t)c * HW + p0 + p];
    }
    __syncthreads();
    unsigned short* ob = outT + ((size_t)b * HW + p0) * C;
    for (int idx = t; idx < (C << 6); idx += 256) {
        int p = idx / C, c = idx - p * C;
        ob[idx] = f2bf(lds[c * 65 + p]);
    }
}

// ---------------- per-(b,ci) mean over pixels of `group` (192 channels)
__global__ __launch_bounds__(256) void k_xmean(
    const float* __restrict__ g, int bstride, float* __restrict__ xmean)
{
    int bc = blockIdx.x;                 // B*192
    int b = bc / 192, ci = bc - b * 192;
    const float* p = g + (size_t)b * bstride + (size_t)ci * HW;
    int t = threadIdx.x;
    float s = 0.f;
    #pragma unroll 4
    for (int i = t; i < HW; i += 256) s += p[i];
    for (int o = 32; o > 0; o >>= 1) s += __shfl_down(s, o, 64);
    __shared__ float red[4];
    if ((t & 63) == 0) red[t >> 6] = s;
    __syncthreads();
    if (t == 0) xmean[bc] = (red[0] + red[1] + red[2] + red[3]) * (1.0f / HW);
}

// 4x4 register-tiled 64x64x64 f32 GEMM from padded LDS (A[64][68], B[64][68] as B[k][c])
static __device__ __forceinline__ void gemm64_tile(
    const float* A, const float* B, int t, float acc[4][4])
{
    const int tr = t >> 4, tc = t & 15;
    #pragma unroll
    for (int i = 0; i < 4; ++i)
        #pragma unroll
        for (int j = 0; j < 4; ++j) acc[i][j] = 0.f;
    for (int k4 = 0; k4 < 64; k4 += 4) {
        float4 a[4], bb[4];
        #pragma unroll
        for (int i = 0; i < 4; ++i) a[i]  = *(const float4*)&A[(4 * tr + i) * 68 + k4];
        #pragma unroll
        for (int kk = 0; kk < 4; ++kk) bb[kk] = *(const float4*)&B[(k4 + kk) * 68 + 4 * tc];
        #pragma unroll
        for (int i = 0; i < 4; ++i)
            #pragma unroll
            for (int kk = 0; kk < 4; ++kk)
                #pragma unroll
                for (int j = 0; j < 4; ++j)
                    acc[i][j] = fmaf(g4(a[i], kk), g4(bb[kk], j), acc[i][j]);
    }
}

// ---------------- prep: bid<4 = scales(b) role; bid>=4 = weight-chain(x) role.
// chain: V=wf@wg3; W3L=log2e*V@wg2 [64x192]; U=wg@wc2; bQ0L=log2e*(V@bg2+wf@bg3+fb);
//        bK0=wg@bc2+g_b; wg1b=bf16(wg1).
// scales: s_g[b],s_c[b] from xmean-pools + CA MLPs; whb (b==0).
__global__ __launch_bounds__(256) void k_prep(
    const float* __restrict__ xmean,
    const float* __restrict__ wg1, const float* __restrict__ bg1,
    const float* __restrict__ cag_w1, const float* __restrict__ cag_b1,
    const float* __restrict__ cag_w2, const float* __restrict__ cag_b2,
    const float* __restrict__ wc1, const float* __restrict__ bc1,
    const float* __restrict__ cac_w1, const float* __restrict__ cac_b1,
    const float* __restrict__ cac_w2, const float* __restrict__ cac_b2,
    const float* __restrict__ wg2, const float* __restrict__ bg2,
    const float* __restrict__ wg3, const float* __restrict__ bg3,
    const float* __restrict__ wc2, const float* __restrict__ bc2,
    const float* __restrict__ wf, const float* __restrict__ fb,
    const float* __restrict__ wgw, const float* __restrict__ gbv,
    const float* __restrict__ wh,
    float* __restrict__ W3L, float* __restrict__ Uf,
    float* __restrict__ bQ0L, float* __restrict__ bK0,
    float* __restrict__ sgG, float* __restrict__ scG,
    unsigned short* __restrict__ whb, unsigned short* __restrict__ wg1b)
{
    const float LOG2E = 1.4426950408889634f;
    __shared__ float sA[64 * 68], sB[64 * 68], sC[64 * 68];
    __shared__ float xm[192], pg[192], pc[64], zz[16];
    const int bid = blockIdx.x, t = threadIdx.x;

    if (bid >= 4) {
        const int x = bid - 4;
        #pragma unroll
        for (int j = 0; j < 16; ++j) {
            int idx = t + j * 256, r = idx >> 6, c = idx & 63;
            sA[r * 68 + c] = wf[idx];
            sB[r * 68 + c] = wg3[idx];
        }
        __syncthreads();
        float acc[4][4];
        gemm64_tile(sA, sB, t, acc);                   // V = wf@wg3
        {
            const int tr = t >> 4, tc = t & 15;
            #pragma unroll
            for (int i = 0; i < 4; ++i)
                #pragma unroll
                for (int j = 0; j < 4; ++j)
                    sC[(4 * tr + i) * 68 + 4 * tc + j] = acc[i][j];
        }
        __syncthreads();
        if (x == 0 && t < 64) {                        // bQ0L (reads sC=V, sA=wf)
            float a = fb[t];
            #pragma unroll 16
            for (int m = 0; m < 64; ++m) {
                a = fmaf(sC[t * 68 + m], bg2[m], a);
                a = fmaf(sA[t * 68 + m], bg3[m], a);
            }
            bQ0L[t] = a * LOG2E;
        }
        __syncthreads();
        // stage wg2 slice transposed: sA[c][m] = wg2[m][x*48+c]
        for (int idx = t; idx < 3072; idx += 256) {
            int c = idx >> 6, m = idx & 63;
            sA[c * 68 + m] = wg2[m * 192 + x * 48 + c];
        }
        __syncthreads();
        // W3L slice = LOG2E * V @ wg2slice : rows 4/thr, cols 3/thr
        {
            const int tr = t >> 4, tc = t & 15;
            float a2[4][3];
            #pragma unroll
            for (int i = 0; i < 4; ++i)
                #pragma unroll
                for (int j = 0; j < 3; ++j) a2[i][j] = 0.f;
            for (int k4 = 0; k4 < 64; k4 += 4) {
                float4 a[4], bb[3];
                #pragma unroll
                for (int i = 0; i < 4; ++i) a[i] = *(const float4*)&sC[(4 * tr + i) * 68 + k4];
                #pragma unroll
                for (int j = 0; j < 3; ++j) bb[j] = *(const float4*)&sA[(3 * tc + j) * 68 + k4];
                #pragma unroll
                for (int i = 0; i < 4; ++i)
                    #pragma unroll
                    for (int j = 0; j < 3; ++j)
                        #pragma unroll
                        for (int kk = 0; kk < 4; ++kk)
                            a2[i][j] = fmaf(g4(a[i], kk), g4(bb[j], kk), a2[i][j]);
            }
            #pragma unroll
            for (int i = 0; i < 4; ++i)
                #pragma unroll
                for (int j = 0; j < 3; ++j)
                    W3L[(4 * tr + i) * 192 + x * 48 + 3 * tc + j] = a2[i][j] * LOG2E;
        }
        if (x == 1) {                                   // U = wg@wc2, bK0
            __syncthreads();
            #pragma unroll
            for (int j = 0; j < 16; ++j) {
                int idx = t + j * 256, r = idx >> 6, c = idx & 63;
                sA[r * 68 + c] = wgw[idx];
                sB[r * 68 + c] = wc2[idx];
            }
            __syncthreads();
            float au[4][4];
            gemm64_tile(sA, sB, t, au);
            {
                const int tr = t >> 4, tc = t & 15;
                #pragma unroll
                for (int i = 0; i < 4; ++i)
                    #pragma unroll
                    for (int j = 0; j < 4; ++j)
                        Uf[(4 * tr + i) * 64 + 4 * tc + j] = au[i][j];
            }
            if (t < 64) {
                float a = gbv[t];
                #pragma unroll 16
                for (int m = 0; m < 64; ++m) a = fmaf(sA[t * 68 + m], bc2[m], a);
                bK0[t] = a;
            }
        }
        // wg1 -> bf16, spread over 4 chain blocks
        for (int idx = t; idx < 9216; idx += 256) {
            int g = x * 9216 + idx;
            wg1b[g] = f2bf(wg1[g]);
        }
        return;
    }

    // ---- scales role: b = bid
    const int b = bid, w = t >> 6, lane = t & 63;
    if (t < 192) xm[t] = xmean[b * 192 + t];
    __syncthreads();
    for (int r = w; r < 192; r += 4) {              // pool_g rows (coalesced wave-dots)
        float part = 0.f;
        #pragma unroll
        for (int j = 0; j < 3; ++j)
            part = fmaf(wg1[r * 192 + lane + 64 * j], xm[lane + 64 * j], part);
        #pragma unroll
        for (int o = 32; o > 0; o >>= 1) part += __shfl_down(part, o, 64);
        if (lane == 0) pg[r] = part + bg1[r];
    }
    for (int r = w; r < 64; r += 4) {               // pool_c rows
        float part = wc1[r * 64 + lane] * xm[64 + lane];
        #pragma unroll
        for (int o = 32; o > 0; o >>= 1) part += __shfl_down(part, o, 64);
        if (lane == 0) pc[r] = part + bc1[r];
    }
    __syncthreads();
    if (t < 12) {
        float a = cag_b1[t];
        #pragma unroll 16
        for (int i = 0; i < 192; ++i) a = fmaf(cag_w1[t * 192 + i], pg[i], a);
        zz[t] = fmaxf(a, 0.f);
    }
    if (t >= 64 && t < 68) {
        int r = t - 64;
        float a = cac_b1[r];
        #pragma unroll 16
        for (int i = 0; i < 64; ++i) a = fmaf(cac_w1[r * 64 + i], pc[i], a);
        zz[12 + r] = fmaxf(a, 0.f);
    }
    __syncthreads();
    if (t < 192) {
        float a = cag_b2[t];
        #pragma unroll
        for (int j = 0; j < 12; ++j) a = fmaf(cag_w2[t * 12 + j], zz[j], a);
        sgG[b * 192 + t] = 1.f / (1.f + __expf(-a));
    } else {
        int c = t - 192;
        float a = cac_b2[c];
        #pragma unroll
        for (int j = 0; j < 4; ++j) a = fmaf(cac_w2[c * 4 + j], zz[12 + j], a);
        scG[b * 64 + c] = 1.f / (1.f + __expf(-a));
    }
    if (b == 0) {
        #pragma unroll
        for (int j = 0; j < 16; ++j) whb[t + j * 256] = f2bf(wh[t + j * 256]);
    }
}

// ---------------- per-batch finalize: bid<192 -> WQs = bf16(W3L . s_g-col);
// bid 192..195 -> per-batch WK = (U.diag(s_c))@wc1 (bf16) + biasK.
__global__ __launch_bounds__(256) void k_wscale(
    const float* __restrict__ W3L, const float* __restrict__ Uf,
    const float* __restrict__ sgG, const float* __restrict__ scG,
    const float* __restrict__ wc1, const float* __restrict__ bc1,
    const float* __restrict__ bK0,
    unsigned short* __restrict__ WQs, unsigned short* __restrict__ WKb,
    float* __restrict__ biasK)
{
    const int bid = blockIdx.x, t = threadIdx.x;
    if (bid < 192) {
        int i = bid * 256 + t;                // [0, 49152)
        int b = i / 12288, rem = i - b * 12288;
        int c = rem % 192;
        WQs[i] = f2bf(W3L[rem] * sgG[b * 192 + c]);
        return;
    }
    __shared__ float Usc[64 * 68], sW[64 * 68], u2[64];
    const int b = bid - 192;
    #pragma unroll
    for (int j = 0; j < 16; ++j) {
        int idx = t + j * 256, r = idx >> 6, c = idx & 63;
        Usc[r * 68 + c] = Uf[idx] * scG[b * 64 + c];
        sW[r * 68 + c]  = wc1[idx];
    }
    if (t < 64) u2[t] = scG[b * 64 + t] * bc1[t];
    __syncthreads();
    float acc[4][4];
    gemm64_tile(Usc, sW, t, acc);                  // WK = (U.sc) @ wc1
    const int tr = t >> 4, tc = t & 15;
    #pragma unroll
    for (int i = 0; i < 4; ++i)
        #pragma unroll
        for (int j = 0; j < 4; ++j)
            WKb[(size_t)b * 4096 + (4 * tr + i) * 64 + 4 * tc + j] = f2bf(acc[i][j]);
    if (t < 64) {
        float a = bK0[t];
        #pragma unroll 16
        for (int m = 0; m < 64; ++m) a = fmaf(Uf[t * 64 + m], u2[m], a);
        biasK[b * 64 + t] = a;
    }
}

// ---------------- MFMA conv: g1T = bf16(wg1 @ X0 + bg1)  (Cin=Cout=192)
__global__ __launch_bounds__(256) void k_gconv(
    const unsigned short* __restrict__ X0T, const unsigned short* __restrict__ wg1b,
    const float* __restrict__ bg1, unsigned short* __restrict__ g1T)
{
    const int t = threadIdx.x;
    const int w = t >> 6, lane = t & 63;
    const int gid = lane >> 4, cid = lane & 15;
    const int b = blockIdx.z;
    const int p0 = blockIdx.x << 6;
    const int co16 = ((blockIdx.y << 2) + w) << 4;
    const unsigned short* xrow = X0T + (size_t)b * HW * 192;
    const unsigned short* wr = wg1b + (size_t)co16 * 192;
    f32x4 acc[4];
    #pragma unroll
    for (int n = 0; n < 4; ++n)
        #pragma unroll
        for (int r = 0; r < 4; ++r)
            acc[n][r] = bg1[co16 + 4 * gid + r];
    for (int kc = 0; kc < 192; kc += 32) {
        bf16x8 a = *(const bf16x8*)(wr + (size_t)cid * 192 + kc + 8 * gid);
        #pragma unroll
        for (int n = 0; n < 4; ++n) {
            bf16x8 bfr = *(const bf16x8*)(xrow + (size_t)(p0 + 16 * n + cid) * 192 + kc + 8 * gid);
            acc[n] = __builtin_amdgcn_mfma_f32_16x16x32_bf16(a, bfr, acc[n], 0, 0, 0);
        }
    }
    #pragma unroll
    for (int n = 0; n < 4; ++n)
        #pragma unroll
        for (int r = 0; r < 4; ++r)
            g1T[((size_t)b * HW + p0 + 16 * n + cid) * 192 + co16 + 4 * gid + r] = f2bf(acc[n][r]);
}

// ---------------- merged MFMA projections: y=0 Fq (g1T,K=192), y=1 Gk (X0T@64,K=64), y=2 Hv
__global__ __launch_bounds__(256) void k_proj(
    const unsigned short* __restrict__ g1T, const unsigned short* __restrict__ X0T,
    const unsigned short* __restrict__ BGcT,
    const unsigned short* __restrict__ WQs, const float* __restrict__ bQ0L,
    const unsigned short* __restrict__ WKb, const float* __restrict__ biasK,
    const unsigned short* __restrict__ whb, const float* __restrict__ h_b,
    unsigned short* __restrict__ FqT, unsigned short* __restrict__ GkT,
    unsigned short* __restrict__ hvN)
{
    const int t = threadIdx.x;
    const int w = t >> 6, lane = t & 63;
    const int gid = lane >> 4, cid = lane & 15;
    const int which = blockIdx.y;
    const int b = blockIdx.z;
    const int p0 = blockIdx.x << 6;
    const int co16 = w << 4;
    int Cin, kOff, ldx;
    const unsigned short *XT, *W;
    const float* bp;
    if (which == 0)      { XT = g1T;  ldx = 192; kOff = 0;  Cin = 192; W = WQs + (size_t)b * 12288; bp = bQ0L; }
    else if (which == 1) { XT = X0T;  ldx = 192; kOff = 64; Cin = 64;  W = WKb + (size_t)b * 4096;  bp = biasK + b * 64; }
    else                 { XT = BGcT; ldx = 64;  kOff = 0;  Cin = 64;  W = whb;                      bp = h_b; }
    const unsigned short* xrow = XT + (size_t)b * HW * ldx + kOff;
    const unsigned short* wr = W + (size_t)co16 * Cin;
    f32x4 acc[4];
    #pragma unroll
    for (int n = 0; n < 4; ++n)
        #pragma unroll
        for (int r = 0; r < 4; ++r)
            acc[n][r] = bp[co16 + 4 * gid + r];
    for (int kc = 0; kc < Cin; kc += 32) {
        bf16x8 a = *(const bf16x8*)(wr + (size_t)cid * Cin + kc + 8 * gid);
        #pragma unroll
        for (int n = 0; n < 4; ++n) {
            bf16x8 bfr = *(const bf16x8*)(xrow + (size_t)(p0 + 16 * n + cid) * ldx + kc + 8 * gid);
            acc[n] = __builtin_amdgcn_mfma_f32_16x16x32_bf16(a, bfr, acc[n], 0, 0, 0);
        }
    }
    #pragma unroll
    for (int n = 0; n < 4; ++n)
        #pragma unroll
        for (int r = 0; r < 4; ++r) {
            float v = acc[n][r];
            int co = co16 + 4 * gid + r;
            int p  = p0 + 16 * n + cid;
            if (which == 0)      FqT[((size_t)b * HW + p) * 64 + co] = f2bf(v);
            else if (which == 1) GkT[((size_t)b * HW + p) * 64 + co] = f2bf(v);
            else                 hvN[((size_t)b * 64 + co) * HW + p] = f2bf(v);
        }
}

// ---------------- MFMA attention (proven round-8/11 config, exp2, in-reg Hv^2).
__global__ __launch_bounds__(512, 2) void k_attn(
    const unsigned short* __restrict__ FqT, const unsigned short* __restrict__ GkT,
    const unsigned short* __restrict__ HvN,
    float* __restrict__ mb, float* __restrict__ sbuf)
{
    __shared__ __align__(16) char smem[65536];
    const int t = threadIdx.x;
    const int bid = blockIdx.x;
    const int b = (bid & 7) >> 1;
    const int qbase = (((bid >> 3) << 1) | (bid & 1)) << 6;
    const int w = t >> 6, lane = t & 63;
    const int gid = lane >> 4, cid = lane & 15;
    const size_t CQ = (size_t)HW * 64;
    const unsigned short* fqt = FqT + (size_t)b * CQ;
    const unsigned short* gkt = GkT + (size_t)b * CQ;
    const unsigned short* hv  = HvN + (size_t)b * CQ;
    unsigned short* Pw = (unsigned short*)smem + w * 4096;

    bf16x8 fqa[4][2];
    #pragma unroll
    for (int qt = 0; qt < 4; ++qt) {
        const unsigned short* fr = fqt + (size_t)(qbase + 16 * qt + cid) * 64 + 8 * gid;
        fqa[qt][0] = *(const bf16x8*)fr;
        fqa[qt][1] = *(const bf16x8*)(fr + 32);
    }
    bf16x8 ones;
    #pragma unroll
    for (int j = 0; j < 8; ++j) ones[j] = (short)0x3F80;

    const f32x4 fz = {0.f, 0.f, 0.f, 0.f};
    f32x4 am[4][4], a2[4][4], lac[4];
    #pragma unroll
    for (int qt = 0; qt < 4; ++qt) {
        lac[qt] = fz;
        #pragma unroll
        for (int n = 0; n < 4; ++n) { am[qt][n] = fz; a2[qt][n] = fz; }
    }

    const int k00 = w << 9;
    for (int it = 0; it < 8; ++it) {
        const int k0 = k00 + (it << 6);
        #pragma unroll
        for (int n = 0; n < 4; ++n) {
            const unsigned short* gr = gkt + (size_t)(k0 + 16 * n + cid) * 64 + 8 * gid;
            bf16x8 b0 = *(const bf16x8*)gr;
            bf16x8 b1 = *(const bf16x8*)(gr + 32);
            const int k = 16 * n + cid;
            #pragma unroll
            for (int qt = 0; qt < 4; ++qt) {
                f32x4 s = __builtin_amdgcn_mfma_f32_16x16x32_bf16(fqa[qt][0], b0, fz, 0, 0, 0);
                s = __builtin_amdgcn_mfma_f32_16x16x32_bf16(fqa[qt][1], b1, s, 0, 0, 0);
                #pragma unroll
                for (int r = 0; r < 4; ++r) {
                    int q = 4 * gid + r;
                    Pw[qt * 1024 + q * 64 + (((k >> 3) ^ (q & 7)) << 3) + (k & 7)] =
                        f2bf(__builtin_amdgcn_exp2f(s[r]));
                }
            }
        }
        bf16x8 pa[4][2];
        #pragma unroll
        for (int qt = 0; qt < 4; ++qt)
            #pragma unroll
            for (int kh = 0; kh < 2; ++kh)
                pa[qt][kh] = *(const bf16x8*)(Pw + qt * 1024 + cid * 64 +
                                              (((4 * kh + gid) ^ (cid & 7)) << 3));
        #pragma unroll
        for (int qt = 0; qt < 4; ++qt) {
            lac[qt] = __builtin_amdgcn_mfma_f32_16x16x32_bf16(pa[qt][0], ones, lac[qt], 0, 0, 0);
            lac[qt] = __builtin_amdgcn_mfma_f32_16x16x32_bf16(pa[qt][1], ones, lac[qt], 0, 0, 0);
        }
        #pragma unroll
        for (int n = 0; n < 4; ++n) {
            const unsigned short* hr = hv + (size_t)(16 * n + cid) * HW + k0;
            #pragma unroll
            for (int kh = 0; kh < 2; ++kh) {
                bf16x8 hb = *(const bf16x8*)(hr + 32 * kh + 8 * gid);
                bf16x8 h2;
                #pragma unroll
                for (int j = 0; j < 8; ++j) {
                    float v = bf2f((unsigned short)hb[j]);
                    h2[j] = (short)f2bf(v * v);
                }
                #pragma unroll
                for (int qt = 0; qt < 4; ++qt) {
                    am[qt][n] = __builtin_amdgcn_mfma_f32_16x16x32_bf16(pa[qt][kh], hb, am[qt][n], 0, 0, 0);
                    a2[qt][n] = __builtin_amdgcn_mfma_f32_16x16x32_bf16(pa[qt][kh], h2, a2[qt][n], 0, 0, 0);
                }
            }
        }
    }

    __syncthreads();
    float* lb = (float*)smem;
    #pragma unroll
    for (int qt = 0; qt < 4; ++qt)
        *(f32x4*)(lb + ((size_t)(w * 4 + qt) * 64 + lane) * 4) = lac[qt];
    __syncthreads();
    float* Lm = (float*)(smem + 32768);
    if (t < 256) {
        int qt = t >> 6, ls = t & 63;
        f32x4 s = fz;
        #pragma unroll
        for (int ww = 0; ww < 8; ++ww)
            s += *(const f32x4*)(lb + ((size_t)(ww * 4 + qt) * 64 + ls) * 4);
        *(f32x4*)(Lm + ((size_t)qt * 64 + ls) * 4) = s;
    }
    __syncthreads();
    float* ab = (float*)smem;
    f32x4 meanv = fz;
    for (int qt = 0; qt < 4; ++qt) {
        #pragma unroll
        for (int n = 0; n < 4; ++n)
            *(f32x4*)(ab + ((size_t)(w * 4 + n) * 64 + lane) * 4) = am[qt][n];
        __syncthreads();
        if (t < 256) {
            int n = t >> 6, ls = t & 63;
            f32x4 s = fz;
            #pragma unroll
            for (int ww = 0; ww < 8; ++ww)
                s += *(const f32x4*)(ab + ((size_t)(ww * 4 + n) * 64 + ls) * 4);
            f32x4 lv = *(const f32x4*)(Lm + ((size_t)qt * 64 + ls) * 4);
            #pragma unroll
            for (int r = 0; r < 4; ++r) meanv[r] = s[r] / lv[r];
            int q0s = qbase + 16 * qt + 4 * (ls >> 4);
            int c   = 16 * n + (ls & 15);
            *(f32x4*)(mb + (size_t)b * CQ + (size_t)c * HW + q0s) = meanv;
        }
        __syncthreads();
        #pragma unroll
        for (int n = 0; n < 4; ++n)
            *(f32x4*)(ab + ((size_t)(w * 4 + n) * 64 + lane) * 4) = a2[qt][n];
        __syncthreads();
        if (t < 256) {
            int n = t >> 6, ls = t & 63;
            f32x4 s = fz;
            #pragma unroll
            for (int ww = 0; ww < 8; ++ww)
                s += *(const f32x4*)(ab + ((size_t)(ww * 4 + n) * 64 + ls) * 4);
            f32x4 lv = *(const f32x4*)(Lm + ((size_t)qt * 64 + ls) * 4);
            f32x4 sv;
            #pragma unroll
            for (int r = 0; r < 4; ++r) {
                float sec = s[r] / lv[r];
                sv[r] = sqrtf(fmaxf(sec - meanv[r] * meanv[r], 0.f));
            }
            int q0s = qbase + 16 * qt + 4 * (ls >> 4);
            int c   = 16 * n + (ls & 15);
            *(f32x4*)(sbuf + (size_t)b * CQ + (size_t)c * HW + q0s) = sv;
        }
        __syncthreads();
    }
}

// ---------------- fused: mvn stats + transfer + cbam channel pools
__global__ __launch_bounds__(256) void k_transfer_f(
    const float* __restrict__ mb, const float* __restrict__ sb,
    const float* __restrict__ FG, const float* __restrict__ BG, int bstride,
    float* __restrict__ xb, float* __restrict__ pavg, float* __restrict__ pmaxb)
{
    __shared__ float fgl[4096];
    __shared__ float r1[4], r2[4];
    const int bc = blockIdx.x, t = threadIdx.x;
    const int b = bc >> 6, c = bc & 63;
    const size_t row = (size_t)bc * HW;
    const float* fg = FG + (size_t)b * bstride + (size_t)(64 + c) * HW;
    const float* bg = BG + (size_t)b * bstride + (size_t)(64 + c) * HW;
    float s = 0.f, s2 = 0.f;
    #pragma unroll
    for (int j = 0; j < 16; ++j) {
        int i = t + j * 256;
        float v = fg[i];
        fgl[i] = v;
        s += v; s2 += v * v;
    }
    #pragma unroll
    for (int o = 32; o > 0; o >>= 1) { s += __shfl_down(s, o, 64); s2 += __shfl_down(s2, o, 64); }
    if ((t & 63) == 0) { r1[t >> 6] = s; r2[t >> 6] = s2; }
    __syncthreads();
    float m  = (r1[0] + r1[1] + r1[2] + r1[3]) * (1.0f / HW);
    float e2 = (r2[0] + r2[1] + r2[2] + r2[3]) * (1.0f / HW);
    float rs = rsqrtf(fmaxf(e2 - m * m, 0.f) + 1e-5f);
    float psum = 0.f, pmax = -1e30f;
    #pragma unroll
    for (int j = 0; j < 16; ++j) {
        int q = t + j * 256;
        float xv = sb[row + q] * (fgl[q] - m) * rs + mb[row + q] + bg[q];
        xb[row + q] = xv;
        psum += xv; pmax = fmaxf(pmax, xv);
    }
    __syncthreads();
    #pragma unroll
    for (int o = 32; o > 0; o >>= 1) {
        psum += __shfl_down(psum, o, 64);
        pmax = fmaxf(pmax, __shfl_down(pmax, o, 64));
    }
    if ((t & 63) == 0) { r1[t >> 6] = psum; r2[t >> 6] = pmax; }
    __syncthreads();
    if (t == 0) {
        pavg[bc]  = (r1[0] + r1[1] + r1[2] + r1[3]) * (1.0f / HW);
        pmaxb[bc] = fmaxf(fmaxf(r2[0], r2[1]), fmaxf(r2[2], r2[3]));
    }
}

// ---------------- CBAM channel-scale (recomputed per block)
static __device__ __forceinline__ void cbam_scale(
    const float* __restrict__ pav, const float* __restrict__ pmx,
    const float* __restrict__ w1, const float* __restrict__ b1,
    const float* __restrict__ w2, const float* __restrict__ b2,
    int b, int t, float* scb)
{
    __shared__ float za[4], zm[4];
    if (t < 4) {
        float aa = b1[t], am = b1[t];
        #pragma unroll 16
        for (int i = 0; i < 64; ++i) {
            aa = fmaf(w1[t * 64 + i], pav[b * 64 + i], aa);
            am = fmaf(w1[t * 64 + i], pmx[b * 64 + i], am);
        }
        za[t] = fmaxf(aa, 0.f);
        zm[t] = fmaxf(am, 0.f);
    }
    __syncthreads();
    if (t < 64) {
        float a = 2.f * b2[t];
        #pragma unroll
        for (int j = 0; j < 4; ++j) a = fmaf(w2[t * 4 + j], za[j] + zm[j], a);
        scb[t] = 1.f / (1.f + __expf(-a));
    }
    __syncthreads();
}

// ---------------- spatial pool of (xb*s) with inlined cbam MLP
__global__ __launch_bounds__(256) void k_sp_pool(
    const float* __restrict__ xb,
    const float* __restrict__ pav, const float* __restrict__ pmx,
    const float* __restrict__ w1, const float* __restrict__ b1,
    const float* __restrict__ w2, const float* __restrict__ b2,
    float* __restrict__ spm, float* __restrict__ spx)
{
    __shared__ float scb[64];
    const int b = blockIdx.y, t = threadIdx.x;
    cbam_scale(pav, pmx, w1, b1, w2, b2, b, t, scb);
    const int p = blockIdx.x * 256 + t;
    const float* xp = xb + (size_t)b * 262144 + p;
    float sum = 0.f, mx = -1e30f;
    #pragma unroll 8
    for (int c = 0; c < 64; ++c) {
        float v = xp[(size_t)c * HW] * scb[c];
        sum += v;
        mx = fmaxf(mx, v);
    }
    spm[b * HW + p] = sum * (1.0f / 64.0f);
    spx[b * HW + p] = mx;
}

// ---------------- fused 7x7 spatial conv + sigmoid + final output
__global__ __launch_bounds__(256) void k_spf(
    const float* __restrict__ spm, const float* __restrict__ spx,
    const float* __restrict__ w, const float* __restrict__ bias,
    const float* __restrict__ xb,
    const float* __restrict__ pav, const float* __restrict__ pmx,
    const float* __restrict__ w1, const float* __restrict__ b1,
    const float* __restrict__ w2, const float* __restrict__ b2,
    float* __restrict__ out)
{
    __shared__ float scb[64];
    const int b = blockIdx.y, t = threadIdx.x;
    cbam_scale(pav, pmx, w1, b1, w2, b2, b, t, scb);
    const int p = blockIdx.x * 256 + t;
    const int y = p >> 6, x = p & 63;
    float acc = bias[0];
    for (int dy = 0; dy < 7; ++dy) {
        int yy = y + dy - 3;
        if (yy < 0 || yy >= 64) continue;
        for (int dx = 0; dx < 7; ++dx) {
            int xx = x + dx - 3;
            if (xx < 0 || xx >= 64) continue;
            int q = b * HW + yy * 64 + xx;
            acc = fmaf(spm[q], w[dy * 7 + dx],      acc);
            acc = fmaf(spx[q], w[49 + dy * 7 + dx], acc);
        }
    }
    float sgm = 1.f / (1.f + __expf(-acc));
    const float* xp = xb + (size_t)b * 262144 + p;
    float* op = out + (size_t)b * 262144 + p;
    #pragma unroll 8
    for (int c = 0; c < 64; ++c)
        op[(size_t)c * HW] = xp[(size_t)c * HW] * scb[c] * sgm;
}

extern "C" void kernel_launch(void* const* d_in, const int* in_sizes, int n_in,
                              void* d_out, int out_size, void* d_ws, size_t ws_size,
                              hipStream_t stream)
{
    const float* group  = (const float*)d_in[0];
    const float* FG     = (const float*)d_in[1];
    const float* BG     = (const float*)d_in[2];
    const float* wg1    = (const float*)d_in[3];
    const float* bg1    = (const float*)d_in[4];
    const float* cag_w1 = (const float*)d_in[5];
    const float* cag_b1 = (const float*)d_in[6];
    const float* cag_w2 = (const float*)d_in[7];
    const float* cag_b2 = (const float*)d_in[8];
    const float* wg2    = (const float*)d_in[9];
    const float* bg2    = (const float*)d_in[10];
    const float* wg3    = (const float*)d_in[11];
    const float* bg3    = (const float*)d_in[12];
    const float* wc1    = (const float*)d_in[13];
    const float* bc1    = (const float*)d_in[14];
    const float* cac_w1 = (const float*)d_in[15];
    const float* cac_b1 = (const float*)d_in[16];
    const float* cac_w2 = (const float*)d_in[17];
    const float* cac_b2 = (const float*)d_in[18];
    const float* wc2    = (const float*)d_in[19];
    const float* bc2    = (const float*)d_in[20];
    const float* f_w    = (const float*)d_in[21];
    const float* f_b    = (const float*)d_in[22];
    const float* g_w    = (const float*)d_in[23];
    const float* g_b    = (const float*)d_in[24];
    const float* h_w    = (const float*)d_in[25];
    const float* h_b    = (const float*)d_in[26];
    const float* mlp_w1 = (const float*)d_in[27];
    const float* mlp_b1 = (const float*)d_in[28];
    const float* mlp_w2 = (const float*)d_in[29];
    const float* mlp_b2 = (const float*)d_in[30];
    const float* sp_w   = (const float*)d_in[31];
    const float* sp_b   = (const float*)d_in[32];
    float* out = (float*)d_out;

    const int B = 4;
    const size_t CHW = (size_t)64 * HW;
    const int BST = (int)(3 * CHW);

    float* ws = (float*)d_ws;
    const size_t M = 1048576;
    unsigned short* X0T  = (unsigned short*)ws;                 // [0,1.5M)f
    unsigned short* BGcT = (unsigned short*)(ws + 3 * M / 2);   // [1.5M,2M)
    unsigned short* g1T  = (unsigned short*)(ws + 2 * M);       // [2M,3.5M)
    unsigned short* FqT  = (unsigned short*)(ws + 7 * M / 2);   // [3.5M,4M)
    unsigned short* GkT  = (unsigned short*)(ws + 4 * M);       // [4M,4.5M)
    unsigned short* hvN  = (unsigned short*)(ws + 9 * M / 2);   // [4.5M,5M)
    float* mbuf = ws + 5 * M;       // [5M,6M)
    float* sbuf = ws + 6 * M;       // [6M,7M)
    float* xb   = ws;               // [0,1M) over X0T (dead after proj)
    float* smalls = ws + 7 * M;
    float* xmean = smalls;             // 768
    float* sgG   = smalls + 768;       // 768
    float* scG   = smalls + 1536;      // 256
    float* pav   = smalls + 1792;      // 256
    float* pmx   = smalls + 2048;      // 256
    float* biasK = smalls + 2304;      // 256
    float* bQ0L  = smalls + 2560;      // 64
    float* bK0   = smalls + 2624;      // 64
    float* Uf    = smalls + 2688;      // 4096
    float* W3L   = smalls + 6784;      // 12288
    float* spm   = smalls + 19072;     // 16384
    float* spx   = smalls + 35456;     // 16384
    unsigned short* wsh = (unsigned short*)(smalls + 51840);
    unsigned short* WQs  = wsh;              // 49152
    unsigned short* WKb  = wsh + 49152;      // 16384
    unsigned short* whb  = wsh + 65536;      // 4096
    unsigned short* wg1b = wsh + 69632;      // 36864

    dim3 blk(256);

    // 1. input transposes
    k_transpose2<<<dim3(64, B, 2), blk, 192 * 65 * 4, stream>>>(group, BG + CHW, BST, X0T, BGcT);
    // 2. channel means of group
    k_xmean<<<B * 192, blk, 0, stream>>>(group, BST, xmean);
    // 3. scales + weight chain
    k_prep<<<8, blk, 0, stream>>>(
        xmean, wg1, bg1, cag_w1, cag_b1, cag_w2, cag_b2,
        wc1, bc1, cac_w1, cac_b1, cac_w2, cac_b2,
        wg2, bg2, wg3, bg3, wc2, bc2,
        f_w, f_b, g_w, g_b, h_w,
        W3L, Uf, bQ0L, bK0, sgG, scG, whb, wg1b);
    // 4. per-batch WQ scale + WK GEMM + biasK
    k_wscale<<<196, blk, 0, stream>>>(W3L, Uf, sgG, scG, wc1, bc1, bK0, WQs, WKb, biasK);
    // 5. g1 conv (MFMA)
    k_gconv<<<dim3(64, 3, B), blk, 0, stream>>>(X0T, wg1b, bg1, g1T);
    // 6. merged projections
    k_proj<<<dim3(64, 3, B), blk, 0, stream>>>(
        g1T, X0T, BGcT, WQs, bQ0L, WKb, biasK, whb, h_b, FqT, GkT, hvN);
    // 7. attention
    k_attn<<<256, 512, 0, stream>>>(FqT, GkT, hvN, mbuf, sbuf);
    // 8. fused mvn + transfer + cbam pools
    k_transfer_f<<<B * 64, blk, 0, stream>>>(mbuf, sbuf, FG, BG, BST, xb, pav, pmx);
    // 9/10. CBAM spatial
    k_sp_pool<<<dim3(HW / 256, B), blk, 0, stream>>>(xb, pav, pmx, mlp_w1, mlp_b1, mlp_w2, mlp_b2, spm, spx);
    k_spf<<<dim3(HW / 256, B), blk, 0, stream>>>(spm, spx, sp_w, sp_b, xb, pav, pmx, mlp_w1, mlp_b1, mlp_w2, mlp_b2, out);
}